// Round 1
// baseline (4220.539 us; speedup 1.0000x reference)
//
#include <hip/hip_runtime.h>

#define EPS 1e-5f

// workspace float offsets
#define OFF_S1   0                    // 32*25 = 800   spa1 table [o2*25+v]
#define OFF_T1   800                  // 128*64 = 8192 tem1 table [o*64+t]
#define OFF_A    8992                 // 64*64 = 4096  A = G1^T G2
#define OFF_C1   13088                // 64            c1[j] = b1^T G2[:,j]
#define OFF_C2   13152                // 64            c2[i] = b2^T G1[:,i]
#define OFF_D0   13216                // 1             b1.b2
#define OFF_BNJ  13217                // 150  (s75,o75)
#define OFF_BND  13367                // 150
#define OFF_BN1  13517                // 128  (s64,o64)
#define OFF_BN2  13645                // 256
#define OFF_BN3  13901                // 256
#define OFF_BNL1 14157                // 256
#define OFF_BNL2 14413                // 512 -> ends 14925
#define OFF_HP   16384                // 256*16*128*25 = 13107200
#define OFF_PART (16384+13107200)     // 256*25*256 = 1638400

struct P {
  const float *x,*bn_joint,*jw1,*jb1,*jw2,*jb2,*bn_dif,*dw1,*db1,*dw2,*db2,
    *tw1,*tb1,*tw2,*tb2,*sw1,*sb1,*sw2,*sb2,*g1w,*g1b,*g2w,*g2b,
    *c1w,*c1w1,*c1b1,*bnc1,*c2w,*c2w1,*c2b1,*bnc2,*c3w,*c3w1,*c3b1,*bnc3,
    *lw1,*lb1,*bnl1,*lw2,*lb2,*bnl2,*fcw,*fcb,*hww,*hwb,*pw,*pb,*ls;
  float *ws, *out;
};

__device__ inline void bn_pre(const float* bn, int C, float* dst, int tid){
  for (int c = tid; c < C; c += 256){
    float g = bn[c], b = bn[C+c], m = bn[2*C+c], v = bn[3*C+c];
    float s = g * rsqrtf(v + EPS);
    dst[c] = s; dst[C+c] = b - m*s;
  }
}

__global__ __launch_bounds__(256) void k_pre(P p){
  int tid = threadIdx.x;
  float* ws = p.ws;
  bn_pre(p.bn_joint, 75, ws+OFF_BNJ, tid);
  bn_pre(p.bn_dif,   75, ws+OFF_BND, tid);
  bn_pre(p.bnc1,     64, ws+OFF_BN1, tid);
  bn_pre(p.bnc2,    128, ws+OFF_BN2, tid);
  bn_pre(p.bnc3,    128, ws+OFF_BN3, tid);
  bn_pre(p.bnl1,    128, ws+OFF_BNL1, tid);
  bn_pre(p.bnl2,    256, ws+OFF_BNL2, tid);
  // spa1 table: [o2*25+v]
  for (int idx = tid; idx < 800; idx += 256){
    int o2 = idx / 25, v = idx % 25;
    float acc = p.sb2[o2];
    for (int o = 0; o < 64; o++){
      float e = fmaxf(p.sw1[o*25+v] + p.sb1[o], 0.f);
      acc += p.sw2[o2*64+o] * e;
    }
    ws[OFF_S1+idx] = fmaxf(acc, 0.f);
  }
  // tem1 table: [o*64+t]
  for (int idx = tid; idx < 8192; idx += 256){
    int o = idx / 64, t = idx % 64;
    float acc = p.tb2[o];
    for (int o1 = 0; o1 < 64; o1++){
      float e = fmaxf(p.tw1[o1*64+t] + p.tb1[o1], 0.f);
      acc += p.tw2[o*64+o1] * e;
    }
    ws[OFF_T1+idx] = fmaxf(acc, 0.f);
  }
  // A = G1^T G2
  for (int idx = tid; idx < 4096; idx += 256){
    int i = idx / 64, j = idx % 64;
    float acc = 0.f;
    for (int c = 0; c < 128; c++) acc += p.g1w[c*64+i] * p.g2w[c*64+j];
    ws[OFF_A+idx] = acc;
  }
  if (tid < 64){
    float a = 0.f; for (int c = 0; c < 128; c++) a += p.g1b[c]*p.g2w[c*64+tid];
    ws[OFF_C1+tid] = a;
  } else if (tid < 128){
    int j = tid - 64;
    float a = 0.f; for (int c = 0; c < 128; c++) a += p.g2b[c]*p.g1w[c*64+j];
    ws[OFF_C2+j] = a;
  } else if (tid == 128){
    float a = 0.f; for (int c = 0; c < 128; c++) a += p.g1b[c]*p.g2b[c];
    ws[OFF_D0] = a;
  }
}

// xp[c][v] = sum_u g[v][u] * Xin[c][u]
__device__ inline void xp_stage(int tid, int CIN, const float* sG, const float* sXin, float* sXp){
  for (int idx = tid; idx < CIN*25; idx += 256){
    int c = idx / 25, v = idx % 25;
    const float* gr = sG + v*25;
    const float* xr = sXin + c*25;
    float acc = 0.f;
    for (int u = 0; u < 25; u++) acc += gr[u]*xr[u];
    sXp[idx] = acc;
  }
}

// out[co][v] = relu(bnS[co]*(W.xp + W1.Xin + b1[co]) + bnO[co])
template<int CIN, int COUT, int COPT>
__device__ inline void gcn_conv(int tid, const float* W, const float* W1, const float* B1,
                                const float* bnS, const float* bnO,
                                const float* sXp, const float* sXin, float* sXout)
{
  const int NCOG = COUT / COPT;     // 32
  const int NVG  = 256 / NCOG;      // 8
  int cog = tid / NVG;
  int vg  = tid % NVG;
  int v0  = vg * 4;
  float acc[COPT][4];
  #pragma unroll
  for (int pp = 0; pp < COPT; pp++){
    float bb = B1[cog*COPT+pp];
    #pragma unroll
    for (int q = 0; q < 4; q++) acc[pp][q] = bb;
  }
  for (int c = 0; c < CIN; c++){
    float xpv[4], xiv[4];
    #pragma unroll
    for (int q = 0; q < 4; q++){
      int v = v0 + q;
      xpv[q] = (v < 25) ? sXp[c*25+v] : 0.f;
      xiv[q] = (v < 25) ? sXin[c*25+v] : 0.f;
    }
    #pragma unroll
    for (int pp = 0; pp < COPT; pp++){
      int co = cog*COPT+pp;
      float w  = W [co*CIN+c];
      float w1 = W1[co*CIN+c];
      #pragma unroll
      for (int q = 0; q < 4; q++) acc[pp][q] += w*xpv[q] + w1*xiv[q];
    }
  }
  #pragma unroll
  for (int pp = 0; pp < COPT; pp++){
    int co = cog*COPT+pp;
    float s = bnS[co], o = bnO[co];
    #pragma unroll
    for (int q = 0; q < 4; q++){
      int v = v0 + q;
      if (v < 25) sXout[co*25+v] = fmaxf(s*acc[pp][q]+o, 0.f);
    }
  }
}

// gcn3 variant: + tem1, running max
template<int CIN, int COUT, int COPT>
__device__ inline void gcn_conv3(int tid, const float* W, const float* W1, const float* B1,
                                 const float* bnS, const float* bnO,
                                 const float* sXp, const float* sXin,
                                 float* sHm, const float* sT1, int tt)
{
  const int NCOG = COUT / COPT;
  const int NVG  = 256 / NCOG;
  int cog = tid / NVG;
  int vg  = tid % NVG;
  int v0  = vg * 4;
  float acc[COPT][4];
  #pragma unroll
  for (int pp = 0; pp < COPT; pp++){
    float bb = B1[cog*COPT+pp];
    #pragma unroll
    for (int q = 0; q < 4; q++) acc[pp][q] = bb;
  }
  for (int c = 0; c < CIN; c++){
    float xpv[4], xiv[4];
    #pragma unroll
    for (int q = 0; q < 4; q++){
      int v = v0 + q;
      xpv[q] = (v < 25) ? sXp[c*25+v] : 0.f;
      xiv[q] = (v < 25) ? sXin[c*25+v] : 0.f;
    }
    #pragma unroll
    for (int pp = 0; pp < COPT; pp++){
      int co = cog*COPT+pp;
      float w  = W [co*CIN+c];
      float w1 = W1[co*CIN+c];
      #pragma unroll
      for (int q = 0; q < 4; q++) acc[pp][q] += w*xpv[q] + w1*xiv[q];
    }
  }
  #pragma unroll
  for (int pp = 0; pp < COPT; pp++){
    int co = cog*COPT+pp;
    float s = bnS[co], o = bnO[co];
    float tv = sT1[co*4+tt];
    #pragma unroll
    for (int q = 0; q < 4; q++){
      int v = v0 + q;
      if (v < 25){
        float val = fmaxf(s*acc[pp][q]+o, 0.f) + tv;
        sHm[co*25+v] = fmaxf(sHm[co*25+v], val);
      }
    }
  }
}

// fused: h0-embed + attention + gcn1..3 + tem + maxpool(4) per (b, tb)
__global__ __launch_bounds__(256) void k_main(P p){
  __shared__ float sXa[3200], sXb[1600], sXp[3400], sY[1600], sG[625], sHm[3200];
  __shared__ float sT1[512], sS1[800], sC1[64], sC2[64], sBn[640];
  __shared__ float sBnJ[150], sBnD[150], sXc[150], sCu[25], sCv[25], sD0[1];

  int tid = threadIdx.x;
  int bid = blockIdx.x;
  int b = bid >> 4, tb = bid & 15;
  int n = b >> 1, m = b & 1;
  int t0 = tb * 4;
  float* ws = p.ws;

  for (int i = tid; i < 800; i += 256) sS1[i] = ws[OFF_S1+i];
  for (int i = tid; i < 512; i += 256){
    int co = i >> 2, q = i & 3;
    sT1[i] = ws[OFF_T1 + co*64 + t0 + q];
  }
  if (tid < 64){ sC1[tid] = ws[OFF_C1+tid]; sC2[tid] = ws[OFF_C2+tid]; }
  if (tid == 64) sD0[0] = ws[OFF_D0];
  for (int i = tid; i < 128; i += 256) sBn[i]     = ws[OFF_BN1+i];
  for (int i = tid; i < 256; i += 256) sBn[128+i] = ws[OFF_BN2+i];
  for (int i = tid; i < 256; i += 256) sBn[384+i] = ws[OFF_BN3+i];
  for (int i = tid; i < 150; i += 256){ sBnJ[i] = ws[OFF_BNJ+i]; sBnD[i] = ws[OFF_BND+i]; }
  for (int i = tid; i < 3200; i += 256) sHm[i] = -1e30f;
  __syncthreads();

  for (int tt = 0; tt < 4; tt++){
    int t = t0 + tt;
    // stage x (cur + prev)
    if (tid < 150){
      int which = tid / 75; int j = tid % 75;
      int c = j / 25, v = j % 25;
      int ts = t - which;
      sXc[tid] = (ts >= 0) ? p.x[(((n*3+c)*64+ts)*25+v)*2+m] : 0.f;
    }
    __syncthreads();
    // e1 for pos + dif embeds (stride 65 to dodge bank conflicts)
    for (int idx = tid; idx < 1600; idx += 256){
      int v = idx >> 6, o = idx & 63;
      float pa = p.jb1[o], da = p.db1[o];
      #pragma unroll
      for (int c = 0; c < 3; c++){
        int ch = c*25+v;
        float xc = sXc[ch], xpv = sXc[75+ch];
        float y  = sBnJ[ch]*xc + sBnJ[75+ch];
        float d  = (t > 0) ? (xc - xpv) : 0.f;
        float yd = sBnD[ch]*d + sBnD[75+ch];
        pa += p.jw1[o*3+c]*y;
        da += p.dw1[o*3+c]*yd;
      }
      sXp[v*65+o]      = fmaxf(pa, 0.f);
      sXp[1700+v*65+o] = fmaxf(da, 0.f);
    }
    __syncthreads();
    // h0: ch 0-31 = pos+dife, 32-63 = spa1
    for (int idx = tid; idx < 800; idx += 256){
      int o2 = idx / 25, v = idx % 25;
      float pa = p.jb2[o2], da = p.db2[o2];
      for (int o = 0; o < 64; o++){
        pa += p.jw2[o2*64+o]*sXp[v*65+o];
        da += p.dw2[o2*64+o]*sXp[1700+v*65+o];
      }
      sXa[o2*25+v] = fmaxf(pa, 0.f) + fmaxf(da, 0.f);
      sXa[800+idx] = sS1[idx];
    }
    __syncthreads();
    // attention: Y[i][u] = sum_j A[i][j] h_u[j]
    for (int idx = tid; idx < 1600; idx += 256){
      int i = idx / 25, u = idx % 25;
      const float* Ar = ws + OFF_A + i*64;
      float acc = 0.f;
      for (int j = 0; j < 64; j++) acc += Ar[j]*sXa[j*25+u];
      sY[idx] = acc;
    }
    if (tid < 50){
      int u = tid % 25;
      const float* cc = (tid < 25) ? sC1 : sC2;
      float a = 0.f;
      for (int j = 0; j < 64; j++) a += cc[j]*sXa[j*25+u];
      if (tid < 25) sCu[u] = a; else sCv[u] = a;
    }
    __syncthreads();
    // scores
    for (int idx = tid; idx < 625; idx += 256){
      int v = idx / 25, u = idx % 25;
      float acc = sCu[u] + sCv[v] + sD0[0];
      for (int i = 0; i < 64; i++) acc += sXa[i*25+v]*sY[i*25+u];
      sG[idx] = acc;
    }
    __syncthreads();
    // softmax over u per row v
    if (tid < 25){
      float mx = -1e30f;
      for (int u = 0; u < 25; u++) mx = fmaxf(mx, sG[tid*25+u]);
      float s = 0.f;
      for (int u = 0; u < 25; u++){ float e = expf(sG[tid*25+u]-mx); sG[tid*25+u] = e; s += e; }
      float inv = 1.f/s;
      for (int u = 0; u < 25; u++) sG[tid*25+u] *= inv;
    }
    __syncthreads();
    // gcn1 (64->64): in sXa, out sXb
    xp_stage(tid, 64, sG, sXa, sXp);
    __syncthreads();
    gcn_conv<64,64,2>(tid, p.c1w, p.c1w1, p.c1b1, sBn, sBn+64, sXp, sXa, sXb);
    __syncthreads();
    // gcn2 (64->128): in sXb, out sXa
    xp_stage(tid, 64, sG, sXb, sXp);
    __syncthreads();
    gcn_conv<64,128,4>(tid, p.c2w, p.c2w1, p.c2b1, sBn+128, sBn+256, sXp, sXb, sXa);
    __syncthreads();
    // gcn3 (128->128): in sXa, +tem1, running max
    xp_stage(tid, 128, sG, sXa, sXp);
    __syncthreads();
    gcn_conv3<128,128,4>(tid, p.c3w, p.c3w1, p.c3b1, sBn+384, sBn+512, sXp, sXa, sHm, sT1, tt);
    __syncthreads();
  }
  // write hp: layout (B,16,128,25) contiguous per block
  float* hp = ws + OFF_HP + (size_t)(b*16+tb)*3200;
  for (int i = tid; i < 3200; i += 256) hp[i] = sHm[i];
}

// loc stage per (b, v): conv3(t) + bn + relu, 1x1 -> 256 + bn + relu, sum over s
__global__ __launch_bounds__(256) void k_loc(P p){
  __shared__ float sIn[128*18];   // padded s: [ci][0..17], 0 and 17 are zero pad
  __shared__ float sO1[128*16];
  int tid = threadIdx.x;
  int bid = blockIdx.x;
  int b = bid / 25, v = bid % 25;
  float* ws = p.ws;

  for (int i = tid; i < 2304; i += 256) sIn[i] = 0.f;
  __syncthreads();
  for (int i = tid; i < 2048; i += 256){
    int s = i >> 7, ci = i & 127;
    sIn[ci*18 + 1 + s] = ws[OFF_HP + (size_t)((b*16+s)*128+ci)*25 + v];
  }
  __syncthreads();
  {
    int co = tid >> 1, sh = tid & 1;
    float acc[8];
    float bb = p.lb1[co];
    #pragma unroll
    for (int j = 0; j < 8; j++) acc[j] = bb;
    for (int ci = 0; ci < 128; ci++){
      float r[10];
      #pragma unroll
      for (int j = 0; j < 10; j++) r[j] = sIn[ci*18 + sh*8 + j];
      const float* wr = p.lw1 + (co*128+ci)*3;
      float w0 = wr[0], w1 = wr[1], w2 = wr[2];
      #pragma unroll
      for (int j = 0; j < 8; j++) acc[j] += w0*r[j] + w1*r[j+1] + w2*r[j+2];
    }
    float s1 = ws[OFF_BNL1+co], o1 = ws[OFF_BNL1+128+co];
    #pragma unroll
    for (int j = 0; j < 8; j++) sO1[co*16 + sh*8 + j] = fmaxf(s1*acc[j]+o1, 0.f);
  }
  __syncthreads();
  {
    int co2 = tid;
    float acc[16];
    float bb = p.lb2[co2];
    #pragma unroll
    for (int s = 0; s < 16; s++) acc[s] = bb;
    for (int ci = 0; ci < 128; ci++){
      float w = p.lw2[co2*128+ci];
      const float* orow = sO1 + ci*16;
      #pragma unroll
      for (int s = 0; s < 16; s++) acc[s] += w*orow[s];
    }
    float s2 = ws[OFF_BNL2+co2], o2 = ws[OFF_BNL2+256+co2];
    float psum = 0.f;
    #pragma unroll
    for (int s = 0; s < 16; s++) psum += fmaxf(s2*acc[s]+o2, 0.f);
    ws[OFF_PART + (size_t)(b*25+v)*256 + co2] = psum;
  }
}

// pooling + all FC heads, per n
__global__ __launch_bounds__(256) void k_final(P p){
  __shared__ float pool[5*256];
  int tid = threadIdx.x, n = blockIdx.x;
  const float* part = p.ws + OFF_PART;
  float tot = 0.f, hd = 0.f, hn = 0.f, ft = 0.f, hq = 0.f;
  for (int m2 = 0; m2 < 2; m2++){
    for (int v = 0; v < 25; v++){
      float pv = part[(size_t)((n*2+m2)*25+v)*256 + tid];
      tot += pv;
      unsigned bit = 1u << v;
      if (bit & 0x10000Cu)  hd += pv;  // HEAD {2,3,20}
      if (bit & 0x1E00FF0u) hn += pv;  // HAND {4..11,21..24}
      if (bit & 0xFF000u)   ft += pv;  // FOOT {12..19}
      if (bit & 0x11007u)   hq += pv;  // HIP  {0,1,2,12,16}
    }
  }
  pool[tid]      = tot * (1.f/800.f);
  pool[256+tid]  = hd  * (1.f/96.f);
  pool[512+tid]  = hn  * (1.f/384.f);
  pool[768+tid]  = ft  * (1.f/256.f);
  pool[1024+tid] = hq  * (1.f/160.f);
  __syncthreads();
  float* out = p.out;
  for (int o = tid; o < 2620; o += 256){
    const float* wrow; float bias; const float* pl; int off;
    if (o < 60)        { wrow = p.fcw + o*256;            bias = p.fcb[o];        pl = pool;       off = n*60+o; }
    else if (o < 572)  { int j=o-60;   wrow = p.hww + j*256;         bias = p.hwb[j];       pl = pool;       off = 7680   + n*512+j; }
    else if (o < 1084) { int j=o-572;  wrow = p.pw  + j*256;         bias = p.pb[j];        pl = pool+256;   off = 73221  + n*512+j; }
    else if (o < 1596) { int j=o-1084; wrow = p.pw  + (512+j)*256;   bias = p.pb[512+j];    pl = pool+512;   off = 138757 + n*512+j; }
    else if (o < 2108) { int j=o-1596; wrow = p.pw  + (1536+j)*256;  bias = p.pb[1536+j];   pl = pool+1024;  off = 204293 + n*512+j; }
    else               { int j=o-2108; wrow = p.pw  + (1024+j)*256;  bias = p.pb[1024+j];   pl = pool+768;   off = 269829 + n*512+j; }
    float acc = bias;
    for (int c = 0; c < 256; c++) acc += wrow[c]*pl[c];
    out[off] = acc;
  }
  if (n == 0 && tid < 5) out[73216+tid] = p.ls[tid];
}

extern "C" void kernel_launch(void* const* d_in, const int* in_sizes, int n_in,
                              void* d_out, int out_size, void* d_ws, size_t ws_size,
                              hipStream_t stream){
  P p;
  p.x        = (const float*)d_in[0];
  p.bn_joint = (const float*)d_in[1];
  p.jw1      = (const float*)d_in[2];
  p.jb1      = (const float*)d_in[3];
  p.jw2      = (const float*)d_in[4];
  p.jb2      = (const float*)d_in[5];
  p.bn_dif   = (const float*)d_in[6];
  p.dw1      = (const float*)d_in[7];
  p.db1      = (const float*)d_in[8];
  p.dw2      = (const float*)d_in[9];
  p.db2      = (const float*)d_in[10];
  p.tw1      = (const float*)d_in[11];
  p.tb1      = (const float*)d_in[12];
  p.tw2      = (const float*)d_in[13];
  p.tb2      = (const float*)d_in[14];
  p.sw1      = (const float*)d_in[15];
  p.sb1      = (const float*)d_in[16];
  p.sw2      = (const float*)d_in[17];
  p.sb2      = (const float*)d_in[18];
  p.g1w      = (const float*)d_in[19];
  p.g1b      = (const float*)d_in[20];
  p.g2w      = (const float*)d_in[21];
  p.g2b      = (const float*)d_in[22];
  p.c1w      = (const float*)d_in[23];
  p.c1w1     = (const float*)d_in[24];
  p.c1b1     = (const float*)d_in[25];
  p.bnc1     = (const float*)d_in[26];
  p.c2w      = (const float*)d_in[27];
  p.c2w1     = (const float*)d_in[28];
  p.c2b1     = (const float*)d_in[29];
  p.bnc2     = (const float*)d_in[30];
  p.c3w      = (const float*)d_in[31];
  p.c3w1     = (const float*)d_in[32];
  p.c3b1     = (const float*)d_in[33];
  p.bnc3     = (const float*)d_in[34];
  p.lw1      = (const float*)d_in[35];
  p.lb1      = (const float*)d_in[36];
  p.bnl1     = (const float*)d_in[37];
  p.lw2      = (const float*)d_in[38];
  p.lb2      = (const float*)d_in[39];
  p.bnl2     = (const float*)d_in[40];
  p.fcw      = (const float*)d_in[41];
  p.fcb      = (const float*)d_in[42];
  p.hww      = (const float*)d_in[43];
  p.hwb      = (const float*)d_in[44];
  p.pw       = (const float*)d_in[45];
  p.pb       = (const float*)d_in[46];
  p.ls       = (const float*)d_in[47];
  p.ws  = (float*)d_ws;
  p.out = (float*)d_out;

  k_pre  <<<dim3(1),    dim3(256), 0, stream>>>(p);
  k_main <<<dim3(4096), dim3(256), 0, stream>>>(p);
  k_loc  <<<dim3(6400), dim3(256), 0, stream>>>(p);
  k_final<<<dim3(128),  dim3(256), 0, stream>>>(p);
}

// Round 3
// 3672.391 us; speedup vs baseline: 1.1493x; 1.1493x over previous
//
#include <hip/hip_runtime.h>

#define EPS 1e-5f

// workspace float offsets
#define OFF_S1   0                    // 25*32 spa1 table [v*32+o2]
#define OFF_T1   800                  // 128*64 tem1 table [o*64+t]
#define OFF_A    8992                 // 64*64  A = G1^T G2
#define OFF_C1   13088                // 64 C1, 64 C2, 1 D0 (contiguous 129)
#define OFF_BNJ  13217                // 150
#define OFF_BND  13367                // 150
#define OFF_BN1  13517                // 128+256+256 = 640 contiguous (gcn1,2,3)
#define OFF_BNL1 14157                // 256
#define OFF_BNL2 14413                // 512
#define OFF_POOL 16384                // 256*16*25*128 uint keys = 13107200
#define OFF_PART (16384+13107200)     // 256*25*256

#define SB 68
#define SBIG 132
#define SGS 28

struct P {
  const float *x,*bn_joint,*jw1,*jb1,*jw2,*jb2,*bn_dif,*dw1,*db1,*dw2,*db2,
    *tw1,*tb1,*tw2,*tb2,*sw1,*sb1,*sw2,*sb2,*g1w,*g1b,*g2w,*g2b,
    *c1w,*c1w1,*c1b1,*bnc1,*c2w,*c2w1,*c2b1,*bnc2,*c3w,*c3w1,*c3b1,*bnc3,
    *lw1,*lb1,*bnl1,*lw2,*lb2,*bnl2,*fcw,*fcb,*hww,*hwb,*pw,*pb,*ls;
  float *ws, *out;
};

__device__ inline unsigned fkey(float x){
  unsigned u = __float_as_uint(x);
  return (u >> 31) ? ~u : (u | 0x80000000u);
}
__device__ inline float fdec(unsigned k){
  unsigned u = (k & 0x80000000u) ? (k ^ 0x80000000u) : ~k;
  return __uint_as_float(u);
}

__device__ inline void dot4(float& acc, float4 a, float4 b){
  acc += a.x*b.x + a.y*b.y + a.z*b.z + a.w*b.w;
}

__device__ inline void bn_pre(const float* bn, int C, float* dst, int tid){
  for (int c = tid; c < C; c += 256){
    float g = bn[c], b = bn[C+c], m = bn[2*C+c], v = bn[3*C+c];
    float s = g * rsqrtf(v + EPS);
    dst[c] = s; dst[C+c] = b - m*s;
  }
}

__global__ __launch_bounds__(256) void k_pre(P p){
  int tid = threadIdx.x;
  float* ws = p.ws;
  bn_pre(p.bn_joint, 75, ws+OFF_BNJ, tid);
  bn_pre(p.bn_dif,   75, ws+OFF_BND, tid);
  bn_pre(p.bnc1,     64, ws+OFF_BN1, tid);
  bn_pre(p.bnc2,    128, ws+OFF_BN1+128, tid);
  bn_pre(p.bnc3,    128, ws+OFF_BN1+384, tid);
  bn_pre(p.bnl1,    128, ws+OFF_BNL1, tid);
  bn_pre(p.bnl2,    256, ws+OFF_BNL2, tid);
  // spa1 table: [v*32+o2]
  for (int idx = tid; idx < 800; idx += 256){
    int v = idx >> 5, o2 = idx & 31;
    float acc = p.sb2[o2];
    for (int o = 0; o < 64; o++){
      float e = fmaxf(p.sw1[o*25+v] + p.sb1[o], 0.f);
      acc += p.sw2[o2*64+o] * e;
    }
    ws[OFF_S1+idx] = fmaxf(acc, 0.f);
  }
  // tem1 table: [o*64+t]
  for (int idx = tid; idx < 8192; idx += 256){
    int o = idx / 64, t = idx % 64;
    float acc = p.tb2[o];
    for (int o1 = 0; o1 < 64; o1++){
      float e = fmaxf(p.tw1[o1*64+t] + p.tb1[o1], 0.f);
      acc += p.tw2[o*64+o1] * e;
    }
    ws[OFF_T1+idx] = fmaxf(acc, 0.f);
  }
  // A = G1^T G2
  for (int idx = tid; idx < 4096; idx += 256){
    int i = idx / 64, j = idx % 64;
    float acc = 0.f;
    for (int c = 0; c < 128; c++) acc += p.g1w[c*64+i] * p.g2w[c*64+j];
    ws[OFF_A+idx] = acc;
  }
  if (tid < 64){
    float a = 0.f; for (int c = 0; c < 128; c++) a += p.g1b[c]*p.g2w[c*64+tid];
    ws[OFF_C1+tid] = a;
  } else if (tid < 128){
    int j = tid - 64;
    float a = 0.f; for (int c = 0; c < 128; c++) a += p.g2b[c]*p.g1w[c*64+j];
    ws[OFF_C1+64+j] = a;
  } else if (tid == 128){
    float a = 0.f; for (int c = 0; c < 128; c++) a += p.g1b[c]*p.g2b[c];
    ws[OFF_C1+128] = a;
  }
}

// one block per (b, t)
__global__ __launch_bounds__(256) void k_main(P p){
  __shared__ float B1[28*SB];     // e1p -> Y2 -> gcn1out
  __shared__ float B2[28*SB];     // e1d -> xp1 -> xp2
  __shared__ float Big1[28*SBIG]; // h0(64) -> gcn2out(128)
  __shared__ float Big2[28*SBIG]; // xp3(128)
  __shared__ float sG[28*SGS];
  __shared__ float sBnJ[150], sBnD[150], sBn[640], sC[132], sXc[152], sT[128], sCuv[52];

  int tid = threadIdx.x;
  int bid = blockIdx.x;
  int b = bid >> 6, t = bid & 63;
  int n = b >> 1, m = b & 1;
  float* ws = p.ws;
  const float* A = ws + OFF_A;

  // stage 0: tables + x slice
  for (int i = tid; i < 150; i += 256){ sBnJ[i] = ws[OFF_BNJ+i]; sBnD[i] = ws[OFF_BND+i]; }
  for (int i = tid; i < 640; i += 256) sBn[i] = ws[OFF_BN1+i];
  if (tid < 129) sC[tid] = ws[OFF_C1+tid];
  if (tid < 128) sT[tid] = ws[OFF_T1 + tid*64 + t];
  if (tid < 150){
    int which = tid / 75, j = tid % 75;
    int c = j / 25, v = j % 25;
    int ts = t - which;
    sXc[tid] = (ts >= 0) ? p.x[(((n*3+c)*64+ts)*25+v)*2+m] : 0.f;
  }
  __syncthreads();

  // e1 (pos + dif): [v][o] o=0..63
  for (int idx = tid; idx < 1600; idx += 256){
    int v = idx >> 6, o = idx & 63;
    float pa = p.jb1[o], da = p.db1[o];
    #pragma unroll
    for (int c = 0; c < 3; c++){
      int ch = c*25+v;
      float xc = sXc[ch];
      float y  = sBnJ[ch]*xc + sBnJ[75+ch];
      float d  = (t > 0) ? (xc - sXc[75+ch]) : 0.f;
      float yd = sBnD[ch]*d + sBnD[75+ch];
      pa += p.jw1[o*3+c]*y;
      da += p.dw1[o*3+c]*yd;
    }
    B1[v*SB+o] = fmaxf(pa, 0.f);
    B2[v*SB+o] = fmaxf(da, 0.f);
  }
  __syncthreads();

  // h0 -> Big1[v][0..63]: c<32 pos2+dif2, c>=32 spa
  for (int idx = tid; idx < 1600; idx += 256){
    if (idx < 800){
      int v = idx >> 5, c2 = idx & 31;
      float accp = p.jb2[c2], accd = p.db2[c2];
      for (int j = 0; j < 64; j += 4){
        float4 ep = *(const float4*)&B1[v*SB+j];
        float4 ed = *(const float4*)&B2[v*SB+j];
        float4 wp = *(const float4*)&p.jw2[c2*64+j];
        float4 wd = *(const float4*)&p.dw2[c2*64+j];
        dot4(accp, wp, ep);
        dot4(accd, wd, ed);
      }
      Big1[v*SBIG+c2] = fmaxf(accp, 0.f) + fmaxf(accd, 0.f);
    } else {
      int idx2 = idx - 800;
      int v = idx2 >> 5, c2 = idx2 & 31;
      Big1[v*SBIG+32+c2] = ws[OFF_S1 + v*32 + c2];
    }
  }
  __syncthreads();

  // Y2[u][i] = (A h_u)[i] -> B1 ; Cu/Cv
  for (int idx = tid; idx < 1650; idx += 256){
    if (idx < 1600){
      int u = idx >> 6, i = idx & 63;
      float acc = 0.f;
      for (int j = 0; j < 64; j += 4){
        float4 ar = *(const float4*)&A[i*64+j];
        float4 hu = *(const float4*)&Big1[u*SBIG+j];
        dot4(acc, ar, hu);
      }
      B1[u*SB+i] = acc;
    } else {
      int w = idx - 1600;
      int u = (w < 25) ? w : w - 25;
      const float* cc = (w < 25) ? sC : sC + 64;
      float acc = 0.f;
      for (int j = 0; j < 64; j += 4){
        float4 cv = *(const float4*)&cc[j];
        float4 hu = *(const float4*)&Big1[u*SBIG+j];
        dot4(acc, cv, hu);
      }
      sCuv[w] = acc;
    }
  }
  __syncthreads();

  // scores S[v][u]
  for (int idx = tid; idx < 625; idx += 256){
    int v = idx / 25, u = idx % 25;
    float acc = sCuv[u] + sCuv[25+v] + sC[128];
    for (int j = 0; j < 64; j += 4){
      float4 hv = *(const float4*)&Big1[v*SBIG+j];
      float4 yu = *(const float4*)&B1[u*SB+j];
      dot4(acc, hv, yu);
    }
    sG[v*SGS+u] = acc;
  }
  __syncthreads();

  // softmax rows: 32 rows x 8 lanes
  {
    int v = tid >> 3, t8 = tid & 7;
    if (v < 25){
      float a = sG[v*SGS+t8], bb = sG[v*SGS+t8+8], c = sG[v*SGS+t8+16];
      float d = (t8 == 0) ? sG[v*SGS+24] : -1e30f;
      float mx = fmaxf(fmaxf(a, bb), fmaxf(c, d));
      mx = fmaxf(mx, __shfl_xor(mx, 1));
      mx = fmaxf(mx, __shfl_xor(mx, 2));
      mx = fmaxf(mx, __shfl_xor(mx, 4));
      float ea = __expf(a-mx), eb = __expf(bb-mx), ec = __expf(c-mx);
      float ed = (t8 == 0) ? __expf(d-mx) : 0.f;
      float s = ea+eb+ec+ed;
      s += __shfl_xor(s, 1);
      s += __shfl_xor(s, 2);
      s += __shfl_xor(s, 4);
      float inv = 1.f/s;
      sG[v*SGS+t8] = ea*inv; sG[v*SGS+t8+8] = eb*inv; sG[v*SGS+t8+16] = ec*inv;
      if (t8 == 0) sG[v*SGS+24] = ed*inv;
    }
  }
  __syncthreads();

  // xp1: B2[v][c] = sum_u g[v][u] * Big1[u][c]   (64ch, v2-tile)
  if (tid < 208){
    int v2 = tid >> 4, c4 = tid & 15;
    int v0 = v2*2, cc = c4*4;
    float4 a0 = {0,0,0,0}, a1 = {0,0,0,0};
    for (int u = 0; u < 25; u++){
      float g0 = sG[v0*SGS+u], g1 = sG[(v0+1)*SGS+u];
      float4 xu = *(const float4*)&Big1[u*SBIG+cc];
      a0.x += g0*xu.x; a0.y += g0*xu.y; a0.z += g0*xu.z; a0.w += g0*xu.w;
      a1.x += g1*xu.x; a1.y += g1*xu.y; a1.z += g1*xu.z; a1.w += g1*xu.w;
    }
    *(float4*)&B2[v0*SB+cc] = a0;
    *(float4*)&B2[(v0+1)*SB+cc] = a1;
  }
  __syncthreads();

  // gcn1: in Big1(h0), xp B2 -> out B1   (64->64, v2 x co4 tiles, co-major)
  if (tid < 208){
    int co4 = tid / 13, v2 = tid % 13;
    int co0 = co4*4, v0 = v2*2;
    float acc[2][4] = {};
    for (int c = 0; c < 64; c += 4){
      float4 x0 = *(const float4*)&B2[v0*SB+c];
      float4 x1 = *(const float4*)&B2[(v0+1)*SB+c];
      float4 h0a = *(const float4*)&Big1[v0*SBIG+c];
      float4 h0b = *(const float4*)&Big1[(v0+1)*SBIG+c];
      #pragma unroll
      for (int k = 0; k < 4; k++){
        float4 w  = *(const float4*)&p.c1w [(co0+k)*64+c];
        float4 w1 = *(const float4*)&p.c1w1[(co0+k)*64+c];
        dot4(acc[0][k], w, x0); dot4(acc[0][k], w1, h0a);
        dot4(acc[1][k], w, x1); dot4(acc[1][k], w1, h0b);
      }
    }
    #pragma unroll
    for (int i = 0; i < 2; i++){
      float4 o4;
      float* ov = (float*)&o4;
      #pragma unroll
      for (int k = 0; k < 4; k++){
        int co = co0+k;
        ov[k] = fmaxf(sBn[co]*(acc[i][k]+p.c1b1[co]) + sBn[64+co], 0.f);
      }
      *(float4*)&B1[(v0+i)*SB+co0] = o4;
    }
  }
  __syncthreads();

  // xp2: B2[v][c] from B1 (gcn1 out)
  if (tid < 208){
    int v2 = tid >> 4, c4 = tid & 15;
    int v0 = v2*2, cc = c4*4;
    float4 a0 = {0,0,0,0}, a1 = {0,0,0,0};
    for (int u = 0; u < 25; u++){
      float g0 = sG[v0*SGS+u], g1 = sG[(v0+1)*SGS+u];
      float4 xu = *(const float4*)&B1[u*SB+cc];
      a0.x += g0*xu.x; a0.y += g0*xu.y; a0.z += g0*xu.z; a0.w += g0*xu.w;
      a1.x += g1*xu.x; a1.y += g1*xu.y; a1.z += g1*xu.z; a1.w += g1*xu.w;
    }
    *(float4*)&B2[v0*SB+cc] = a0;
    *(float4*)&B2[(v0+1)*SB+cc] = a1;
  }
  __syncthreads();

  // gcn2: in B1, xp B2 -> out Big1 (64->128, v4 x co4, co-major)
  if (tid < 224){
    int co4 = tid / 7, vq = tid % 7;
    int co0 = co4*4, v0 = vq*4;
    float acc[4][4] = {};
    for (int c = 0; c < 64; c += 4){
      float4 xp[4], xi[4];
      #pragma unroll
      for (int i = 0; i < 4; i++){
        xp[i] = *(const float4*)&B2[(v0+i)*SB+c];
        xi[i] = *(const float4*)&B1[(v0+i)*SB+c];
      }
      #pragma unroll
      for (int k = 0; k < 4; k++){
        float4 w  = *(const float4*)&p.c2w [(co0+k)*64+c];
        float4 w1 = *(const float4*)&p.c2w1[(co0+k)*64+c];
        #pragma unroll
        for (int i = 0; i < 4; i++){ dot4(acc[i][k], w, xp[i]); dot4(acc[i][k], w1, xi[i]); }
      }
    }
    #pragma unroll
    for (int i = 0; i < 4; i++){
      float4 o4; float* ov = (float*)&o4;
      #pragma unroll
      for (int k = 0; k < 4; k++){
        int co = co0+k;
        ov[k] = fmaxf(sBn[128+co]*(acc[i][k]+p.c2b1[co]) + sBn[256+co], 0.f);
      }
      *(float4*)&Big1[(v0+i)*SBIG+co0] = o4;
    }
  }
  __syncthreads();

  // xp3: Big2[v][c] from Big1 (128ch, v4-tile)
  if (tid < 224){
    int vq = tid >> 5, c4 = tid & 31;
    int v0 = vq*4, cc = c4*4;
    float4 a[4] = {};
    for (int u = 0; u < 25; u++){
      float4 xu = *(const float4*)&Big1[u*SBIG+cc];
      #pragma unroll
      for (int i = 0; i < 4; i++){
        float g = sG[(v0+i)*SGS+u];
        a[i].x += g*xu.x; a[i].y += g*xu.y; a[i].z += g*xu.z; a[i].w += g*xu.w;
      }
    }
    #pragma unroll
    for (int i = 0; i < 4; i++) *(float4*)&Big2[(v0+i)*SBIG+cc] = a[i];
  }
  __syncthreads();

  // gcn3: in Big1, xp Big2 -> +tem -> atomic max pool (128->128)
  if (tid < 224){
    int co4 = tid / 7, vq = tid % 7;
    int co0 = co4*4, v0 = vq*4;
    float acc[4][4] = {};
    for (int c = 0; c < 128; c += 4){
      float4 xp[4], xi[4];
      #pragma unroll
      for (int i = 0; i < 4; i++){
        xp[i] = *(const float4*)&Big2[(v0+i)*SBIG+c];
        xi[i] = *(const float4*)&Big1[(v0+i)*SBIG+c];
      }
      #pragma unroll
      for (int k = 0; k < 4; k++){
        float4 w  = *(const float4*)&p.c3w [(co0+k)*128+c];
        float4 w1 = *(const float4*)&p.c3w1[(co0+k)*128+c];
        #pragma unroll
        for (int i = 0; i < 4; i++){ dot4(acc[i][k], w, xp[i]); dot4(acc[i][k], w1, xi[i]); }
      }
    }
    unsigned* pool = (unsigned*)(ws + OFF_POOL);
    int s = t >> 2;
    #pragma unroll
    for (int i = 0; i < 4; i++){
      int v = v0 + i;
      if (v < 25){
        size_t base = ((size_t)(b*16+s)*25+v)*128 + co0;
        #pragma unroll
        for (int k = 0; k < 4; k++){
          int co = co0+k;
          float val = fmaxf(sBn[384+co]*(acc[i][k]+p.c3b1[co]) + sBn[512+co], 0.f) + sT[co];
          atomicMax(&pool[base+k], fkey(val));
        }
      }
    }
  }
}

// loc stage per (b, v)
__global__ __launch_bounds__(256) void k_loc(P p){
  __shared__ float sIn[128*18];
  __shared__ float sO1[128*16];
  int tid = threadIdx.x;
  int bid = blockIdx.x;
  int b = bid / 25, v = bid % 25;
  float* ws = p.ws;
  const unsigned* pool = (const unsigned*)(ws + OFF_POOL);

  for (int i = tid; i < 2304; i += 256) sIn[i] = 0.f;
  __syncthreads();
  for (int i = tid; i < 2048; i += 256){
    int s = i >> 7, ci = i & 127;
    sIn[ci*18 + 1 + s] = fdec(pool[((size_t)(b*16+s)*25+v)*128 + ci]);
  }
  __syncthreads();
  {
    int co = tid >> 1, sh = tid & 1;
    float acc[8];
    float bb = p.lb1[co];
    #pragma unroll
    for (int j = 0; j < 8; j++) acc[j] = bb;
    for (int ci = 0; ci < 128; ci++){
      float r[10];
      #pragma unroll
      for (int j = 0; j < 10; j++) r[j] = sIn[ci*18 + sh*8 + j];
      const float* wr = p.lw1 + (co*128+ci)*3;
      float w0 = wr[0], w1 = wr[1], w2 = wr[2];
      #pragma unroll
      for (int j = 0; j < 8; j++) acc[j] += w0*r[j] + w1*r[j+1] + w2*r[j+2];
    }
    float s1 = ws[OFF_BNL1+co], o1 = ws[OFF_BNL1+128+co];
    #pragma unroll
    for (int j = 0; j < 8; j++) sO1[co*16 + sh*8 + j] = fmaxf(s1*acc[j]+o1, 0.f);
  }
  __syncthreads();
  {
    int co2 = tid;
    float acc[16];
    float bb = p.lb2[co2];
    #pragma unroll
    for (int s = 0; s < 16; s++) acc[s] = bb;
    for (int ci = 0; ci < 128; ci++){
      float w = p.lw2[co2*128+ci];
      const float* orow = sO1 + ci*16;
      #pragma unroll
      for (int s = 0; s < 16; s++) acc[s] += w*orow[s];
    }
    float s2 = ws[OFF_BNL2+co2], o2 = ws[OFF_BNL2+256+co2];
    float psum = 0.f;
    #pragma unroll
    for (int s = 0; s < 16; s++) psum += fmaxf(s2*acc[s]+o2, 0.f);
    ws[OFF_PART + (size_t)(b*25+v)*256 + co2] = psum;
  }
}

// pooling + FC heads, per n
__global__ __launch_bounds__(256) void k_final(P p){
  __shared__ float pool[5*256];
  int tid = threadIdx.x, n = blockIdx.x;
  const float* part = p.ws + OFF_PART;
  float tot = 0.f, hd = 0.f, hn = 0.f, ft = 0.f, hq = 0.f;
  for (int m2 = 0; m2 < 2; m2++){
    for (int v = 0; v < 25; v++){
      float pv = part[(size_t)((n*2+m2)*25+v)*256 + tid];
      tot += pv;
      unsigned bit = 1u << v;
      if (bit & 0x10000Cu)  hd += pv;
      if (bit & 0x1E00FF0u) hn += pv;
      if (bit & 0xFF000u)   ft += pv;
      if (bit & 0x11007u)   hq += pv;
    }
  }
  pool[tid]      = tot * (1.f/800.f);
  pool[256+tid]  = hd  * (1.f/96.f);
  pool[512+tid]  = hn  * (1.f/384.f);
  pool[768+tid]  = ft  * (1.f/256.f);
  pool[1024+tid] = hq  * (1.f/160.f);
  __syncthreads();
  float* out = p.out;
  for (int o = tid; o < 2620; o += 256){
    const float* wrow; float bias; const float* pl; int off;
    if (o < 60)        { wrow = p.fcw + o*256;            bias = p.fcb[o];        pl = pool;       off = n*60+o; }
    else if (o < 572)  { int j=o-60;   wrow = p.hww + j*256;         bias = p.hwb[j];       pl = pool;       off = 7680   + n*512+j; }
    else if (o < 1084) { int j=o-572;  wrow = p.pw  + j*256;         bias = p.pb[j];        pl = pool+256;   off = 73221  + n*512+j; }
    else if (o < 1596) { int j=o-1084; wrow = p.pw  + (512+j)*256;   bias = p.pb[512+j];    pl = pool+512;   off = 138757 + n*512+j; }
    else if (o < 2108) { int j=o-1596; wrow = p.pw  + (1536+j)*256;  bias = p.pb[1536+j];   pl = pool+1024;  off = 204293 + n*512+j; }
    else               { int j=o-2108; wrow = p.pw  + (1024+j)*256;  bias = p.pb[1024+j];   pl = pool+768;   off = 269829 + n*512+j; }
    float acc = bias;
    for (int c = 0; c < 256; c++) acc += wrow[c]*pl[c];
    out[off] = acc;
  }
  if (n == 0 && tid < 5) out[73216+tid] = p.ls[tid];
}

extern "C" void kernel_launch(void* const* d_in, const int* in_sizes, int n_in,
                              void* d_out, int out_size, void* d_ws, size_t ws_size,
                              hipStream_t stream){
  P p;
  p.x        = (const float*)d_in[0];
  p.bn_joint = (const float*)d_in[1];
  p.jw1      = (const float*)d_in[2];
  p.jb1      = (const float*)d_in[3];
  p.jw2      = (const float*)d_in[4];
  p.jb2      = (const float*)d_in[5];
  p.bn_dif   = (const float*)d_in[6];
  p.dw1      = (const float*)d_in[7];
  p.db1      = (const float*)d_in[8];
  p.dw2      = (const float*)d_in[9];
  p.db2      = (const float*)d_in[10];
  p.tw1      = (const float*)d_in[11];
  p.tb1      = (const float*)d_in[12];
  p.tw2      = (const float*)d_in[13];
  p.tb2      = (const float*)d_in[14];
  p.sw1      = (const float*)d_in[15];
  p.sb1      = (const float*)d_in[16];
  p.sw2      = (const float*)d_in[17];
  p.sb2      = (const float*)d_in[18];
  p.g1w      = (const float*)d_in[19];
  p.g1b      = (const float*)d_in[20];
  p.g2w      = (const float*)d_in[21];
  p.g2b      = (const float*)d_in[22];
  p.c1w      = (const float*)d_in[23];
  p.c1w1     = (const float*)d_in[24];
  p.c1b1     = (const float*)d_in[25];
  p.bnc1     = (const float*)d_in[26];
  p.c2w      = (const float*)d_in[27];
  p.c2w1     = (const float*)d_in[28];
  p.c2b1     = (const float*)d_in[29];
  p.bnc2     = (const float*)d_in[30];
  p.c3w      = (const float*)d_in[31];
  p.c3w1     = (const float*)d_in[32];
  p.c3b1     = (const float*)d_in[33];
  p.bnc3     = (const float*)d_in[34];
  p.lw1      = (const float*)d_in[35];
  p.lb1      = (const float*)d_in[36];
  p.bnl1     = (const float*)d_in[37];
  p.lw2      = (const float*)d_in[38];
  p.lb2      = (const float*)d_in[39];
  p.bnl2     = (const float*)d_in[40];
  p.fcw      = (const float*)d_in[41];
  p.fcb      = (const float*)d_in[42];
  p.hww      = (const float*)d_in[43];
  p.hwb      = (const float*)d_in[44];
  p.pw       = (const float*)d_in[45];
  p.pb       = (const float*)d_in[46];
  p.ls       = (const float*)d_in[47];
  p.ws  = (float*)d_ws;
  p.out = (float*)d_out;

  // zero the pooled-max key buffer (key 0 < any real key)
  hipMemsetAsync((char*)d_ws + (size_t)OFF_POOL*4, 0, (size_t)13107200*4, stream);
  k_pre  <<<dim3(1),     dim3(256), 0, stream>>>(p);
  k_main <<<dim3(16384), dim3(256), 0, stream>>>(p);
  k_loc  <<<dim3(6400),  dim3(256), 0, stream>>>(p);
  k_final<<<dim3(128),   dim3(256), 0, stream>>>(p);
}

// Round 4
// 3067.819 us; speedup vs baseline: 1.3757x; 1.1971x over previous
//
#include <hip/hip_runtime.h>

#define EPS 1e-5f

// table offsets (floats) within first 64KB of ws
#define OFF_S1   0
#define OFF_T1   800
#define OFF_A    8992
#define OFF_C1   13088
#define OFF_BNJ  13217
#define OFF_BND  13367
#define OFF_BN1  13517
#define OFF_BNL1 14157
#define OFF_BNL2 14413
// byte layout: [0,65536) tables | [65536, +26214400) pool bf16 | part fp32 | chunk bufs
#define POOL_B   65536
#define PART_B   (65536 + 26214400)
#define CH_B     (PART_B + 6553600)
#define OFF_PART2 6569984   // PART_B/4 in floats

typedef unsigned short ushortT;

struct P {
  const float *x,*bn_joint,*jw1,*jb1,*jw2,*jb2,*bn_dif,*dw1,*db1,*dw2,*db2,
    *tw1,*tb1,*tw2,*tb2,*sw1,*sb1,*sw2,*sb2,*g1w,*g1b,*g2w,*g2b,
    *c1w,*c1w1,*c1b1,*bnc1,*c2w,*c2w1,*c2b1,*bnc2,*c3w,*c3w1,*c3b1,*bnc3,
    *lw1,*lb1,*bnl1,*lw2,*lb2,*bnl2,*fcw,*fcb,*hww,*hwb,*pw,*pb,*ls;
  float *ws, *out;
  float* gg;            // g transposed [ic][25u][26v] fp32
  ushortT *h0g, *h1g, *h2g, *poolb;
  int tBase, TC, tcShift, tcWin;
};

__device__ inline unsigned bbits(float x){
  union{float f;unsigned u;} a; a.f = x;
  return ((a.u + 0x7fffu + ((a.u>>16)&1u))>>16) & 0xffffu;
}
__device__ inline ushortT f2b(float x){ return (ushortT)bbits(x); }
__device__ inline float b2f(ushortT b){
  union{unsigned u;float f;} a; a.u = ((unsigned)b)<<16; return a.f;
}
__device__ inline float wlo(unsigned q){ union{unsigned u;float f;} a; a.u = q<<16; return a.f; }
__device__ inline float whi(unsigned q){ union{unsigned u;float f;} a; a.u = q & 0xffff0000u; return a.f; }

__device__ inline void dot4(float& acc, float4 a, float4 b){
  acc += a.x*b.x + a.y*b.y + a.z*b.z + a.w*b.w;
}

__device__ inline void bn_pre(const float* bn, int C, float* dst, int tid){
  for (int c = tid; c < C; c += 256){
    float g = bn[c], b = bn[C+c], m = bn[2*C+c], v = bn[3*C+c];
    float s = g * rsqrtf(v + EPS);
    dst[c] = s; dst[C+c] = b - m*s;
  }
}

__global__ __launch_bounds__(256) void k_pre(P p){
  int tid = threadIdx.x;
  float* ws = p.ws;
  bn_pre(p.bn_joint, 75, ws+OFF_BNJ, tid);
  bn_pre(p.bn_dif,   75, ws+OFF_BND, tid);
  bn_pre(p.bnc1,     64, ws+OFF_BN1, tid);
  bn_pre(p.bnc2,    128, ws+OFF_BN1+128, tid);
  bn_pre(p.bnc3,    128, ws+OFF_BN1+384, tid);
  bn_pre(p.bnl1,    128, ws+OFF_BNL1, tid);
  bn_pre(p.bnl2,    256, ws+OFF_BNL2, tid);
  // fold conv bias into bn offset for gcn layers (same thread wrote both slots)
  if (tid < 64)  ws[OFF_BN1+64+tid]  += ws[OFF_BN1+tid]     * p.c1b1[tid];
  if (tid < 128) ws[OFF_BN1+256+tid] += ws[OFF_BN1+128+tid] * p.c2b1[tid];
  if (tid < 128) ws[OFF_BN1+512+tid] += ws[OFF_BN1+384+tid] * p.c3b1[tid];
  for (int idx = tid; idx < 800; idx += 256){
    int v = idx >> 5, o2 = idx & 31;
    float acc = p.sb2[o2];
    for (int o = 0; o < 64; o++){
      float e = fmaxf(p.sw1[o*25+v] + p.sb1[o], 0.f);
      acc += p.sw2[o2*64+o] * e;
    }
    ws[OFF_S1+idx] = fmaxf(acc, 0.f);
  }
  for (int idx = tid; idx < 8192; idx += 256){
    int o = idx / 64, t = idx % 64;
    float acc = p.tb2[o];
    for (int o1 = 0; o1 < 64; o1++){
      float e = fmaxf(p.tw1[o1*64+t] + p.tb1[o1], 0.f);
      acc += p.tw2[o*64+o1] * e;
    }
    ws[OFF_T1+idx] = fmaxf(acc, 0.f);
  }
  for (int idx = tid; idx < 4096; idx += 256){
    int i = idx / 64, j = idx % 64;
    float acc = 0.f;
    for (int c = 0; c < 128; c++) acc += p.g1w[c*64+i] * p.g2w[c*64+j];
    ws[OFF_A+idx] = acc;
  }
  if (tid < 64){
    float a = 0.f; for (int c = 0; c < 128; c++) a += p.g1b[c]*p.g2w[c*64+tid];
    ws[OFF_C1+tid] = a;
  } else if (tid < 128){
    int j = tid - 64;
    float a = 0.f; for (int c = 0; c < 128; c++) a += p.g2b[c]*p.g1w[c*64+j];
    ws[OFF_C1+64+j] = a;
  } else if (tid == 128){
    float a = 0.f; for (int c = 0; c < 128; c++) a += p.g1b[c]*p.g2b[c];
    ws[OFF_C1+128] = a;
  }
}

// ---------------- k_ea: embed + attention, 128 threads, wave-per-instance ----
__global__ __launch_bounds__(128) void k_ea(P p){
  __shared__ __attribute__((aligned(16))) float P1[2][1700];  // e1p -> Y, stride 68
  __shared__ __attribute__((aligned(16))) float P2[2][1600];  // e1d, stride 64
  __shared__ __attribute__((aligned(16))) float Hh[2][1700];  // h0, stride 68
  __shared__ float SS[2][725];                                 // scores/g, stride 29
  __shared__ float sXc[2][152], sCuv[2][64];
  __shared__ __attribute__((aligned(16))) float sS1[800];
  __shared__ __attribute__((aligned(16))) float sC[132];
  __shared__ float sBnJ[152], sBnD[152];

  int tid = threadIdx.x, bid = blockIdx.x;
  int w = tid >> 6, lane = tid & 63;
  float* ws = p.ws;

  for (int i = tid; i < 800; i += 128) sS1[i] = ws[OFF_S1+i];
  if (tid < 129) sC[tid] = ws[OFF_C1+tid];
  for (int i = tid; i < 150; i += 128){ sBnJ[i] = ws[OFF_BNJ+i]; sBnD[i] = ws[OFF_BND+i]; }
  __syncthreads();

  int ic = bid*2 + w;
  int b  = ic >> p.tcShift;
  int t  = p.tBase + (ic & (p.TC-1));
  int n = b >> 1, m = b & 1;

  // stage x (cur + prev)
  for (int i = lane; i < 150; i += 64){
    int which = (i < 75) ? 0 : 1;
    int j = i - which*75;
    int c = j / 25, vj = j % 25;
    int ts = t - which;
    sXc[w][i] = (ts >= 0) ? p.x[(((n*3+c)*64+ts)*25+vj)*2+m] : 0.f;
  }

  // e1: lane = o
  {
    float jw[3], dw[3];
    #pragma unroll
    for (int c = 0; c < 3; c++){ jw[c] = p.jw1[lane*3+c]; dw[c] = p.dw1[lane*3+c]; }
    float jb = p.jb1[lane], db = p.db1[lane];
    for (int v = 0; v < 25; v++){
      float pa = jb, da = db;
      #pragma unroll
      for (int c = 0; c < 3; c++){
        int ch = c*25+v;
        float xc = sXc[w][ch];
        float y  = sBnJ[ch]*xc + sBnJ[75+ch];
        float d  = (t > 0) ? (xc - sXc[w][75+ch]) : 0.f;
        float yd = sBnD[ch]*d + sBnD[75+ch];
        pa += jw[c]*y;  da += dw[c]*yd;
      }
      P1[w][v*68+lane] = fmaxf(pa, 0.f);
      P2[w][v*64+lane] = fmaxf(da, 0.f);
    }
  }

  // h0: lanes<32 pos-c2, lanes>=32 dif-c2; combine via shfl; spa from table
  {
    int up = lane >> 5, c2 = lane & 31;
    const float* wrow = (up ? p.dw2 : p.jw2) + c2*64;
    float bias = (up ? p.db2 : p.jb2)[c2];
    float4 W[16];
    #pragma unroll
    for (int j = 0; j < 16; j++) W[j] = *(const float4*)&wrow[j*4];
    const float* ebase = up ? &P2[w][0] : &P1[w][0];
    int est = up ? 64 : 68;
    for (int v = 0; v < 25; v++){
      float acc = bias;
      const float* er = ebase + v*est;
      #pragma unroll
      for (int j = 0; j < 16; j++) dot4(acc, W[j], *(const float4*)&er[j*4]);
      float r = fmaxf(acc, 0.f);
      float rr = __shfl_xor(r, 32);
      if (!up) Hh[w][v*68+c2] = r + rr;
      else     Hh[w][v*68+32+c2] = sS1[v*32+c2];
    }
  }

  // Cu (lanes 0..24), Cv (lanes 32..56)
  {
    int r = lane & 31, up = lane >> 5;
    if (r < 25){
      const float* cc = up ? (sC+64) : sC;
      float acc = 0.f;
      #pragma unroll
      for (int j = 0; j < 16; j++)
        dot4(acc, *(const float4*)&cc[j*4], *(const float4*)&Hh[w][r*68+j*4]);
      sCuv[w][lane] = acc;
    }
  }

  // Y[u][i] = (A h_u)[i] -> P1 (lane = i)
  {
    const float* ar = ws + OFF_A + lane*64;
    float4 A[16];
    #pragma unroll
    for (int j = 0; j < 16; j++) A[j] = *(const float4*)&ar[j*4];
    for (int u = 0; u < 25; u++){
      float acc = 0.f;
      #pragma unroll
      for (int j = 0; j < 16; j++) dot4(acc, A[j], *(const float4*)&Hh[w][u*68+j*4]);
      P1[w][u*68+lane] = acc;
    }
  }

  // scores S[v][u]
  {
    int ul = lane & 31, vh = lane >> 5;
    for (int vv = 0; vv < 13; vv++){
      int v = vv + vh*13;
      if (ul < 25 && v < 25){
        float acc = sCuv[w][ul] + sCuv[w][32+v] + sC[128];
        #pragma unroll
        for (int j = 0; j < 16; j++)
          dot4(acc, *(const float4*)&Hh[w][v*68+j*4], *(const float4*)&P1[w][ul*68+j*4]);
        SS[w][v*29+ul] = acc;
      }
    }
  }

  // softmax rows (lane = v)
  if (lane < 25){
    float mx = -1e30f;
    for (int u = 0; u < 25; u++) mx = fmaxf(mx, SS[w][lane*29+u]);
    float s = 0.f;
    for (int u = 0; u < 25; u++){ float e = __expf(SS[w][lane*29+u]-mx); SS[w][lane*29+u] = e; s += e; }
    float inv = 1.f/s;
    for (int u = 0; u < 25; u++) SS[w][lane*29+u] *= inv;
  }

  // write gT [u][26+v] fp32 and h0 bf16
  for (int u = 0; u < 25; u++)
    if (lane < 25) p.gg[(size_t)ic*650 + u*26 + lane] = SS[w][lane*29+u];
  for (int v = 0; v < 25; v++)
    p.h0g[(size_t)ic*1600 + v*64 + lane] = f2b(Hh[w][v*68+lane]);
}

// ---------------- k_g1: gcn1 64->64, 256 threads, 2 instances ---------------
__global__ __launch_bounds__(256) void k_g1(P p){
  __shared__ unsigned Wp[4096];
  __shared__ __attribute__((aligned(16))) float sH[2][1600];
  __shared__ __attribute__((aligned(16))) float sXp[2][1600];
  __shared__ float sG[2][650], sBN[128];

  int tid = threadIdx.x, bid = blockIdx.x;
  float* ws = p.ws;
  for (int i = tid; i < 4096; i += 256){
    int co = i >> 6, c = i & 63;
    Wp[c*64+co] = (bbits(p.c1w1[co*64+c])<<16) | bbits(p.c1w[co*64+c]);
  }
  if (tid < 128) sBN[tid] = ws[OFF_BN1 + tid];
  {
    int ll = tid & 127, inst = tid >> 7;
    size_t ic = (size_t)bid*2 + inst;
    for (int e = ll; e < 1600; e += 128) sH[inst][e] = b2f(p.h0g[ic*1600 + e]);
    for (int e = ll; e < 650;  e += 128) sG[inst][e] = p.gg[ic*650 + e];
  }
  __syncthreads();

  int wave = tid >> 6, lane = tid & 63;
  int inst = wave >> 1, sub = wave & 1;
  size_t ic = (size_t)bid*2 + inst;
  int v0 = sub * 12;   // rows 0..12 / 12..24 (overlap row 12 benign)

  // xp
  {
    float acc[13];
    #pragma unroll
    for (int vv = 0; vv < 13; vv++) acc[vv] = 0.f;
    for (int u = 0; u < 25; u++){
      float h = sH[inst][u*64+lane];
      const float* gr = &sG[inst][u*26+v0];
      #pragma unroll
      for (int vv = 0; vv < 13; vv++) acc[vv] += gr[vv]*h;
    }
    #pragma unroll
    for (int vv = 0; vv < 13; vv++) sXp[inst][(v0+vv)*64+lane] = acc[vv];
  }
  __syncthreads();

  // matmul
  {
    float acc[13];
    #pragma unroll
    for (int vv = 0; vv < 13; vv++) acc[vv] = 0.f;
    for (int c4 = 0; c4 < 16; c4++){
      int cb = c4*4;
      unsigned q0 = Wp[(cb+0)*64+lane], q1 = Wp[(cb+1)*64+lane],
               q2 = Wp[(cb+2)*64+lane], q3 = Wp[(cb+3)*64+lane];
      float w0=wlo(q0),w1=wlo(q1),w2=wlo(q2),w3=wlo(q3);
      float u0=whi(q0),u1=whi(q1),u2=whi(q2),u3=whi(q3);
      #pragma unroll
      for (int vv = 0; vv < 13; vv++){
        float4 x4 = *(const float4*)&sXp[inst][(v0+vv)*64+cb];
        float4 h4 = *(const float4*)&sH [inst][(v0+vv)*64+cb];
        acc[vv] += w0*x4.x + w1*x4.y + w2*x4.z + w3*x4.w
                 + u0*h4.x + u1*h4.y + u2*h4.z + u3*h4.w;
      }
    }
    float s = sBN[lane], o = sBN[64+lane];
    #pragma unroll
    for (int vv = 0; vv < 13; vv++)
      p.h1g[ic*1600 + (v0+vv)*64 + lane] = f2b(fmaxf(s*acc[vv]+o, 0.f));
  }
}

// ---------------- k_g2: gcn2 64->128, 256 threads, 2 instances --------------
__global__ __launch_bounds__(256) void k_g2(P p){
  __shared__ unsigned Wp[8192];
  __shared__ __attribute__((aligned(16))) float sH[2][1600];
  __shared__ __attribute__((aligned(16))) float sXp[2][1600];
  __shared__ float sG[2][650], sBN[256];

  int tid = threadIdx.x, bid = blockIdx.x;
  float* ws = p.ws;
  for (int i = tid; i < 8192; i += 256){
    int co = i >> 6, c = i & 63;
    Wp[c*128+co] = (bbits(p.c2w1[co*64+c])<<16) | bbits(p.c2w[co*64+c]);
  }
  if (tid < 256) sBN[tid] = ws[OFF_BN1 + 128 + tid];
  {
    int ll = tid & 127, inst = tid >> 7;
    size_t ic = (size_t)bid*2 + inst;
    for (int e = ll; e < 1600; e += 128) sH[inst][e] = b2f(p.h1g[ic*1600 + e]);
    for (int e = ll; e < 650;  e += 128) sG[inst][e] = p.gg[ic*650 + e];
  }
  __syncthreads();

  int wave = tid >> 6, lane = tid & 63;
  int inst = wave >> 1, sub = wave & 1;
  size_t ic = (size_t)bid*2 + inst;

  // xp (v-split)
  {
    int v0 = sub * 12;
    float acc[13];
    #pragma unroll
    for (int vv = 0; vv < 13; vv++) acc[vv] = 0.f;
    for (int u = 0; u < 25; u++){
      float h = sH[inst][u*64+lane];
      const float* gr = &sG[inst][u*26+v0];
      #pragma unroll
      for (int vv = 0; vv < 13; vv++) acc[vv] += gr[vv]*h;
    }
    #pragma unroll
    for (int vv = 0; vv < 13; vv++) sXp[inst][(v0+vv)*64+lane] = acc[vv];
  }
  __syncthreads();

  // matmul (co-split), all 25 v
  {
    int co = sub*64 + lane;
    float acc[25];
    #pragma unroll
    for (int v = 0; v < 25; v++) acc[v] = 0.f;
    for (int c4 = 0; c4 < 16; c4++){
      int cb = c4*4;
      unsigned q0 = Wp[(cb+0)*128+co], q1 = Wp[(cb+1)*128+co],
               q2 = Wp[(cb+2)*128+co], q3 = Wp[(cb+3)*128+co];
      float w0=wlo(q0),w1=wlo(q1),w2=wlo(q2),w3=wlo(q3);
      float u0=whi(q0),u1=whi(q1),u2=whi(q2),u3=whi(q3);
      #pragma unroll
      for (int v = 0; v < 25; v++){
        float4 x4 = *(const float4*)&sXp[inst][v*64+cb];
        float4 h4 = *(const float4*)&sH [inst][v*64+cb];
        acc[v] += w0*x4.x + w1*x4.y + w2*x4.z + w3*x4.w
                + u0*h4.x + u1*h4.y + u2*h4.z + u3*h4.w;
      }
    }
    float s = sBN[co], o = sBN[128+co];
    #pragma unroll
    for (int v = 0; v < 25; v++)
      p.h2g[ic*3200 + v*128 + co] = f2b(fmaxf(s*acc[v]+o, 0.f));
  }
}

// ---------------- k_g3: gcn3 128->128 + tem + maxpool(4t), 512 thr ----------
__global__ __launch_bounds__(512) void k_g3(P p){
  __shared__ unsigned Wp[8192];
  __shared__ __attribute__((aligned(16))) float sH2[3200];
  __shared__ __attribute__((aligned(16))) float sXp[3200];
  __shared__ float sG[650], sT[256], sBN[128];

  int tid = threadIdx.x, bid = blockIdx.x;
  float* ws = p.ws;
  int hf = bid & 1, wid = bid >> 1;
  int winPerB = p.TC >> 2;
  int b  = wid >> (p.tcShift - 2);
  int sw = wid & (winPerB - 1);
  int sg = p.tcWin + sw;

  for (int i = tid; i < 8192; i += 512){
    int col = i >> 7, c = i & 127;
    Wp[c*64+col] = (bbits(p.c3w1[(hf*64+col)*128 + c])<<16) | bbits(p.c3w[(hf*64+col)*128 + c]);
  }
  if (tid < 64)        sBN[tid]    = ws[OFF_BN1+384 + hf*64 + tid];
  else if (tid < 128)  sBN[tid]    = ws[OFF_BN1+512 + hf*64 + (tid-64)];
  if (tid < 256){
    int tt = tid >> 6, col = tid & 63;
    sT[tid] = ws[OFF_T1 + (hf*64+col)*64 + (sg*4+tt)];
  }

  int wave = tid >> 6, lane = tid & 63;
  int xc  = ((wave & 1) << 6) + lane;
  int xv0 = (wave >> 1) * 6;
  int mv0 = wave * 3;
  float runmax[4] = {-1e30f,-1e30f,-1e30f,-1e30f};

  for (int tt = 0; tt < 4; tt++){
    int t = sg*4 + tt;
    size_t ic = ((size_t)b << p.tcShift) + (t - p.tBase);
    for (int e = tid; e < 3200; e += 512) sH2[e] = b2f(p.h2g[ic*3200 + e]);
    for (int e = tid; e < 650;  e += 512) sG[e]  = p.gg[ic*650 + e];
    __syncthreads();

    // xp (c via wave&1, v-range via wave>>1; overlaps benign)
    {
      float acc[7];
      #pragma unroll
      for (int vv = 0; vv < 7; vv++) acc[vv] = 0.f;
      for (int u = 0; u < 25; u++){
        float h = sH2[u*128+xc];
        const float* gr = &sG[u*26+xv0];
        #pragma unroll
        for (int vv = 0; vv < 7; vv++) acc[vv] += gr[vv]*h;
      }
      #pragma unroll
      for (int vv = 0; vv < 7; vv++) sXp[(xv0+vv)*128+xc] = acc[vv];
    }
    __syncthreads();

    // matmul: lane = co-col, v-range 3-4 per wave
    {
      float acc[4];
      #pragma unroll
      for (int vv = 0; vv < 4; vv++) acc[vv] = 0.f;
      for (int c4 = 0; c4 < 32; c4++){
        int cb = c4*4;
        unsigned q0 = Wp[(cb+0)*64+lane], q1 = Wp[(cb+1)*64+lane],
                 q2 = Wp[(cb+2)*64+lane], q3 = Wp[(cb+3)*64+lane];
        float w0=wlo(q0),w1=wlo(q1),w2=wlo(q2),w3=wlo(q3);
        float u0=whi(q0),u1=whi(q1),u2=whi(q2),u3=whi(q3);
        #pragma unroll
        for (int vv = 0; vv < 4; vv++){
          float4 x4 = *(const float4*)&sXp[(mv0+vv)*128+cb];
          float4 h4 = *(const float4*)&sH2[(mv0+vv)*128+cb];
          acc[vv] += w0*x4.x + w1*x4.y + w2*x4.z + w3*x4.w
                   + u0*h4.x + u1*h4.y + u2*h4.z + u3*h4.w;
        }
      }
      float s = sBN[lane], o = sBN[64+lane];
      #pragma unroll
      for (int vv = 0; vv < 4; vv++){
        float r = fmaxf(s*acc[vv]+o, 0.f) + sT[tt*64+lane];
        runmax[vv] = fmaxf(runmax[vv], r);
      }
    }
    __syncthreads();
  }
  #pragma unroll
  for (int vv = 0; vv < 4; vv++){
    int v = mv0 + vv;
    p.poolb[(((size_t)b*16 + sg)*25 + v)*128 + hf*64 + lane] = f2b(runmax[vv]);
  }
}

// ---------------- k_loc: per (b, v) ----------------------------------------
__global__ __launch_bounds__(256) void k_loc(P p){
  __shared__ float sIn[128*18];
  __shared__ float sO1[128*16];
  int tid = threadIdx.x, bid = blockIdx.x;
  int b = bid / 25, v = bid % 25;
  float* ws = p.ws;

  for (int i = tid; i < 2304; i += 256) sIn[i] = 0.f;
  __syncthreads();
  for (int i = tid; i < 2048; i += 256){
    int s = i >> 7, ci = i & 127;
    sIn[ci*18 + 1 + s] = b2f(p.poolb[(((size_t)b*16+s)*25+v)*128 + ci]);
  }
  __syncthreads();
  {
    int co = tid >> 1, sh = tid & 1;
    float acc[8];
    float bb = p.lb1[co];
    #pragma unroll
    for (int j = 0; j < 8; j++) acc[j] = bb;
    for (int ci = 0; ci < 128; ci++){
      float r[10];
      #pragma unroll
      for (int j = 0; j < 10; j++) r[j] = sIn[ci*18 + sh*8 + j];
      const float* wr = p.lw1 + (co*128+ci)*3;
      float w0 = wr[0], w1 = wr[1], w2 = wr[2];
      #pragma unroll
      for (int j = 0; j < 8; j++) acc[j] += w0*r[j] + w1*r[j+1] + w2*r[j+2];
    }
    float s1 = ws[OFF_BNL1+co], o1 = ws[OFF_BNL1+128+co];
    #pragma unroll
    for (int j = 0; j < 8; j++) sO1[co*16 + sh*8 + j] = fmaxf(s1*acc[j]+o1, 0.f);
  }
  __syncthreads();
  {
    int co2 = tid;
    float acc[16];
    float bb = p.lb2[co2];
    #pragma unroll
    for (int s = 0; s < 16; s++) acc[s] = bb;
    for (int ci = 0; ci < 128; ci++){
      float w = p.lw2[co2*128+ci];
      const float* orow = sO1 + ci*16;
      #pragma unroll
      for (int s = 0; s < 16; s++) acc[s] += w*orow[s];
    }
    float s2 = ws[OFF_BNL2+co2], o2 = ws[OFF_BNL2+256+co2];
    float psum = 0.f;
    #pragma unroll
    for (int s = 0; s < 16; s++) psum += fmaxf(s2*acc[s]+o2, 0.f);
    ws[OFF_PART2 + (size_t)(b*25+v)*256 + co2] = psum;
  }
}

// ---------------- k_final ---------------------------------------------------
__global__ __launch_bounds__(256) void k_final(P p){
  __shared__ float pool[5*256];
  int tid = threadIdx.x, n = blockIdx.x;
  const float* part = p.ws + OFF_PART2;
  float tot = 0.f, hd = 0.f, hn = 0.f, ft = 0.f, hq = 0.f;
  for (int m2 = 0; m2 < 2; m2++){
    for (int v = 0; v < 25; v++){
      float pv = part[(size_t)((n*2+m2)*25+v)*256 + tid];
      tot += pv;
      unsigned bit = 1u << v;
      if (bit & 0x10000Cu)  hd += pv;
      if (bit & 0x1E00FF0u) hn += pv;
      if (bit & 0xFF000u)   ft += pv;
      if (bit & 0x11007u)   hq += pv;
    }
  }
  pool[tid]      = tot * (1.f/800.f);
  pool[256+tid]  = hd  * (1.f/96.f);
  pool[512+tid]  = hn  * (1.f/384.f);
  pool[768+tid]  = ft  * (1.f/256.f);
  pool[1024+tid] = hq  * (1.f/160.f);
  __syncthreads();
  float* out = p.out;
  for (int o = tid; o < 2620; o += 256){
    const float* wrow; float bias; const float* pl; int off;
    if (o < 60)        { wrow = p.fcw + o*256;            bias = p.fcb[o];        pl = pool;       off = n*60+o; }
    else if (o < 572)  { int j=o-60;   wrow = p.hww + j*256;         bias = p.hwb[j];       pl = pool;       off = 7680   + n*512+j; }
    else if (o < 1084) { int j=o-572;  wrow = p.pw  + j*256;         bias = p.pb[j];        pl = pool+256;   off = 73221  + n*512+j; }
    else if (o < 1596) { int j=o-1084; wrow = p.pw  + (512+j)*256;   bias = p.pb[512+j];    pl = pool+512;   off = 138757 + n*512+j; }
    else if (o < 2108) { int j=o-1596; wrow = p.pw  + (1536+j)*256;  bias = p.pb[1536+j];   pl = pool+1024;  off = 204293 + n*512+j; }
    else               { int j=o-2108; wrow = p.pw  + (1024+j)*256;  bias = p.pb[1024+j];   pl = pool+768;   off = 269829 + n*512+j; }
    float acc = bias;
    for (int c = 0; c < 256; c++) acc += wrow[c]*pl[c];
    out[off] = acc;
  }
  if (n == 0 && tid < 5) out[73216+tid] = p.ls[tid];
}

extern "C" void kernel_launch(void* const* d_in, const int* in_sizes, int n_in,
                              void* d_out, int out_size, void* d_ws, size_t ws_size,
                              hipStream_t stream){
  P p;
  p.x        = (const float*)d_in[0];
  p.bn_joint = (const float*)d_in[1];
  p.jw1      = (const float*)d_in[2];
  p.jb1      = (const float*)d_in[3];
  p.jw2      = (const float*)d_in[4];
  p.jb2      = (const float*)d_in[5];
  p.bn_dif   = (const float*)d_in[6];
  p.dw1      = (const float*)d_in[7];
  p.db1      = (const float*)d_in[8];
  p.dw2      = (const float*)d_in[9];
  p.db2      = (const float*)d_in[10];
  p.tw1      = (const float*)d_in[11];
  p.tb1      = (const float*)d_in[12];
  p.tw2      = (const float*)d_in[13];
  p.tb2      = (const float*)d_in[14];
  p.sw1      = (const float*)d_in[15];
  p.sb1      = (const float*)d_in[16];
  p.sw2      = (const float*)d_in[17];
  p.sb2      = (const float*)d_in[18];
  p.g1w      = (const float*)d_in[19];
  p.g1b      = (const float*)d_in[20];
  p.g2w      = (const float*)d_in[21];
  p.g2b      = (const float*)d_in[22];
  p.c1w      = (const float*)d_in[23];
  p.c1w1     = (const float*)d_in[24];
  p.c1b1     = (const float*)d_in[25];
  p.bnc1     = (const float*)d_in[26];
  p.c2w      = (const float*)d_in[27];
  p.c2w1     = (const float*)d_in[28];
  p.c2b1     = (const float*)d_in[29];
  p.bnc2     = (const float*)d_in[30];
  p.c3w      = (const float*)d_in[31];
  p.c3w1     = (const float*)d_in[32];
  p.c3b1     = (const float*)d_in[33];
  p.bnc3     = (const float*)d_in[34];
  p.lw1      = (const float*)d_in[35];
  p.lb1      = (const float*)d_in[36];
  p.bnl1     = (const float*)d_in[37];
  p.lw2      = (const float*)d_in[38];
  p.lb2      = (const float*)d_in[39];
  p.bnl2     = (const float*)d_in[40];
  p.fcw      = (const float*)d_in[41];
  p.fcb      = (const float*)d_in[42];
  p.hww      = (const float*)d_in[43];
  p.hwb      = (const float*)d_in[44];
  p.pw       = (const float*)d_in[45];
  p.pb       = (const float*)d_in[46];
  p.ls       = (const float*)d_in[47];
  p.ws  = (float*)d_ws;
  p.out = (float*)d_out;

  char* wsb = (char*)d_ws;
  // pick largest T-chunk that fits ws
  int TC = 4;
  for (int c = 1; c <= 16; c <<= 1){
    size_t NIc = (size_t)16384 / c;
    if ((size_t)CH_B + NIc*15400 <= ws_size){ TC = 64/c; break; }
  }
  int C = 64 / TC;
  size_t NI = (size_t)256 * TC;
  p.poolb = (ushortT*)(wsb + POOL_B);
  p.gg    = (float*)(wsb + CH_B);
  p.h0g   = (ushortT*)(wsb + CH_B + NI*2600);
  p.h1g   = p.h0g + NI*1600;
  p.h2g   = p.h1g + NI*1600;
  p.tcShift = __builtin_ctz((unsigned)TC);
  p.TC = TC;

  k_pre<<<dim3(1), dim3(256), 0, stream>>>(p);
  for (int tc = 0; tc < C; tc++){
    p.tBase = tc*TC;
    p.tcWin = tc*(TC>>2);
    k_ea<<<dim3((unsigned)(NI/2)), dim3(128), 0, stream>>>(p);
    k_g1<<<dim3((unsigned)(NI/2)), dim3(256), 0, stream>>>(p);
    k_g2<<<dim3((unsigned)(NI/2)), dim3(256), 0, stream>>>(p);
    k_g3<<<dim3((unsigned)(256*(TC>>2)*2)), dim3(512), 0, stream>>>(p);
  }
  k_loc<<<dim3(6400), dim3(256), 0, stream>>>(p);
  k_final<<<dim3(128), dim3(256), 0, stream>>>(p);
}

// Round 6
// 1373.626 us; speedup vs baseline: 3.0726x; 2.2334x over previous
//
#include <hip/hip_runtime.h>

#define EPS 1e-5f

// table float offsets (first 64KB of ws)
#define OFF_S1   0
#define OFF_T1   800
#define OFF_A    8992
#define OFF_C1   13088
#define OFF_BNJ  13217
#define OFF_BND  13367
#define OFF_BN1  13517      // g1 s64|o64 [0,128) | g2 s128|o128 [128,384) | g3 [384,640)
#define OFF_BNL1 14157
#define OFF_BNL2 14413

// byte layout
#define WB_B     65536                  // 114688 B of fragment-linear bf16 weights
#define POOL_B   196608
#define PART_B   (POOL_B + 26214400)    // 26411008
#define CH_B     (PART_B + 6553600)     // 32964608
#define OFF_PART2 (PART_B/4)

typedef unsigned short ushortT;
typedef float  f32x4 __attribute__((ext_vector_type(4)));
typedef short  s16x8 __attribute__((ext_vector_type(8)));

struct P {
  const float *x,*bn_joint,*jw1,*jb1,*jw2,*jb2,*bn_dif,*dw1,*db1,*dw2,*db2,
    *tw1,*tb1,*tw2,*tb2,*sw1,*sb1,*sw2,*sb2,*g1w,*g1b,*g2w,*g2b,
    *c1w,*c1w1,*c1b1,*bnc1,*c2w,*c2w1,*c2b1,*bnc2,*c3w,*c3w1,*c3b1,*bnc3,
    *lw1,*lb1,*bnl1,*lw2,*lb2,*bnl2,*fcw,*fcb,*hww,*hwb,*pw,*pb,*ls;
  float *ws, *out;
  ushortT *gbg, *h0g, *h1g, *h2g, *poolb;
  int tBase, TC, tcShift;
};

__device__ inline unsigned bbits(float x){
  union{float f;unsigned u;} a; a.f = x;
  return ((a.u + 0x7fffu + ((a.u>>16)&1u))>>16) & 0xffffu;
}
__device__ inline ushortT f2b(float x){ return (ushortT)bbits(x); }
__device__ inline float b2f(ushortT b){
  union{unsigned u;float f;} a; a.u = ((unsigned)b)<<16; return a.f;
}
__device__ inline void dot4(float& acc, float4 a, float4 b){
  acc += a.x*b.x + a.y*b.y + a.z*b.z + a.w*b.w;
}
__device__ inline f32x4 mfma16(s16x8 a, s16x8 b, f32x4 c){
  return __builtin_amdgcn_mfma_f32_16x16x32_bf16(a, b, c, 0, 0, 0);
}

__device__ inline void bn_pre(const float* bn, int C, float* dst, int tid){
  for (int c = tid; c < C; c += 256){
    float g = bn[c], b = bn[C+c], m = bn[2*C+c], v = bn[3*C+c];
    float s = g * rsqrtf(v + EPS);
    dst[c] = s; dst[C+c] = b - m*s;
  }
}

// fragment-linear bf16 weight pack: dst[((tile*KS+kk)*64+lane)*8+j] = src[co][k]
// co = tile*16 + (lane&15), k = kk*32 + (lane>>4)*8 + j
__device__ inline void wb_fill(const float* src, ushortT* dst, int COUT, int CIN, int tid){
  int KS = CIN/32;
  int total = COUT*CIN;
  for (int d = tid; d < total; d += 256){
    int j = d & 7, l = (d>>3) & 63, rest = d >> 9;
    int kk = rest % KS, tile = rest / KS;
    int co = tile*16 + (l & 15);
    int k  = kk*32 + (l >> 4)*8 + j;
    dst[d] = f2b(src[(size_t)co*CIN + k]);
  }
}

__global__ __launch_bounds__(256) void k_pre(P p){
  int tid = threadIdx.x;
  float* ws = p.ws;
  bn_pre(p.bn_joint, 75, ws+OFF_BNJ, tid);
  bn_pre(p.bn_dif,   75, ws+OFF_BND, tid);
  bn_pre(p.bnc1,     64, ws+OFF_BN1, tid);
  bn_pre(p.bnc2,    128, ws+OFF_BN1+128, tid);
  bn_pre(p.bnc3,    128, ws+OFF_BN1+384, tid);
  bn_pre(p.bnl1,    128, ws+OFF_BNL1, tid);
  bn_pre(p.bnl2,    256, ws+OFF_BNL2, tid);
  // fold conv bias into bn offsets (same thread wrote both slots)
  if (tid < 64)  ws[OFF_BN1+64+tid]  += ws[OFF_BN1+tid]     * p.c1b1[tid];
  if (tid < 128) ws[OFF_BN1+256+tid] += ws[OFF_BN1+128+tid] * p.c2b1[tid];
  if (tid < 128) ws[OFF_BN1+512+tid] += ws[OFF_BN1+384+tid] * p.c3b1[tid];
  // fragment-linear weights
  ushortT* wb = (ushortT*)((char*)ws + WB_B);
  wb_fill(p.c1w,  wb + 0,     64, 64, tid);
  wb_fill(p.c1w1, wb + 4096,  64, 64, tid);
  wb_fill(p.c2w,  wb + 8192, 128, 64, tid);
  wb_fill(p.c2w1, wb + 16384,128, 64, tid);
  wb_fill(p.c3w,  wb + 24576,128,128, tid);
  wb_fill(p.c3w1, wb + 40960,128,128, tid);
  for (int idx = tid; idx < 800; idx += 256){
    int v = idx >> 5, o2 = idx & 31;
    float acc = p.sb2[o2];
    for (int o = 0; o < 64; o++){
      float e = fmaxf(p.sw1[o*25+v] + p.sb1[o], 0.f);
      acc += p.sw2[o2*64+o] * e;
    }
    ws[OFF_S1+idx] = fmaxf(acc, 0.f);
  }
  for (int idx = tid; idx < 8192; idx += 256){
    int o = idx / 64, t = idx % 64;
    float acc = p.tb2[o];
    for (int o1 = 0; o1 < 64; o1++){
      float e = fmaxf(p.tw1[o1*64+t] + p.tb1[o1], 0.f);
      acc += p.tw2[o*64+o1] * e;
    }
    ws[OFF_T1+idx] = fmaxf(acc, 0.f);
  }
  for (int idx = tid; idx < 4096; idx += 256){
    int i = idx / 64, j = idx % 64;
    float acc = 0.f;
    for (int c = 0; c < 128; c++) acc += p.g1w[c*64+i] * p.g2w[c*64+j];
    ws[OFF_A+idx] = acc;
  }
  if (tid < 64){
    float a = 0.f; for (int c = 0; c < 128; c++) a += p.g1b[c]*p.g2w[c*64+tid];
    ws[OFF_C1+tid] = a;
  } else if (tid < 128){
    int j = tid - 64;
    float a = 0.f; for (int c = 0; c < 128; c++) a += p.g2b[c]*p.g1w[c*64+j];
    ws[OFF_C1+64+j] = a;
  } else if (tid == 128){
    float a = 0.f; for (int c = 0; c < 128; c++) a += p.g1b[c]*p.g2b[c];
    ws[OFF_C1+128] = a;
  }
}

// ---------------- k_ea: embed + attention, 128 threads, wave-per-instance ----
__global__ __launch_bounds__(128) void k_ea(P p){
  __shared__ __attribute__((aligned(16))) float P1[2][1700];
  __shared__ __attribute__((aligned(16))) float P2[2][1600];
  __shared__ __attribute__((aligned(16))) float Hh[2][1700];
  __shared__ float SS[2][725];
  __shared__ float sXc[2][152], sCuv[2][64];
  __shared__ __attribute__((aligned(16))) float sS1[800];
  __shared__ __attribute__((aligned(16))) float sC[132];
  __shared__ float sBnJ[152], sBnD[152];

  int tid = threadIdx.x, bid = blockIdx.x;
  int w = tid >> 6, lane = tid & 63;
  float* ws = p.ws;

  for (int i = tid; i < 800; i += 128) sS1[i] = ws[OFF_S1+i];
  if (tid < 129) sC[tid] = ws[OFF_C1+tid];
  for (int i = tid; i < 150; i += 128){ sBnJ[i] = ws[OFF_BNJ+i]; sBnD[i] = ws[OFF_BND+i]; }
  __syncthreads();

  int ic = bid*2 + w;
  int b  = ic >> p.tcShift;
  int t  = p.tBase + (ic & (p.TC-1));
  int n = b >> 1, m = b & 1;

  for (int i = lane; i < 150; i += 64){
    int which = (i < 75) ? 0 : 1;
    int j = i - which*75;
    int c = j / 25, vj = j % 25;
    int ts = t - which;
    sXc[w][i] = (ts >= 0) ? p.x[(((n*3+c)*64+ts)*25+vj)*2+m] : 0.f;
  }

  {
    float jw[3], dw[3];
    #pragma unroll
    for (int c = 0; c < 3; c++){ jw[c] = p.jw1[lane*3+c]; dw[c] = p.dw1[lane*3+c]; }
    float jb = p.jb1[lane], db = p.db1[lane];
    for (int v = 0; v < 25; v++){
      float pa = jb, da = db;
      #pragma unroll
      for (int c = 0; c < 3; c++){
        int ch = c*25+v;
        float xc = sXc[w][ch];
        float y  = sBnJ[ch]*xc + sBnJ[75+ch];
        float d  = (t > 0) ? (xc - sXc[w][75+ch]) : 0.f;
        float yd = sBnD[ch]*d + sBnD[75+ch];
        pa += jw[c]*y;  da += dw[c]*yd;
      }
      P1[w][v*68+lane] = fmaxf(pa, 0.f);
      P2[w][v*64+lane] = fmaxf(da, 0.f);
    }
  }

  {
    int up = lane >> 5, c2 = lane & 31;
    const float* wrow = (up ? p.dw2 : p.jw2) + c2*64;
    float bias = (up ? p.db2 : p.jb2)[c2];
    float4 W[16];
    #pragma unroll
    for (int j = 0; j < 16; j++) W[j] = *(const float4*)&wrow[j*4];
    const float* ebase = up ? &P2[w][0] : &P1[w][0];
    int est = up ? 64 : 68;
    for (int v = 0; v < 25; v++){
      float acc = bias;
      const float* er = ebase + v*est;
      #pragma unroll
      for (int j = 0; j < 16; j++) dot4(acc, W[j], *(const float4*)&er[j*4]);
      float r = fmaxf(acc, 0.f);
      float rr = __shfl_xor(r, 32);
      if (!up) Hh[w][v*68+c2] = r + rr;
      else     Hh[w][v*68+32+c2] = sS1[v*32+c2];
    }
  }

  {
    int r = lane & 31, up = lane >> 5;
    if (r < 25){
      const float* cc = up ? (sC+64) : sC;
      float acc = 0.f;
      #pragma unroll
      for (int j = 0; j < 16; j++)
        dot4(acc, *(const float4*)&cc[j*4], *(const float4*)&Hh[w][r*68+j*4]);
      sCuv[w][lane] = acc;
    }
  }

  {
    const float* ar = ws + OFF_A + lane*64;
    float4 A[16];
    #pragma unroll
    for (int j = 0; j < 16; j++) A[j] = *(const float4*)&ar[j*4];
    for (int u = 0; u < 25; u++){
      float acc = 0.f;
      #pragma unroll
      for (int j = 0; j < 16; j++) dot4(acc, A[j], *(const float4*)&Hh[w][u*68+j*4]);
      P1[w][u*68+lane] = acc;
    }
  }

  {
    int ul = lane & 31, vh = lane >> 5;
    for (int vv = 0; vv < 13; vv++){
      int v = vv + vh*13;
      if (ul < 25 && v < 25){
        float acc = sCuv[w][ul] + sCuv[w][32+v] + sC[128];
        #pragma unroll
        for (int j = 0; j < 16; j++)
          dot4(acc, *(const float4*)&Hh[w][v*68+j*4], *(const float4*)&P1[w][ul*68+j*4]);
        SS[w][v*29+ul] = acc;
      }
    }
  }

  if (lane < 25){
    float mx = -1e30f;
    for (int u = 0; u < 25; u++) mx = fmaxf(mx, SS[w][lane*29+u]);
    float s = 0.f;
    for (int u = 0; u < 25; u++){ float e = __expf(SS[w][lane*29+u]-mx); SS[w][lane*29+u] = e; s += e; }
    float inv = 1.f/s;
    for (int u = 0; u < 25; u++) SS[w][lane*29+u] *= inv;
  }

  // g bf16 hi/lo planes [ic][2][32v][32u], zeros outside 25x25
  {
    unsigned* gw = (unsigned*)p.gbg;
    for (int i = lane; i < 512; i += 64){
      int row = i >> 4, up = i & 15;
      int u0 = up*2, u1 = u0+1;
      float g0 = (row < 25 && u0 < 25) ? SS[w][row*29+u0] : 0.f;
      float g1 = (row < 25 && u1 < 25) ? SS[w][row*29+u1] : 0.f;
      unsigned b0 = bbits(g0), b1 = bbits(g1);
      float r0 = g0 - b2f((ushortT)b0), r1 = g1 - b2f((ushortT)b1);
      gw[((size_t)ic*2 + 0)*512 + row*16 + up] = b0 | (b1<<16);
      gw[((size_t)ic*2 + 1)*512 + row*16 + up] = bbits(r0) | (bbits(r1)<<16);
    }
  }
  for (int v = 0; v < 25; v++)
    p.h0g[(size_t)ic*1600 + v*64 + lane] = f2b(Hh[w][v*68+lane]);
}

// ---------------- k_gcn: MFMA gcn layer (role-swapped operands) --------------
// Z^T[co][v] = W1.h^T + Y^T.g^T ; Y^T = (h.W^T)^T, hi/lo split via LDS.
// 256 thr = 4 waves, wave = instance. POOL: +tem, 4-t maxpool across waves.
template<int CIN, int COUT, int POOL>
__global__ __launch_bounds__(256) void k_gcn(P p, const ushortT* __restrict__ hin,
    const ushortT* __restrict__ WB, const ushortT* __restrict__ W1B,
    ushortT* __restrict__ hout, int bnOff){
  constexpr int KS = CIN/32;
  constexpr int SECS = COUT/64;
  __shared__ ushortT YT[4*2*2560];              // [wave][plane][co*40+u]
  __shared__ float sBN[2*COUT];
  __shared__ ushortT PS[POOL ? 4*32*64 : 2];
  __shared__ float sTM[POOL ? 512 : 1];

  int tid = threadIdx.x;
  int wave = tid >> 6, lane = tid & 63;
  int l15 = lane & 15, l4 = lane >> 4;
  int ic0 = blockIdx.x * 4;
  size_t ic = (size_t)ic0 + wave;

  for (int i = tid; i < 2*COUT; i += 256) sBN[i] = p.ws[bnOff + i];
  if (POOL){
    int t0 = p.tBase + (ic0 & (p.TC-1));
    for (int i = tid; i < 512; i += 256){
      int tt = i >> 7, co = i & 127;
      sTM[i] = p.ws[OFF_T1 + co*64 + t0 + tt];
    }
  }
  __syncthreads();

  // h fragments: dual-use (A of Y-GEMM rows u, B of Z-GEMM cols v). mask v>=25.
  s16x8 hf[2][KS];
  #pragma unroll
  for (int nt = 0; nt < 2; nt++){
    int v = nt*16 + l15;
    const ushortT* hr = hin + ((size_t)ic*25 + (v < 25 ? v : 0))*CIN + l4*8;
    #pragma unroll
    for (int kk = 0; kk < KS; kk++){
      s16x8 tv = *(const s16x8*)(hr + kk*32);
      s16x8 z = {0,0,0,0,0,0,0,0};
      hf[nt][kk] = (v < 25) ? tv : z;
    }
  }
  // g fragments hi/lo: B[k=u][n=v] = g[v][u]
  s16x8 gf[2][2];
  #pragma unroll
  for (int pl = 0; pl < 2; pl++)
    #pragma unroll
    for (int nt = 0; nt < 2; nt++)
      gf[pl][nt] = *(const s16x8*)(p.gbg + ((size_t)ic*2 + pl)*1024 + (size_t)(nt*16 + l15)*32 + l4*8);

  ushortT* myYT = &YT[wave*5120];

  for (int sec = 0; sec < SECS; sec++){
    // ---- Y-GEMM: A = hf (rows u), B = W frags (cols co) -> accY[ut][mt]
    f32x4 accY[2][4];
    #pragma unroll
    for (int ut = 0; ut < 2; ut++)
      #pragma unroll
      for (int mt = 0; mt < 4; mt++) accY[ut][mt] = (f32x4){0.f,0.f,0.f,0.f};
    #pragma unroll
    for (int kk = 0; kk < KS; kk++){
      #pragma unroll
      for (int mt = 0; mt < 4; mt++){
        s16x8 bw = *(const s16x8*)(WB + ((size_t)((sec*4+mt)*KS + kk)*64 + lane)*8);
        accY[0][mt] = mfma16(hf[0][kk], bw, accY[0][mt]);
        accY[1][mt] = mfma16(hf[1][kk], bw, accY[1][mt]);
      }
    }
    // pack Y^T hi/lo into LDS: [co][u], rows u contiguous per lane (uint2)
    #pragma unroll
    for (int ut = 0; ut < 2; ut++){
      #pragma unroll
      for (int mt = 0; mt < 4; mt++){
        unsigned h0 = bbits(accY[ut][mt][0]), h1 = bbits(accY[ut][mt][1]);
        unsigned h2 = bbits(accY[ut][mt][2]), h3 = bbits(accY[ut][mt][3]);
        float l0 = accY[ut][mt][0] - b2f((ushortT)h0);
        float l1 = accY[ut][mt][1] - b2f((ushortT)h1);
        float l2 = accY[ut][mt][2] - b2f((ushortT)h2);
        float l3 = accY[ut][mt][3] - b2f((ushortT)h3);
        int base = (mt*16 + l15)*40 + ut*16 + l4*4;
        uint2 hi, lo;
        hi.x = h0 | (h1<<16);  hi.y = h2 | (h3<<16);
        lo.x = bbits(l0) | (bbits(l1)<<16);  lo.y = bbits(l2) | (bbits(l3)<<16);
        *(uint2*)&myYT[base] = hi;
        *(uint2*)&myYT[2560 + base] = lo;
      }
    }
    // ---- Z-GEMM: A = W1 frags (rows co), B = hf (cols v) -> accZ[mt][nt]
    f32x4 accZ[4][2];
    #pragma unroll
    for (int mt = 0; mt < 4; mt++)
      #pragma unroll
      for (int nt = 0; nt < 2; nt++) accZ[mt][nt] = (f32x4){0.f,0.f,0.f,0.f};
    #pragma unroll
    for (int kk = 0; kk < KS; kk++){
      #pragma unroll
      for (int mt = 0; mt < 4; mt++){
        s16x8 aw = *(const s16x8*)(W1B + ((size_t)((sec*4+mt)*KS + kk)*64 + lane)*8);
        accZ[mt][0] = mfma16(aw, hf[0][kk], accZ[mt][0]);
        accZ[mt][1] = mfma16(aw, hf[1][kk], accZ[mt][1]);
      }
    }
    // ---- g-MFMA: accZ += Y^T . g^T (3-term hi/lo)
    #pragma unroll
    for (int mt = 0; mt < 4; mt++){
      s16x8 ah = *(const s16x8*)&myYT[(mt*16 + l15)*40 + l4*8];
      s16x8 al = *(const s16x8*)&myYT[2560 + (mt*16 + l15)*40 + l4*8];
      #pragma unroll
      for (int nt = 0; nt < 2; nt++){
        accZ[mt][nt] = mfma16(ah, gf[0][nt], accZ[mt][nt]);
        accZ[mt][nt] = mfma16(ah, gf[1][nt], accZ[mt][nt]);
        accZ[mt][nt] = mfma16(al, gf[0][nt], accZ[mt][nt]);
      }
    }
    // ---- epilogue: bn+relu (+tem / store). C layout: col v = l15, rows co.
    #pragma unroll
    for (int mt = 0; mt < 4; mt++){
      #pragma unroll
      for (int nt = 0; nt < 2; nt++){
        int co0 = sec*64 + mt*16 + l4*4;
        int v = nt*16 + l15;
        float z[4];
        #pragma unroll
        for (int r = 0; r < 4; r++)
          z[r] = fmaxf(sBN[co0+r]*accZ[mt][nt][r] + sBN[COUT+co0+r], 0.f);
        if (POOL){
          #pragma unroll
          for (int r = 0; r < 4; r++) z[r] += sTM[wave*128 + co0 + r];
          uint2 pk;
          pk.x = bbits(z[0]) | (bbits(z[1])<<16);
          pk.y = bbits(z[2]) | (bbits(z[3])<<16);
          *(uint2*)&PS[(wave*32 + v)*64 + (mt*16 + l4*4)] = pk;
        } else if (v < 25){
          uint2 pk;
          pk.x = bbits(z[0]) | (bbits(z[1])<<16);
          pk.y = bbits(z[2]) | (bbits(z[3])<<16);
          *(uint2*)&hout[((size_t)ic*25 + v)*COUT + co0] = pk;
        }
      }
    }
    if (POOL){
      __syncthreads();
      int b  = ic0 >> p.tcShift;
      int sg = (p.tBase + (ic0 & (p.TC-1))) >> 2;
      for (int i = tid; i < 1600; i += 256){
        int v = i >> 6, co = i & 63;
        float mx = b2f(PS[(0*32+v)*64+co]);
        mx = fmaxf(mx, b2f(PS[(1*32+v)*64+co]));
        mx = fmaxf(mx, b2f(PS[(2*32+v)*64+co]));
        mx = fmaxf(mx, b2f(PS[(3*32+v)*64+co]));
        p.poolb[(((size_t)b*16+sg)*25+v)*128 + sec*64 + co] = f2b(mx);
      }
      if (sec+1 < SECS) __syncthreads();
    }
  }
}

// ---------------- k_loc: per (b, v) ----------------------------------------
__global__ __launch_bounds__(256) void k_loc(P p){
  __shared__ float sIn[128*18];
  __shared__ float sO1[128*16];
  int tid = threadIdx.x, bid = blockIdx.x;
  int b = bid / 25, v = bid % 25;
  float* ws = p.ws;

  for (int i = tid; i < 2304; i += 256) sIn[i] = 0.f;
  __syncthreads();
  for (int i = tid; i < 2048; i += 256){
    int s = i >> 7, ci = i & 127;
    sIn[ci*18 + 1 + s] = b2f(p.poolb[(((size_t)b*16+s)*25+v)*128 + ci]);
  }
  __syncthreads();
  {
    int co = tid >> 1, sh = tid & 1;
    float acc[8];
    float bb = p.lb1[co];
    #pragma unroll
    for (int j = 0; j < 8; j++) acc[j] = bb;
    for (int ci = 0; ci < 128; ci++){
      float r[10];
      #pragma unroll
      for (int j = 0; j < 10; j++) r[j] = sIn[ci*18 + sh*8 + j];
      const float* wr = p.lw1 + (co*128+ci)*3;
      float w0 = wr[0], w1 = wr[1], w2 = wr[2];
      #pragma unroll
      for (int j = 0; j < 8; j++) acc[j] += w0*r[j] + w1*r[j+1] + w2*r[j+2];
    }
    float s1 = ws[OFF_BNL1+co], o1 = ws[OFF_BNL1+128+co];
    #pragma unroll
    for (int j = 0; j < 8; j++) sO1[co*16 + sh*8 + j] = fmaxf(s1*acc[j]+o1, 0.f);
  }
  __syncthreads();
  {
    int co2 = tid;
    float acc[16];
    float bb = p.lb2[co2];
    #pragma unroll
    for (int s = 0; s < 16; s++) acc[s] = bb;
    for (int ci = 0; ci < 128; ci++){
      float w = p.lw2[co2*128+ci];
      const float* orow = sO1 + ci*16;
      #pragma unroll
      for (int s = 0; s < 16; s++) acc[s] += w*orow[s];
    }
    float s2 = ws[OFF_BNL2+co2], o2 = ws[OFF_BNL2+256+co2];
    float psum = 0.f;
    #pragma unroll
    for (int s = 0; s < 16; s++) psum += fmaxf(s2*acc[s]+o2, 0.f);
    ws[OFF_PART2 + (size_t)(b*25+v)*256 + co2] = psum;
  }
}

// ---------------- k_final ---------------------------------------------------
__global__ __launch_bounds__(256) void k_final(P p){
  __shared__ float pool[5*256];
  int tid = threadIdx.x, n = blockIdx.x;
  const float* part = p.ws + OFF_PART2;
  float tot = 0.f, hd = 0.f, hn = 0.f, ft = 0.f, hq = 0.f;
  for (int m2 = 0; m2 < 2; m2++){
    for (int v = 0; v < 25; v++){
      float pv = part[(size_t)((n*2+m2)*25+v)*256 + tid];
      tot += pv;
      unsigned bit = 1u << v;
      if (bit & 0x10000Cu)  hd += pv;
      if (bit & 0x1E00FF0u) hn += pv;
      if (bit & 0xFF000u)   ft += pv;
      if (bit & 0x11007u)   hq += pv;
    }
  }
  pool[tid]      = tot * (1.f/800.f);
  pool[256+tid]  = hd  * (1.f/96.f);
  pool[512+tid]  = hn  * (1.f/384.f);
  pool[768+tid]  = ft  * (1.f/256.f);
  pool[1024+tid] = hq  * (1.f/160.f);
  __syncthreads();
  float* out = p.out;
  for (int o = tid; o < 2620; o += 256){
    const float* wrow; float bias; const float* pl; int off;
    if (o < 60)        { wrow = p.fcw + o*256;            bias = p.fcb[o];        pl = pool;       off = n*60+o; }
    else if (o < 572)  { int j=o-60;   wrow = p.hww + j*256;         bias = p.hwb[j];       pl = pool;       off = 7680   + n*512+j; }
    else if (o < 1084) { int j=o-572;  wrow = p.pw  + j*256;         bias = p.pb[j];        pl = pool+256;   off = 73221  + n*512+j; }
    else if (o < 1596) { int j=o-1084; wrow = p.pw  + (512+j)*256;   bias = p.pb[512+j];    pl = pool+512;   off = 138757 + n*512+j; }
    else if (o < 2108) { int j=o-1596; wrow = p.pw  + (1536+j)*256;  bias = p.pb[1536+j];   pl = pool+1024;  off = 204293 + n*512+j; }
    else               { int j=o-2108; wrow = p.pw  + (1024+j)*256;  bias = p.pb[1024+j];   pl = pool+768;   off = 269829 + n*512+j; }
    float acc = bias;
    for (int c = 0; c < 256; c++) acc += wrow[c]*pl[c];
    out[off] = acc;
  }
  if (n == 0 && tid < 5) out[73216+tid] = p.ls[tid];
}

extern "C" void kernel_launch(void* const* d_in, const int* in_sizes, int n_in,
                              void* d_out, int out_size, void* d_ws, size_t ws_size,
                              hipStream_t stream){
  P p;
  p.x        = (const float*)d_in[0];
  p.bn_joint = (const float*)d_in[1];
  p.jw1      = (const float*)d_in[2];
  p.jb1      = (const float*)d_in[3];
  p.jw2      = (const float*)d_in[4];
  p.jb2      = (const float*)d_in[5];
  p.bn_dif   = (const float*)d_in[6];
  p.dw1      = (const float*)d_in[7];
  p.db1      = (const float*)d_in[8];
  p.dw2      = (const float*)d_in[9];
  p.db2      = (const float*)d_in[10];
  p.tw1      = (const float*)d_in[11];
  p.tb1      = (const float*)d_in[12];
  p.tw2      = (const float*)d_in[13];
  p.tb2      = (const float*)d_in[14];
  p.sw1      = (const float*)d_in[15];
  p.sb1      = (const float*)d_in[16];
  p.sw2      = (const float*)d_in[17];
  p.sb2      = (const float*)d_in[18];
  p.g1w      = (const float*)d_in[19];
  p.g1b      = (const float*)d_in[20];
  p.g2w      = (const float*)d_in[21];
  p.g2b      = (const float*)d_in[22];
  p.c1w      = (const float*)d_in[23];
  p.c1w1     = (const float*)d_in[24];
  p.c1b1     = (const float*)d_in[25];
  p.bnc1     = (const float*)d_in[26];
  p.c2w      = (const float*)d_in[27];
  p.c2w1     = (const float*)d_in[28];
  p.c2b1     = (const float*)d_in[29];
  p.bnc2     = (const float*)d_in[30];
  p.c3w      = (const float*)d_in[31];
  p.c3w1     = (const float*)d_in[32];
  p.c3b1     = (const float*)d_in[33];
  p.bnc3     = (const float*)d_in[34];
  p.lw1      = (const float*)d_in[35];
  p.lb1      = (const float*)d_in[36];
  p.bnl1     = (const float*)d_in[37];
  p.lw2      = (const float*)d_in[38];
  p.lb2      = (const float*)d_in[39];
  p.bnl2     = (const float*)d_in[40];
  p.fcw      = (const float*)d_in[41];
  p.fcb      = (const float*)d_in[42];
  p.hww      = (const float*)d_in[43];
  p.hwb      = (const float*)d_in[44];
  p.pw       = (const float*)d_in[45];
  p.pb       = (const float*)d_in[46];
  p.ls       = (const float*)d_in[47];
  p.ws  = (float*)d_ws;
  p.out = (float*)d_out;

  char* wsb = (char*)d_ws;
  // pick largest T-chunk that fits ws (per-instance: g 4096B + h0 3200 + h1 3200 + h2 6400)
  int TC = 4;
  for (int c = 1; c <= 16; c <<= 1){
    size_t NIc = (size_t)16384 / c;
    if ((size_t)CH_B + NIc*16896 <= ws_size){ TC = 64/c; break; }
  }
  int C = 64 / TC;
  size_t NI = (size_t)256 * TC;
  p.poolb = (ushortT*)(wsb + POOL_B);
  p.gbg   = (ushortT*)(wsb + CH_B);
  p.h0g   = (ushortT*)(wsb + CH_B + NI*4096);
  p.h1g   = p.h0g + NI*1600;
  p.h2g   = p.h1g + NI*1600;
  p.tcShift = __builtin_ctz((unsigned)TC);
  p.TC = TC;
  ushortT* WBp = (ushortT*)(wsb + WB_B);

  k_pre<<<dim3(1), dim3(256), 0, stream>>>(p);
  for (int tc = 0; tc < C; tc++){
    p.tBase = tc*TC;
    k_ea<<<dim3((unsigned)(NI/2)), dim3(128), 0, stream>>>(p);
    k_gcn<64,64,0>  <<<dim3((unsigned)(NI/4)), dim3(256), 0, stream>>>(p, p.h0g, WBp+0,     WBp+4096,  p.h1g, OFF_BN1);
    k_gcn<64,128,0> <<<dim3((unsigned)(NI/4)), dim3(256), 0, stream>>>(p, p.h1g, WBp+8192,  WBp+16384, p.h2g, OFF_BN1+128);
    k_gcn<128,128,1><<<dim3((unsigned)(NI/4)), dim3(256), 0, stream>>>(p, p.h2g, WBp+24576, WBp+40960, p.h2g, OFF_BN1+384);
  }
  k_loc  <<<dim3(6400), dim3(256), 0, stream>>>(p);
  k_final<<<dim3(128),  dim3(256), 0, stream>>>(p);
}

// Round 7
// 978.619 us; speedup vs baseline: 4.3127x; 1.4036x over previous
//
#include <hip/hip_runtime.h>

#define EPS 1e-5f

// table float offsets
#define OFF_S1   0
#define OFF_T1   800
#define OFF_A    8992
#define OFF_C1   13088
#define OFF_BNJ  13217
#define OFF_BND  13367
#define OFF_BN1  13517      // g1 s64|o64 | g2 s128|o128 | g3 s128|o128
#define OFF_BNL1 14157
#define OFF_BNL2 14413
#define OFF_TMT  16384      // [64t][128co] f32

// byte layout
#define WF_B     98304                    // fragment-linear bf16 weights (278528 B)
#define POOL_B   376832
#define PART_B   (POOL_B + 26214400)      // 26591232
#define CH_B     (PART_B + 6553600)       // 33144832
#define OFF_PART2 (PART_B/4)

// WF half-offsets
#define WF_W1   0
#define WF_W1B  4096
#define WF_W2   8192
#define WF_W2B  16384
#define WF_W3   24576
#define WF_W3B  40960
#define WF_LW1  57344
#define WF_LW2  106496

typedef unsigned short ushortT;
typedef float  f32x4 __attribute__((ext_vector_type(4)));
typedef short  s16x8 __attribute__((ext_vector_type(8)));

struct P {
  const float *x,*bn_joint,*jw1,*jb1,*jw2,*jb2,*bn_dif,*dw1,*db1,*dw2,*db2,
    *tw1,*tb1,*tw2,*tb2,*sw1,*sb1,*sw2,*sb2,*g1w,*g1b,*g2w,*g2b,
    *c1w,*c1w1,*c1b1,*bnc1,*c2w,*c2w1,*c2b1,*bnc2,*c3w,*c3w1,*c3b1,*bnc3,
    *lw1,*lb1,*bnl1,*lw2,*lb2,*bnl2,*fcw,*fcb,*hww,*hwb,*pw,*pb,*ls;
  float *ws, *out;
  const ushortT* wf;
  ushortT *gbg, *h0g, *poolb;
  int tBase, TC, tcShift;
};

__device__ inline unsigned bbits(float x){
  union{float f;unsigned u;} a; a.f = x;
  return ((a.u + 0x7fffu + ((a.u>>16)&1u))>>16) & 0xffffu;
}
__device__ inline ushortT f2b(float x){ return (ushortT)bbits(x); }
__device__ inline float b2f(ushortT b){
  union{unsigned u;float f;} a; a.u = ((unsigned)b)<<16; return a.f;
}
__device__ inline void dot4(float& acc, float4 a, float4 b){
  acc += a.x*b.x + a.y*b.y + a.z*b.z + a.w*b.w;
}
__device__ inline f32x4 mfma16(s16x8 a, s16x8 b, f32x4 c){
  return __builtin_amdgcn_mfma_f32_16x16x32_bf16(a, b, c, 0, 0, 0);
}

__device__ inline void bn_pre(const float* bn, int C, float* dst, int tid){
  for (int c = tid; c < C; c += 256){
    float g = bn[c], b = bn[C+c], m = bn[2*C+c], v = bn[3*C+c];
    float s = g * rsqrtf(v + EPS);
    dst[c] = s; dst[C+c] = b - m*s;
  }
}

// fragment-linear pack: dst[((tile*KS+kk)*64+l)*8+j] = src[tile*16+(l&15)][kk*32+(l>>4)*8+j]
__device__ inline void wb_fill(const float* src, ushortT* dst, int COUT, int CIN, int tid){
  int KS = CIN/32;
  int total = COUT*CIN;
  for (int d = tid; d < total; d += 256){
    int j = d & 7, l = (d>>3) & 63, rest = d >> 9;
    int kk = rest % KS, tile = rest / KS;
    int co = tile*16 + (l & 15);
    int k  = kk*32 + (l >> 4)*8 + j;
    dst[d] = f2b(src[(size_t)co*CIN + k]);
  }
}

__global__ __launch_bounds__(256) void k_pre(P p){
  int tid = threadIdx.x;
  float* ws = p.ws;
  bn_pre(p.bn_joint, 75, ws+OFF_BNJ, tid);
  bn_pre(p.bn_dif,   75, ws+OFF_BND, tid);
  bn_pre(p.bnc1,     64, ws+OFF_BN1, tid);
  bn_pre(p.bnc2,    128, ws+OFF_BN1+128, tid);
  bn_pre(p.bnc3,    128, ws+OFF_BN1+384, tid);
  bn_pre(p.bnl1,    128, ws+OFF_BNL1, tid);
  bn_pre(p.bnl2,    256, ws+OFF_BNL2, tid);
  // fold conv biases into bn offsets (same thread wrote both slots)
  if (tid < 64)  ws[OFF_BN1+64+tid]  += ws[OFF_BN1+tid]     * p.c1b1[tid];
  if (tid < 128) ws[OFF_BN1+256+tid] += ws[OFF_BN1+128+tid] * p.c2b1[tid];
  if (tid < 128) ws[OFF_BN1+512+tid] += ws[OFF_BN1+384+tid] * p.c3b1[tid];
  if (tid < 128) ws[OFF_BNL1+128+tid] += ws[OFF_BNL1+tid] * p.lb1[tid];
  if (tid < 256) ws[OFF_BNL2+256+tid] += ws[OFF_BNL2+tid] * p.lb2[tid];

  ushortT* wf = (ushortT*)((char*)ws + WF_B);
  wb_fill(p.c1w,  wf + WF_W1,  64, 64, tid);
  wb_fill(p.c1w1, wf + WF_W1B, 64, 64, tid);
  wb_fill(p.c2w,  wf + WF_W2, 128, 64, tid);
  wb_fill(p.c2w1, wf + WF_W2B,128, 64, tid);
  wb_fill(p.c3w,  wf + WF_W3, 128,128, tid);
  wb_fill(p.c3w1, wf + WF_W3B,128,128, tid);
  // lw1: (128co,128ci,3d) -> [((d*4+kk)*8+ct)*512 + l*8 + j]
  for (int d_ = tid; d_ < 49152; d_ += 256){
    int j = d_ & 7, l = (d_>>3) & 63, rest = d_ >> 9;
    int ct = rest & 7, kk = (rest>>3) & 3, d = rest>>5;
    int co = ct*16 + (l & 15);
    int ci = kk*32 + (l>>4)*8 + j;
    wf[WF_LW1 + d_] = f2b(p.lw1[(size_t)co*384 + ci*3 + d]);
  }
  // lw2: (256co,128ci) -> [(kk*16+ct)*512 + l*8 + j]
  for (int d_ = tid; d_ < 32768; d_ += 256){
    int j = d_ & 7, l = (d_>>3) & 63, rest = d_ >> 9;
    int ct = rest & 15, kk = rest >> 4;
    int co = ct*16 + (l & 15);
    int ci = kk*32 + (l>>4)*8 + j;
    wf[WF_LW2 + d_] = f2b(p.lw2[(size_t)co*128 + ci]);
  }

  for (int idx = tid; idx < 800; idx += 256){
    int v = idx >> 5, o2 = idx & 31;
    float acc = p.sb2[o2];
    for (int o = 0; o < 64; o++){
      float e = fmaxf(p.sw1[o*25+v] + p.sb1[o], 0.f);
      acc += p.sw2[o2*64+o] * e;
    }
    ws[OFF_S1+idx] = fmaxf(acc, 0.f);
  }
  for (int idx = tid; idx < 8192; idx += 256){
    int o = idx / 64, t = idx % 64;
    float acc = p.tb2[o];
    for (int o1 = 0; o1 < 64; o1++){
      float e = fmaxf(p.tw1[o1*64+t] + p.tb1[o1], 0.f);
      acc += p.tw2[o*64+o1] * e;
    }
    ws[OFF_T1+idx] = fmaxf(acc, 0.f);
  }
  __syncthreads();
  // transposed tem: [t][co]
  for (int idx = tid; idx < 8192; idx += 256){
    int t = idx >> 7, co = idx & 127;
    ws[OFF_TMT + idx] = ws[OFF_T1 + co*64 + t];
  }
  for (int idx = tid; idx < 4096; idx += 256){
    int i = idx / 64, j = idx % 64;
    float acc = 0.f;
    for (int c = 0; c < 128; c++) acc += p.g1w[c*64+i] * p.g2w[c*64+j];
    ws[OFF_A+idx] = acc;
  }
  if (tid < 64){
    float a = 0.f; for (int c = 0; c < 128; c++) a += p.g1b[c]*p.g2w[c*64+tid];
    ws[OFF_C1+tid] = a;
  } else if (tid < 128){
    int j = tid - 64;
    float a = 0.f; for (int c = 0; c < 128; c++) a += p.g2b[c]*p.g1w[c*64+j];
    ws[OFF_C1+64+j] = a;
  } else if (tid == 128){
    float a = 0.f; for (int c = 0; c < 128; c++) a += p.g1b[c]*p.g2b[c];
    ws[OFF_C1+128] = a;
  }
}

// ---------------- k_ea: embed + attention (unchanged structure) --------------
__global__ __launch_bounds__(128) void k_ea(P p){
  __shared__ __attribute__((aligned(16))) float P1[2][1700];
  __shared__ __attribute__((aligned(16))) float P2[2][1600];
  __shared__ __attribute__((aligned(16))) float Hh[2][1700];
  __shared__ float SS[2][725];
  __shared__ float sXc[2][152], sCuv[2][64];
  __shared__ __attribute__((aligned(16))) float sS1[800];
  __shared__ __attribute__((aligned(16))) float sC[132];
  __shared__ float sBnJ[152], sBnD[152];

  int tid = threadIdx.x, bid = blockIdx.x;
  int w = tid >> 6, lane = tid & 63;
  float* ws = p.ws;

  for (int i = tid; i < 800; i += 128) sS1[i] = ws[OFF_S1+i];
  if (tid < 129) sC[tid] = ws[OFF_C1+tid];
  for (int i = tid; i < 150; i += 128){ sBnJ[i] = ws[OFF_BNJ+i]; sBnD[i] = ws[OFF_BND+i]; }
  __syncthreads();

  int ic = bid*2 + w;
  int b  = ic >> p.tcShift;
  int t  = p.tBase + (ic & (p.TC-1));
  int n = b >> 1, m = b & 1;

  for (int i = lane; i < 150; i += 64){
    int which = (i < 75) ? 0 : 1;
    int j = i - which*75;
    int c = j / 25, vj = j % 25;
    int ts = t - which;
    sXc[w][i] = (ts >= 0) ? p.x[(((n*3+c)*64+ts)*25+vj)*2+m] : 0.f;
  }

  {
    float jw[3], dw[3];
    #pragma unroll
    for (int c = 0; c < 3; c++){ jw[c] = p.jw1[lane*3+c]; dw[c] = p.dw1[lane*3+c]; }
    float jb = p.jb1[lane], db = p.db1[lane];
    for (int v = 0; v < 25; v++){
      float pa = jb, da = db;
      #pragma unroll
      for (int c = 0; c < 3; c++){
        int ch = c*25+v;
        float xc = sXc[w][ch];
        float y  = sBnJ[ch]*xc + sBnJ[75+ch];
        float d  = (t > 0) ? (xc - sXc[w][75+ch]) : 0.f;
        float yd = sBnD[ch]*d + sBnD[75+ch];
        pa += jw[c]*y;  da += dw[c]*yd;
      }
      P1[w][v*68+lane] = fmaxf(pa, 0.f);
      P2[w][v*64+lane] = fmaxf(da, 0.f);
    }
  }

  {
    int up = lane >> 5, c2 = lane & 31;
    const float* wrow = (up ? p.dw2 : p.jw2) + c2*64;
    float bias = (up ? p.db2 : p.jb2)[c2];
    float4 W[16];
    #pragma unroll
    for (int j = 0; j < 16; j++) W[j] = *(const float4*)&wrow[j*4];
    const float* ebase = up ? &P2[w][0] : &P1[w][0];
    int est = up ? 64 : 68;
    for (int v = 0; v < 25; v++){
      float acc = bias;
      const float* er = ebase + v*est;
      #pragma unroll
      for (int j = 0; j < 16; j++) dot4(acc, W[j], *(const float4*)&er[j*4]);
      float r = fmaxf(acc, 0.f);
      float rr = __shfl_xor(r, 32);
      if (!up) Hh[w][v*68+c2] = r + rr;
      else     Hh[w][v*68+32+c2] = sS1[v*32+c2];
    }
  }

  {
    int r = lane & 31, up = lane >> 5;
    if (r < 25){
      const float* cc = up ? (sC+64) : sC;
      float acc = 0.f;
      #pragma unroll
      for (int j = 0; j < 16; j++)
        dot4(acc, *(const float4*)&cc[j*4], *(const float4*)&Hh[w][r*68+j*4]);
      sCuv[w][lane] = acc;
    }
  }

  {
    const float* ar = ws + OFF_A + lane*64;
    float4 A[16];
    #pragma unroll
    for (int j = 0; j < 16; j++) A[j] = *(const float4*)&ar[j*4];
    for (int u = 0; u < 25; u++){
      float acc = 0.f;
      #pragma unroll
      for (int j = 0; j < 16; j++) dot4(acc, A[j], *(const float4*)&Hh[w][u*68+j*4]);
      P1[w][u*68+lane] = acc;
    }
  }

  {
    int ul = lane & 31, vh = lane >> 5;
    for (int vv = 0; vv < 13; vv++){
      int v = vv + vh*13;
      if (ul < 25 && v < 25){
        float acc = sCuv[w][ul] + sCuv[w][32+v] + sC[128];
        #pragma unroll
        for (int j = 0; j < 16; j++)
          dot4(acc, *(const float4*)&Hh[w][v*68+j*4], *(const float4*)&P1[w][ul*68+j*4]);
        SS[w][v*29+ul] = acc;
      }
    }
  }

  if (lane < 25){
    float mx = -1e30f;
    for (int u = 0; u < 25; u++) mx = fmaxf(mx, SS[w][lane*29+u]);
    float s = 0.f;
    for (int u = 0; u < 25; u++){ float e = __expf(SS[w][lane*29+u]-mx); SS[w][lane*29+u] = e; s += e; }
    float inv = 1.f/s;
    for (int u = 0; u < 25; u++) SS[w][lane*29+u] *= inv;
  }

  {
    unsigned* gw = (unsigned*)p.gbg;
    for (int i = lane; i < 512; i += 64){
      int row = i >> 4, up = i & 15;
      int u0 = up*2, u1 = u0+1;
      float g0 = (row < 25 && u0 < 25) ? SS[w][row*29+u0] : 0.f;
      float g1 = (row < 25 && u1 < 25) ? SS[w][row*29+u1] : 0.f;
      unsigned b0 = bbits(g0), b1 = bbits(g1);
      float r0 = g0 - b2f((ushortT)b0), r1 = g1 - b2f((ushortT)b1);
      gw[((size_t)ic*2 + 0)*512 + row*16 + up] = b0 | (b1<<16);
      gw[((size_t)ic*2 + 1)*512 + row*16 + up] = bbits(r0) | (bbits(r1)<<16);
    }
  }
  for (int v = 0; v < 25; v++)
    p.h0g[(size_t)ic*1600 + v*64 + lane] = f2b(Hh[w][v*68+lane]);
}

// ---------------- gcn layer device helper ------------------------------------
template<int KS, int SECS, int L3>
__device__ inline void gcn_layer(s16x8 hf[2][4], const ushortT* WB, const ushortT* W1B,
    const float* bnS, const float* bnO, const s16x8* gfh, const s16x8* gfl,
    ushortT* sYT, ushortT* sHB, const float* tmtt, int lane){
  int l15 = lane & 15, l4 = lane >> 4;
  for (int sec = 0; sec < SECS; sec++){
    f32x4 accY[2][4];
    #pragma unroll
    for (int ut = 0; ut < 2; ut++)
      #pragma unroll
      for (int mt = 0; mt < 4; mt++) accY[ut][mt] = (f32x4){0.f,0.f,0.f,0.f};
    #pragma unroll
    for (int kk = 0; kk < KS; kk++){
      #pragma unroll
      for (int mt = 0; mt < 4; mt++){
        s16x8 bw = *(const s16x8*)(WB + ((size_t)((sec*4+mt)*KS + kk)*64 + lane)*8);
        accY[0][mt] = mfma16(hf[0][kk], bw, accY[0][mt]);
        accY[1][mt] = mfma16(hf[1][kk], bw, accY[1][mt]);
      }
    }
    #pragma unroll
    for (int ut = 0; ut < 2; ut++){
      #pragma unroll
      for (int mt = 0; mt < 4; mt++){
        unsigned h0 = bbits(accY[ut][mt][0]), h1 = bbits(accY[ut][mt][1]);
        unsigned h2 = bbits(accY[ut][mt][2]), h3 = bbits(accY[ut][mt][3]);
        float l0 = accY[ut][mt][0] - b2f((ushortT)h0);
        float l1 = accY[ut][mt][1] - b2f((ushortT)h1);
        float l2 = accY[ut][mt][2] - b2f((ushortT)h2);
        float l3 = accY[ut][mt][3] - b2f((ushortT)h3);
        int base = (mt*16 + l15)*40 + ut*16 + l4*4;
        uint2 hi, lo;
        hi.x = h0 | (h1<<16);  hi.y = h2 | (h3<<16);
        lo.x = bbits(l0) | (bbits(l1)<<16);  lo.y = bbits(l2) | (bbits(l3)<<16);
        *(uint2*)&sYT[base] = hi;
        *(uint2*)&sYT[2560 + base] = lo;
      }
    }
    f32x4 accZ[4][2];
    #pragma unroll
    for (int mt = 0; mt < 4; mt++)
      #pragma unroll
      for (int nt = 0; nt < 2; nt++) accZ[mt][nt] = (f32x4){0.f,0.f,0.f,0.f};
    #pragma unroll
    for (int kk = 0; kk < KS; kk++){
      #pragma unroll
      for (int mt = 0; mt < 4; mt++){
        s16x8 aw = *(const s16x8*)(W1B + ((size_t)((sec*4+mt)*KS + kk)*64 + lane)*8);
        accZ[mt][0] = mfma16(aw, hf[0][kk], accZ[mt][0]);
        accZ[mt][1] = mfma16(aw, hf[1][kk], accZ[mt][1]);
      }
    }
    #pragma unroll
    for (int mt = 0; mt < 4; mt++){
      s16x8 ah = *(const s16x8*)&sYT[(mt*16 + l15)*40 + l4*8];
      s16x8 al = *(const s16x8*)&sYT[2560 + (mt*16 + l15)*40 + l4*8];
      #pragma unroll
      for (int nt = 0; nt < 2; nt++){
        accZ[mt][nt] = mfma16(ah, gfh[nt], accZ[mt][nt]);
        accZ[mt][nt] = mfma16(ah, gfl[nt], accZ[mt][nt]);
        accZ[mt][nt] = mfma16(al, gfh[nt], accZ[mt][nt]);
      }
    }
    #pragma unroll
    for (int mt = 0; mt < 4; mt++){
      #pragma unroll
      for (int nt = 0; nt < 2; nt++){
        int co0 = sec*64 + mt*16 + l4*4;
        int v = nt*16 + l15;
        float z[4];
        #pragma unroll
        for (int r = 0; r < 4; r++)
          z[r] = fmaxf(bnS[co0+r]*accZ[mt][nt][r] + bnO[co0+r], 0.f);
        if (L3){
          float4 tv = *(const float4*)&tmtt[co0];
          z[0] += tv.x; z[1] += tv.y; z[2] += tv.z; z[3] += tv.w;
        }
        if (v < 25){
          uint2 pk;
          pk.x = bbits(z[0]) | (bbits(z[1])<<16);
          pk.y = bbits(z[2]) | (bbits(z[3])<<16);
          *(uint2*)&sHB[v*136 + co0] = pk;
        }
      }
    }
  }
}

// ---------------- k_g: fused gcn1+2+3 + pool ---------------------------------
__global__ __launch_bounds__(256) void k_g(P p){
  __shared__ ushortT YT[4*5120];
  __shared__ ushortT HB[4*4352];
  __shared__ float sBN[640];
  int tid = threadIdx.x, wave = tid >> 6, lane = tid & 63;
  int l15 = lane & 15, l4 = lane >> 4;
  int ic0 = blockIdx.x * 4;
  size_t ic = (size_t)ic0 + wave;
  int t = p.tBase + ((int)(ic) & (p.TC-1));
  for (int i = tid; i < 640; i += 256) sBN[i] = p.ws[OFF_BN1+i];
  __syncthreads();
  ushortT* sYT = YT + wave*5120;
  ushortT* sHB = HB + wave*4352;
  for (int i = lane; i < 119; i += 64) *(uint4*)&sHB[3400 + i*8] = (uint4){0u,0u,0u,0u};

  s16x8 gfh[2], gfl[2];
  #pragma unroll
  for (int nt = 0; nt < 2; nt++){
    gfh[nt] = *(const s16x8*)(p.gbg + (ic*2+0)*1024 + (size_t)(nt*16+l15)*32 + l4*8);
    gfl[nt] = *(const s16x8*)(p.gbg + (ic*2+1)*1024 + (size_t)(nt*16+l15)*32 + l4*8);
  }
  s16x8 hf[2][4];
  #pragma unroll
  for (int nt = 0; nt < 2; nt++){
    int v = nt*16 + l15;
    const ushortT* hr = p.h0g + (ic*25 + (v < 25 ? v : 0))*64 + l4*8;
    #pragma unroll
    for (int kk = 0; kk < 2; kk++){
      s16x8 tv = *(const s16x8*)(hr + kk*32);
      s16x8 z = {0,0,0,0,0,0,0,0};
      hf[nt][kk] = (v < 25) ? tv : z;
    }
  }
  const float* tmtt = p.ws + OFF_TMT + t*128;
  const ushortT* wf = p.wf;

  gcn_layer<2,1,0>(hf, wf+WF_W1, wf+WF_W1B, sBN, sBN+64, gfh, gfl, sYT, sHB, tmtt, lane);
  #pragma unroll
  for (int nt = 0; nt < 2; nt++)
    #pragma unroll
    for (int kk = 0; kk < 2; kk++)
      hf[nt][kk] = *(const s16x8*)&sHB[(nt*16+l15)*136 + kk*32 + l4*8];

  gcn_layer<2,2,0>(hf, wf+WF_W2, wf+WF_W2B, sBN+128, sBN+256, gfh, gfl, sYT, sHB, tmtt, lane);
  #pragma unroll
  for (int nt = 0; nt < 2; nt++)
    #pragma unroll
    for (int kk = 0; kk < 4; kk++)
      hf[nt][kk] = *(const s16x8*)&sHB[(nt*16+l15)*136 + kk*32 + l4*8];

  gcn_layer<4,2,1>(hf, wf+WF_W3, wf+WF_W3B, sBN+384, sBN+512, gfh, gfl, sYT, sHB, tmtt, lane);

  __syncthreads();
  int b  = ic0 >> p.tcShift;
  int sg = (p.tBase + (ic0 & (p.TC-1))) >> 2;
  for (int i = tid; i < 3200; i += 256){
    int v = i >> 7, co = i & 127;
    float mx =            b2f(HB[0*4352 + v*136 + co]);
    mx = fmaxf(mx, b2f(HB[1*4352 + v*136 + co]));
    mx = fmaxf(mx, b2f(HB[2*4352 + v*136 + co]));
    mx = fmaxf(mx, b2f(HB[3*4352 + v*136 + co]));
    p.poolb[(((size_t)b*16 + sg)*25 + v)*128 + co] = f2b(mx);
  }
}

// ---------------- k_lc: fused loc (conv3 + 1x1 + sum_s), wave = (b,v) --------
__global__ __launch_bounds__(256) void k_lc(P p){
  __shared__ ushortT sA[4][2448];   // 18 rows * 136
  __shared__ ushortT sO[4][2176];   // 16 rows * 136
  __shared__ float sB1[256], sB2[512];
  int tid = threadIdx.x, wave = tid >> 6, lane = tid & 63;
  int l15 = lane & 15, l4 = lane >> 4;
  int tk = blockIdx.x*4 + wave;
  int b = tk / 25, v = tk % 25;
  float* ws = p.ws;
  if (tid < 256) sB1[tid] = ws[OFF_BNL1 + tid];
  for (int i = tid; i < 512; i += 256) sB2[i] = ws[OFF_BNL2 + i];
  __syncthreads();

  ushortT* A = sA[wave];
  ushortT* O = sO[wave];
  // zero pad rows 0 and 17
  for (int i = lane; i < 68; i += 64){
    *(unsigned*)&A[i*2] = 0u;
    *(unsigned*)&A[2312 + i*2] = 0u;   // 17*136 = 2312
  }
  // stage rows 1..16
  for (int i = lane; i < 256; i += 64){
    int r = i >> 4, c8 = i & 15;
    *(uint4*)&A[(r+1)*136 + c8*8] =
      *(const uint4*)&p.poolb[((size_t)(b*16+r)*25 + v)*128 + c8*8];
  }
  const ushortT* lw1f = p.wf + WF_LW1;
  const ushortT* lw2f = p.wf + WF_LW2;

  // conv3: 96 MFMAs
  f32x4 a1[8];
  #pragma unroll
  for (int ct = 0; ct < 8; ct++) a1[ct] = (f32x4){0.f,0.f,0.f,0.f};
  #pragma unroll
  for (int d = 0; d < 3; d++){
    #pragma unroll
    for (int kk = 0; kk < 4; kk++){
      s16x8 af = *(const s16x8*)&A[(l15+d)*136 + kk*32 + l4*8];
      #pragma unroll
      for (int ct = 0; ct < 8; ct++){
        s16x8 bf = *(const s16x8*)(lw1f + (size_t)(((d*4+kk)*8+ct)*512 + lane*8));
        a1[ct] = mfma16(af, bf, a1[ct]);
      }
    }
  }
  // bn1 + relu -> O[s][co]
  #pragma unroll
  for (int ct = 0; ct < 8; ct++){
    int co = ct*16 + l15;
    float s1 = sB1[co], o1 = sB1[128+co];
    #pragma unroll
    for (int r = 0; r < 4; r++)
      O[(l4*4+r)*136 + co] = f2b(fmaxf(s1*a1[ct][r] + o1, 0.f));
  }
  // 1x1: 64 MFMAs
  s16x8 af2[4];
  #pragma unroll
  for (int kk = 0; kk < 4; kk++)
    af2[kk] = *(const s16x8*)&O[l15*136 + kk*32 + l4*8];
  f32x4 a2[16];
  #pragma unroll
  for (int ct = 0; ct < 16; ct++) a2[ct] = (f32x4){0.f,0.f,0.f,0.f};
  #pragma unroll
  for (int kk = 0; kk < 4; kk++){
    #pragma unroll
    for (int ct = 0; ct < 16; ct++){
      s16x8 bf = *(const s16x8*)(lw2f + (size_t)((kk*16+ct)*512 + lane*8));
      a2[ct] = mfma16(af2[kk], bf, a2[ct]);
    }
  }
  // bn2 + relu + sum over s -> part
  #pragma unroll
  for (int ct = 0; ct < 16; ct++){
    int co = ct*16 + l15;
    float s2 = sB2[co], o2 = sB2[256+co];
    float sum = 0.f;
    #pragma unroll
    for (int r = 0; r < 4; r++) sum += fmaxf(s2*a2[ct][r] + o2, 0.f);
    sum += __shfl_xor(sum, 16);
    sum += __shfl_xor(sum, 32);
    if (lane < 16) ws[OFF_PART2 + (size_t)(b*25+v)*256 + co] = sum;
  }
}

// ---------------- k_final ---------------------------------------------------
__global__ __launch_bounds__(256) void k_final(P p){
  __shared__ float pool[5*256];
  int tid = threadIdx.x, n = blockIdx.x;
  const float* part = p.ws + OFF_PART2;
  float tot = 0.f, hd = 0.f, hn = 0.f, ft = 0.f, hq = 0.f;
  for (int m2 = 0; m2 < 2; m2++){
    for (int v = 0; v < 25; v++){
      float pv = part[(size_t)((n*2+m2)*25+v)*256 + tid];
      tot += pv;
      unsigned bit = 1u << v;
      if (bit & 0x10000Cu)  hd += pv;
      if (bit & 0x1E00FF0u) hn += pv;
      if (bit & 0xFF000u)   ft += pv;
      if (bit & 0x11007u)   hq += pv;
    }
  }
  pool[tid]      = tot * (1.f/800.f);
  pool[256+tid]  = hd  * (1.f/96.f);
  pool[512+tid]  = hn  * (1.f/384.f);
  pool[768+tid]  = ft  * (1.f/256.f);
  pool[1024+tid] = hq  * (1.f/160.f);
  __syncthreads();
  float* out = p.out;
  for (int o = tid; o < 2620; o += 256){
    const float* wrow; float bias; const float* pl; int off;
    if (o < 60)        { wrow = p.fcw + o*256;            bias = p.fcb[o];        pl = pool;       off = n*60+o; }
    else if (o < 572)  { int j=o-60;   wrow = p.hww + j*256;         bias = p.hwb[j];       pl = pool;       off = 7680   + n*512+j; }
    else if (o < 1084) { int j=o-572;  wrow = p.pw  + j*256;         bias = p.pb[j];        pl = pool+256;   off = 73221  + n*512+j; }
    else if (o < 1596) { int j=o-1084; wrow = p.pw  + (512+j)*256;   bias = p.pb[512+j];    pl = pool+512;   off = 138757 + n*512+j; }
    else if (o < 2108) { int j=o-1596; wrow = p.pw  + (1536+j)*256;  bias = p.pb[1536+j];   pl = pool+1024;  off = 204293 + n*512+j; }
    else               { int j=o-2108; wrow = p.pw  + (1024+j)*256;  bias = p.pb[1024+j];   pl = pool+768;   off = 269829 + n*512+j; }
    float acc = bias;
    for (int c = 0; c < 256; c++) acc += wrow[c]*pl[c];
    out[off] = acc;
  }
  if (n == 0 && tid < 5) out[73216+tid] = p.ls[tid];
}

extern "C" void kernel_launch(void* const* d_in, const int* in_sizes, int n_in,
                              void* d_out, int out_size, void* d_ws, size_t ws_size,
                              hipStream_t stream){
  P p;
  p.x        = (const float*)d_in[0];
  p.bn_joint = (const float*)d_in[1];
  p.jw1      = (const float*)d_in[2];
  p.jb1      = (const float*)d_in[3];
  p.jw2      = (const float*)d_in[4];
  p.jb2      = (const float*)d_in[5];
  p.bn_dif   = (const float*)d_in[6];
  p.dw1      = (const float*)d_in[7];
  p.db1      = (const float*)d_in[8];
  p.dw2      = (const float*)d_in[9];
  p.db2      = (const float*)d_in[10];
  p.tw1      = (const float*)d_in[11];
  p.tb1      = (const float*)d_in[12];
  p.tw2      = (const float*)d_in[13];
  p.tb2      = (const float*)d_in[14];
  p.sw1      = (const float*)d_in[15];
  p.sb1      = (const float*)d_in[16];
  p.sw2      = (const float*)d_in[17];
  p.sb2      = (const float*)d_in[18];
  p.g1w      = (const float*)d_in[19];
  p.g1b      = (const float*)d_in[20];
  p.g2w      = (const float*)d_in[21];
  p.g2b      = (const float*)d_in[22];
  p.c1w      = (const float*)d_in[23];
  p.c1w1     = (const float*)d_in[24];
  p.c1b1     = (const float*)d_in[25];
  p.bnc1     = (const float*)d_in[26];
  p.c2w      = (const float*)d_in[27];
  p.c2w1     = (const float*)d_in[28];
  p.c2b1     = (const float*)d_in[29];
  p.bnc2     = (const float*)d_in[30];
  p.c3w      = (const float*)d_in[31];
  p.c3w1     = (const float*)d_in[32];
  p.c3b1     = (const float*)d_in[33];
  p.bnc3     = (const float*)d_in[34];
  p.lw1      = (const float*)d_in[35];
  p.lb1      = (const float*)d_in[36];
  p.bnl1     = (const float*)d_in[37];
  p.lw2      = (const float*)d_in[38];
  p.lb2      = (const float*)d_in[39];
  p.bnl2     = (const float*)d_in[40];
  p.fcw      = (const float*)d_in[41];
  p.fcb      = (const float*)d_in[42];
  p.hww      = (const float*)d_in[43];
  p.hwb      = (const float*)d_in[44];
  p.pw       = (const float*)d_in[45];
  p.pb       = (const float*)d_in[46];
  p.ls       = (const float*)d_in[47];
  p.ws  = (float*)d_ws;
  p.out = (float*)d_out;

  char* wsb = (char*)d_ws;
  p.wf    = (const ushortT*)(wsb + WF_B);
  p.poolb = (ushortT*)(wsb + POOL_B);

  int TC = 4;
  for (int c = 1; c <= 16; c <<= 1){
    size_t NIc = (size_t)16384 / c;
    if ((size_t)CH_B + NIc*7296 <= ws_size){ TC = 64/c; break; }
  }
  int C = 64 / TC;
  size_t NI = (size_t)256 * TC;
  p.gbg = (ushortT*)(wsb + CH_B);
  p.h0g = (ushortT*)(wsb + CH_B + NI*4096);
  p.tcShift = __builtin_ctz((unsigned)TC);
  p.TC = TC;

  k_pre<<<dim3(1), dim3(256), 0, stream>>>(p);
  for (int tc = 0; tc < C; tc++){
    p.tBase = tc*TC;
    k_ea<<<dim3((unsigned)(NI/2)), dim3(128), 0, stream>>>(p);
    k_g <<<dim3((unsigned)(NI/4)), dim3(256), 0, stream>>>(p);
  }
  k_lc   <<<dim3(1600), dim3(256), 0, stream>>>(p);
  k_final<<<dim3(128),  dim3(256), 0, stream>>>(p);
}

// Round 8
// 649.970 us; speedup vs baseline: 6.4934x; 1.5056x over previous
//
#include <hip/hip_runtime.h>

#define EPS 1e-5f

// table float offsets
#define OFF_S1   0
#define OFF_T1   800
#define OFF_A    8992
#define OFF_C1   13088
#define OFF_BNJ  13217
#define OFF_BND  13367
#define OFF_BN1  13517      // g1 s64|o64 | g2 s128|o128 | g3 s128|o128
#define OFF_BNL1 14157
#define OFF_BNL2 14413
#define OFF_TMT  16384      // [64t][128co] f32

// byte layout
#define WF_B     98304
#define POOL_B   458752
#define PART_B   (POOL_B + 26214400)
#define OFF_PART2 (PART_B/4)

// WF ush offsets
#define WF_W1    0
#define WF_W1B   4096
#define WF_W2    8192
#define WF_W2B   16384
#define WF_W3    24576
#define WF_W3B   40960
#define WF_LW1   57344
#define WF_LW2   106496
#define WF_JW2H  139264
#define WF_JW2L  141312
#define WF_DW2H  143360
#define WF_DW2L  145408
#define WF_AH    147456
#define WF_AL    151552
#define WF_SPAH  155648
#define WF_SPAL  156448

typedef unsigned short ushortT;
typedef float  f32x4 __attribute__((ext_vector_type(4)));
typedef short  s16x8 __attribute__((ext_vector_type(8)));

struct P {
  const float *x,*bn_joint,*jw1,*jb1,*jw2,*jb2,*bn_dif,*dw1,*db1,*dw2,*db2,
    *tw1,*tb1,*tw2,*tb2,*sw1,*sb1,*sw2,*sb2,*g1w,*g1b,*g2w,*g2b,
    *c1w,*c1w1,*c1b1,*bnc1,*c2w,*c2w1,*c2b1,*bnc2,*c3w,*c3w1,*c3b1,*bnc3,
    *lw1,*lb1,*bnl1,*lw2,*lb2,*bnl2,*fcw,*fcb,*hww,*hwb,*pw,*pb,*ls;
  float *ws, *out;
  const ushortT* wf;
  ushortT *poolb;
};

__device__ inline unsigned bbits(float x){
  union{float f;unsigned u;} a; a.f = x;
  return ((a.u + 0x7fffu + ((a.u>>16)&1u))>>16) & 0xffffu;
}
__device__ inline ushortT f2b(float x){ return (ushortT)bbits(x); }
__device__ inline float b2f(ushortT b){
  union{unsigned u;float f;} a; a.u = ((unsigned)b)<<16; return a.f;
}
__device__ inline f32x4 mfma16(s16x8 a, s16x8 b, f32x4 c){
  return __builtin_amdgcn_mfma_f32_16x16x32_bf16(a, b, c, 0, 0, 0);
}

__device__ inline void bn_pre(const float* bn, int C, float* dst, int tid){
  for (int c = tid; c < C; c += 256){
    float g = bn[c], b = bn[C+c], m = bn[2*C+c], v = bn[3*C+c];
    float s = g * rsqrtf(v + EPS);
    dst[c] = s; dst[C+c] = b - m*s;
  }
}

__device__ inline void wb_fill(const float* src, ushortT* dst, int COUT, int CIN, int tid){
  int KS = CIN/32;
  int total = COUT*CIN;
  for (int d = tid; d < total; d += 256){
    int j = d & 7, l = (d>>3) & 63, rest = d >> 9;
    int kk = rest % KS, tile = rest / KS;
    int co = tile*16 + (l & 15);
    int k  = kk*32 + (l >> 4)*8 + j;
    dst[d] = f2b(src[(size_t)co*CIN + k]);
  }
}

__device__ inline void wb_fill_hl(const float* src, ushortT* dh, ushortT* dl, int COUT, int CIN, int tid){
  int KS = CIN/32;
  int total = COUT*CIN;
  for (int d = tid; d < total; d += 256){
    int j = d & 7, l = (d>>3) & 63, rest = d >> 9;
    int kk = rest % KS, tile = rest / KS;
    int co = tile*16 + (l & 15);
    int k  = kk*32 + (l >> 4)*8 + j;
    float v = src[(size_t)co*CIN + k];
    ushortT h = f2b(v);
    dh[d] = h; dl[d] = f2b(v - b2f(h));
  }
}

__global__ __launch_bounds__(256) void k_pre(P p){
  int tid = threadIdx.x;
  float* ws = p.ws;
  bn_pre(p.bn_joint, 75, ws+OFF_BNJ, tid);
  bn_pre(p.bn_dif,   75, ws+OFF_BND, tid);
  bn_pre(p.bnc1,     64, ws+OFF_BN1, tid);
  bn_pre(p.bnc2,    128, ws+OFF_BN1+128, tid);
  bn_pre(p.bnc3,    128, ws+OFF_BN1+384, tid);
  bn_pre(p.bnl1,    128, ws+OFF_BNL1, tid);
  bn_pre(p.bnl2,    256, ws+OFF_BNL2, tid);
  if (tid < 64)  ws[OFF_BN1+64+tid]  += ws[OFF_BN1+tid]     * p.c1b1[tid];
  if (tid < 128) ws[OFF_BN1+256+tid] += ws[OFF_BN1+128+tid] * p.c2b1[tid];
  if (tid < 128) ws[OFF_BN1+512+tid] += ws[OFF_BN1+384+tid] * p.c3b1[tid];
  if (tid < 128) ws[OFF_BNL1+128+tid] += ws[OFF_BNL1+tid] * p.lb1[tid];
  if (tid < 256) ws[OFF_BNL2+256+tid] += ws[OFF_BNL2+tid] * p.lb2[tid];

  ushortT* wf = (ushortT*)((char*)ws + WF_B);
  wb_fill(p.c1w,  wf + WF_W1,  64, 64, tid);
  wb_fill(p.c1w1, wf + WF_W1B, 64, 64, tid);
  wb_fill(p.c2w,  wf + WF_W2, 128, 64, tid);
  wb_fill(p.c2w1, wf + WF_W2B,128, 64, tid);
  wb_fill(p.c3w,  wf + WF_W3, 128,128, tid);
  wb_fill(p.c3w1, wf + WF_W3B,128,128, tid);
  wb_fill_hl(p.jw2, wf + WF_JW2H, wf + WF_JW2L, 32, 64, tid);
  wb_fill_hl(p.dw2, wf + WF_DW2H, wf + WF_DW2L, 32, 64, tid);
  // lw1: (128co,128ci,3d)
  for (int d_ = tid; d_ < 49152; d_ += 256){
    int j = d_ & 7, l = (d_>>3) & 63, rest = d_ >> 9;
    int ct = rest & 7, kk = (rest>>3) & 3, d = rest>>5;
    int co = ct*16 + (l & 15);
    int ci = kk*32 + (l>>4)*8 + j;
    wf[WF_LW1 + d_] = f2b(p.lw1[(size_t)co*384 + ci*3 + d]);
  }
  // lw2: (256co,128ci)
  for (int d_ = tid; d_ < 32768; d_ += 256){
    int j = d_ & 7, l = (d_>>3) & 63, rest = d_ >> 9;
    int ct = rest & 15, kk = rest >> 4;
    int co = ct*16 + (l & 15);
    int ci = kk*32 + (l>>4)*8 + j;
    wf[WF_LW2 + d_] = f2b(p.lw2[(size_t)co*128 + ci]);
  }

  for (int idx = tid; idx < 800; idx += 256){
    int v = idx >> 5, o2 = idx & 31;
    float acc = p.sb2[o2];
    for (int o = 0; o < 64; o++){
      float e = fmaxf(p.sw1[o*25+v] + p.sb1[o], 0.f);
      acc += p.sw2[o2*64+o] * e;
    }
    ws[OFF_S1+idx] = fmaxf(acc, 0.f);
  }
  for (int idx = tid; idx < 8192; idx += 256){
    int o = idx / 64, t = idx % 64;
    float acc = p.tb2[o];
    for (int o1 = 0; o1 < 64; o1++){
      float e = fmaxf(p.tw1[o1*64+t] + p.tb1[o1], 0.f);
      acc += p.tw2[o*64+o1] * e;
    }
    ws[OFF_T1+idx] = fmaxf(acc, 0.f);
  }
  for (int idx = tid; idx < 4096; idx += 256){
    int i = idx / 64, j = idx % 64;
    float acc = 0.f;
    for (int c = 0; c < 128; c++) acc += p.g1w[c*64+i] * p.g2w[c*64+j];
    ws[OFF_A+idx] = acc;
  }
  if (tid < 64){
    float a = 0.f; for (int c = 0; c < 128; c++) a += p.g1b[c]*p.g2w[c*64+tid];
    ws[OFF_C1+tid] = a;
  } else if (tid < 128){
    int j = tid - 64;
    float a = 0.f; for (int c = 0; c < 128; c++) a += p.g2b[c]*p.g1w[c*64+j];
    ws[OFF_C1+64+j] = a;
  } else if (tid == 128){
    float a = 0.f; for (int c = 0; c < 128; c++) a += p.g1b[c]*p.g2b[c];
    ws[OFF_C1+128] = a;
  }
  __syncthreads();
  // transposed tem + A pack + spa pack (need full tables)
  for (int idx = tid; idx < 8192; idx += 256){
    int t = idx >> 7, co = idx & 127;
    ws[OFF_TMT + idx] = ws[OFF_T1 + co*64 + t];
  }
  wb_fill_hl(ws + OFF_A, wf + WF_AH, wf + WF_AL, 64, 64, tid);
  for (int i = tid; i < 800; i += 256){
    float v = ws[OFF_S1+i];
    ushortT h = f2b(v);
    wf[WF_SPAH+i] = h; wf[WF_SPAL+i] = f2b(v - b2f(h));
  }
}

// ---------------- gcn layer device helper (proven r7) ------------------------
template<int KS, int SECS, int L3>
__device__ inline void gcn_layer(s16x8 hf[2][4], const ushortT* WB, const ushortT* W1B,
    const float* bnS, const float* bnO, const s16x8* gfh, const s16x8* gfl,
    ushortT* sYT, ushortT* sHB, const float* tmtt, int lane){
  int l15 = lane & 15, l4 = lane >> 4;
  for (int sec = 0; sec < SECS; sec++){
    f32x4 accY[2][4];
    #pragma unroll
    for (int ut = 0; ut < 2; ut++)
      #pragma unroll
      for (int mt = 0; mt < 4; mt++) accY[ut][mt] = (f32x4){0.f,0.f,0.f,0.f};
    #pragma unroll
    for (int kk = 0; kk < KS; kk++){
      #pragma unroll
      for (int mt = 0; mt < 4; mt++){
        s16x8 bw = *(const s16x8*)(WB + ((size_t)((sec*4+mt)*KS + kk)*64 + lane)*8);
        accY[0][mt] = mfma16(hf[0][kk], bw, accY[0][mt]);
        accY[1][mt] = mfma16(hf[1][kk], bw, accY[1][mt]);
      }
    }
    #pragma unroll
    for (int ut = 0; ut < 2; ut++){
      #pragma unroll
      for (int mt = 0; mt < 4; mt++){
        unsigned h0 = bbits(accY[ut][mt][0]), h1 = bbits(accY[ut][mt][1]);
        unsigned h2 = bbits(accY[ut][mt][2]), h3 = bbits(accY[ut][mt][3]);
        float l0 = accY[ut][mt][0] - b2f((ushortT)h0);
        float l1 = accY[ut][mt][1] - b2f((ushortT)h1);
        float l2 = accY[ut][mt][2] - b2f((ushortT)h2);
        float l3 = accY[ut][mt][3] - b2f((ushortT)h3);
        int base = (mt*16 + l15)*40 + ut*16 + l4*4;
        uint2 hi, lo;
        hi.x = h0 | (h1<<16);  hi.y = h2 | (h3<<16);
        lo.x = bbits(l0) | (bbits(l1)<<16);  lo.y = bbits(l2) | (bbits(l3)<<16);
        *(uint2*)&sYT[base] = hi;
        *(uint2*)&sYT[2560 + base] = lo;
      }
    }
    f32x4 accZ[4][2];
    #pragma unroll
    for (int mt = 0; mt < 4; mt++)
      #pragma unroll
      for (int nt = 0; nt < 2; nt++) accZ[mt][nt] = (f32x4){0.f,0.f,0.f,0.f};
    #pragma unroll
    for (int kk = 0; kk < KS; kk++){
      #pragma unroll
      for (int mt = 0; mt < 4; mt++){
        s16x8 aw = *(const s16x8*)(W1B + ((size_t)((sec*4+mt)*KS + kk)*64 + lane)*8);
        accZ[mt][0] = mfma16(aw, hf[0][kk], accZ[mt][0]);
        accZ[mt][1] = mfma16(aw, hf[1][kk], accZ[mt][1]);
      }
    }
    #pragma unroll
    for (int mt = 0; mt < 4; mt++){
      s16x8 ah = *(const s16x8*)&sYT[(mt*16 + l15)*40 + l4*8];
      s16x8 al = *(const s16x8*)&sYT[2560 + (mt*16 + l15)*40 + l4*8];
      #pragma unroll
      for (int nt = 0; nt < 2; nt++){
        accZ[mt][nt] = mfma16(ah, gfh[nt], accZ[mt][nt]);
        accZ[mt][nt] = mfma16(ah, gfl[nt], accZ[mt][nt]);
        accZ[mt][nt] = mfma16(al, gfh[nt], accZ[mt][nt]);
      }
    }
    #pragma unroll
    for (int mt = 0; mt < 4; mt++){
      #pragma unroll
      for (int nt = 0; nt < 2; nt++){
        int co0 = sec*64 + mt*16 + l4*4;
        int v = nt*16 + l15;
        float z[4];
        #pragma unroll
        for (int r = 0; r < 4; r++)
          z[r] = fmaxf(bnS[co0+r]*accZ[mt][nt][r] + bnO[co0+r], 0.f);
        if (L3){
          float4 tv = *(const float4*)&tmtt[co0];
          z[0] += tv.x; z[1] += tv.y; z[2] += tv.z; z[3] += tv.w;
        }
        if (v < 25){
          uint2 pk;
          pk.x = bbits(z[0]) | (bbits(z[1])<<16);
          pk.y = bbits(z[2]) | (bbits(z[3])<<16);
          *(uint2*)&sHB[v*136 + co0] = pk;
        }
      }
    }
  }
}

// ---------------- k_fwd: full fused forward, wave = (b,t) instance -----------
__global__ __launch_bounds__(256, 2) void k_fwd(P p){
  __shared__ __attribute__((aligned(16))) ushortT W1[4][5120];
  __shared__ __attribute__((aligned(16))) ushortT W2[4][4352];
  __shared__ float sBN[640], sBnJ[152], sBnD[152];
  int tid = threadIdx.x, wave = tid >> 6, lane = tid & 63;
  int l15 = lane & 15, l4 = lane >> 4;
  float* ws = p.ws;
  const ushortT* wf = p.wf;
  for (int i = tid; i < 640; i += 256) sBN[i] = ws[OFF_BN1+i];
  for (int i = tid; i < 150; i += 256){ sBnJ[i] = ws[OFF_BNJ+i]; sBnD[i] = ws[OFF_BND+i]; }
  __syncthreads();

  int ic0 = blockIdx.x*4;
  int ic = ic0 + wave;
  int b = ic >> 6, t = ic & 63;
  int n = b >> 1, m = b & 1;
  ushortT* w1 = W1[wave];
  ushortT* w2 = W2[wave];
  float* fw1 = (float*)w1;
  float* fw2 = (float*)w2;

  // zero w1 (pad rows for e1/h0)
  for (int i = lane; i < 640; i += 64) ((uint4*)w1)[i] = (uint4){0u,0u,0u,0u};
  // x gather -> fw2[0..149]
  for (int i = lane; i < 150; i += 64){
    int which = (i < 75) ? 0 : 1;
    int j = i - which*75;
    int c = j/25, vj = j%25;
    int ts = t - which;
    fw2[i] = (ts >= 0) ? p.x[(((n*3+c)*64+ts)*25+vj)*2+m] : 0.f;
  }
  // e1 (lane = o): e1p @w1[0] stride 72, e1d @w1[2304]
  {
    float jwv[3], dwv[3];
    #pragma unroll
    for (int c = 0; c < 3; c++){ jwv[c] = p.jw1[lane*3+c]; dwv[c] = p.dw1[lane*3+c]; }
    float jb = p.jb1[lane], db = p.db1[lane];
    for (int v = 0; v < 25; v++){
      float pa = jb, da = db;
      #pragma unroll
      for (int c = 0; c < 3; c++){
        int ch = c*25+v;
        float xc = fw2[ch];
        float y  = sBnJ[ch]*xc + sBnJ[75+ch];
        float d  = (t > 0) ? (xc - fw2[75+ch]) : 0.f;
        float yd = sBnD[ch]*d + sBnD[75+ch];
        pa += jwv[c]*y;  da += dwv[c]*yd;
      }
      w1[v*72+lane]      = f2b(fmaxf(pa, 0.f));
      w1[2304+v*72+lane] = f2b(fmaxf(da, 0.f));
    }
  }
  // h0 GEMM: pos/dif, hi/lo weights
  {
    s16x8 ep[2][2], ed[2][2];
    #pragma unroll
    for (int mt = 0; mt < 2; mt++)
      #pragma unroll
      for (int kk = 0; kk < 2; kk++){
        ep[mt][kk] = *(const s16x8*)&w1[(mt*16+l15)*72 + kk*32 + l4*8];
        ed[mt][kk] = *(const s16x8*)&w1[2304 + (mt*16+l15)*72 + kk*32 + l4*8];
      }
    f32x4 aP[2][2], aD[2][2];
    #pragma unroll
    for (int mt = 0; mt < 2; mt++)
      #pragma unroll
      for (int nt = 0; nt < 2; nt++){ aP[mt][nt] = (f32x4){0.f,0.f,0.f,0.f}; aD[mt][nt] = (f32x4){0.f,0.f,0.f,0.f}; }
    #pragma unroll
    for (int kk = 0; kk < 2; kk++){
      #pragma unroll
      for (int nt = 0; nt < 2; nt++){
        size_t fo = ((size_t)(nt*2+kk)*64 + lane)*8;
        s16x8 bjh = *(const s16x8*)(wf + WF_JW2H + fo);
        s16x8 bjl = *(const s16x8*)(wf + WF_JW2L + fo);
        s16x8 bdh = *(const s16x8*)(wf + WF_DW2H + fo);
        s16x8 bdl = *(const s16x8*)(wf + WF_DW2L + fo);
        #pragma unroll
        for (int mt = 0; mt < 2; mt++){
          aP[mt][nt] = mfma16(ep[mt][kk], bjh, aP[mt][nt]);
          aP[mt][nt] = mfma16(ep[mt][kk], bjl, aP[mt][nt]);
          aD[mt][nt] = mfma16(ed[mt][kk], bdh, aD[mt][nt]);
          aD[mt][nt] = mfma16(ed[mt][kk], bdl, aD[mt][nt]);
        }
      }
    }
    // epilogue: h0 = relu(P+jb2)+relu(D+db2) -> w1 hi @0 / lo @2304 (cols 0-31)
    #pragma unroll
    for (int nt = 0; nt < 2; nt++){
      int c2 = nt*16 + l15;
      float jb2v = p.jb2[c2], db2v = p.db2[c2];
      #pragma unroll
      for (int mt = 0; mt < 2; mt++){
        #pragma unroll
        for (int r = 0; r < 4; r++){
          int v = mt*16 + l4*4 + r;
          if (v < 25){
            float h0 = fmaxf(aP[mt][nt][r]+jb2v, 0.f) + fmaxf(aD[mt][nt][r]+db2v, 0.f);
            ushortT hh = f2b(h0);
            w1[v*72+c2] = hh;
            w1[2304+v*72+c2] = f2b(h0 - b2f(hh));
          }
        }
      }
    }
  }
  // spa cols 32..63 from packed table
  for (int i = lane; i < 100; i += 64){
    int v = i >> 2, ch = i & 3;
    *(uint4*)&w1[v*72+32+ch*8]      = *(const uint4*)(wf + WF_SPAH + i*8);
    *(uint4*)&w1[2304+v*72+32+ch*8] = *(const uint4*)(wf + WF_SPAL + i*8);
  }
  // h fragments (dual-use; rows >=25 are zero from pre-zeroing)
  s16x8 hfh[2][4], hfl[2][2];
  #pragma unroll
  for (int nt = 0; nt < 2; nt++)
    #pragma unroll
    for (int kk = 0; kk < 2; kk++){
      hfh[nt][kk] = *(const s16x8*)&w1[(nt*16+l15)*72 + kk*32 + l4*8];
      hfl[nt][kk] = *(const s16x8*)&w1[2304 + (nt*16+l15)*72 + kk*32 + l4*8];
    }
  // Cu/Cv (VALU): fw1[2304+u]=c1.h_u, fw1[2336+v]=c2.h_v
  {
    int up = lane >> 5, r = lane & 31;
    float acc = 0.f;
    if (r < 25){
      const float* cv = ws + OFF_C1 + up*64;
      for (int j8 = 0; j8 < 8; j8++){
        s16x8 hh = *(const s16x8*)&w1[r*72 + j8*8];
        s16x8 ll = *(const s16x8*)&w1[2304 + r*72 + j8*8];
        #pragma unroll
        for (int e = 0; e < 8; e++)
          acc += cv[j8*8+e] * (b2f((ushortT)hh[e]) + b2f((ushortT)ll[e]));
      }
    }
    fw1[2304 + up*32 + r] = acc;
  }
  // Y-GEMM: Y[u][i] = (A h_u)[i], 3-term hi/lo
  f32x4 aY[2][4];
  #pragma unroll
  for (int mt = 0; mt < 2; mt++)
    #pragma unroll
    for (int nt = 0; nt < 4; nt++) aY[mt][nt] = (f32x4){0.f,0.f,0.f,0.f};
  #pragma unroll
  for (int kk = 0; kk < 2; kk++){
    #pragma unroll
    for (int nt = 0; nt < 4; nt++){
      size_t fo = ((size_t)(nt*2+kk)*64 + lane)*8;
      s16x8 bah = *(const s16x8*)(wf + WF_AH + fo);
      s16x8 bal = *(const s16x8*)(wf + WF_AL + fo);
      #pragma unroll
      for (int mt = 0; mt < 2; mt++){
        aY[mt][nt] = mfma16(hfh[mt][kk], bah, aY[mt][nt]);
        aY[mt][nt] = mfma16(hfl[mt][kk], bah, aY[mt][nt]);
        aY[mt][nt] = mfma16(hfh[mt][kk], bal, aY[mt][nt]);
      }
    }
  }
  // pack Y: hi @w2[0] stride 72 (linear), lo @w2[2304] stride 64 chunk-XOR swizzled
  #pragma unroll
  for (int mt = 0; mt < 2; mt++){
    #pragma unroll
    for (int nt = 0; nt < 4; nt++){
      int i_ = nt*16 + l15;
      #pragma unroll
      for (int r = 0; r < 4; r++){
        int u = mt*16 + l4*4 + r;
        float y = aY[mt][nt][r];
        ushortT hh = f2b(y);
        w2[u*72 + i_] = hh;
        w2[2304 + u*64 + (((i_>>3) ^ (u&7))<<3) + (i_&7)] = f2b(y - b2f(hh));
      }
    }
  }
  // S-GEMM: S[v][u] = h_v . Y_u, 3-term
  f32x4 aS[2][2];
  #pragma unroll
  for (int mt = 0; mt < 2; mt++)
    #pragma unroll
    for (int nt = 0; nt < 2; nt++) aS[mt][nt] = (f32x4){0.f,0.f,0.f,0.f};
  #pragma unroll
  for (int kk = 0; kk < 2; kk++){
    #pragma unroll
    for (int nt = 0; nt < 2; nt++){
      int ur = nt*16 + l15;
      s16x8 byh = *(const s16x8*)&w2[ur*72 + kk*32 + l4*8];
      s16x8 byl = *(const s16x8*)&w2[2304 + ur*64 + ((((kk*4+l4)) ^ (ur&7))<<3)];
      #pragma unroll
      for (int mt = 0; mt < 2; mt++){
        aS[mt][nt] = mfma16(hfh[mt][kk], byh, aS[mt][nt]);
        aS[mt][nt] = mfma16(hfl[mt][kk], byh, aS[mt][nt]);
        aS[mt][nt] = mfma16(hfh[mt][kk], byl, aS[mt][nt]);
      }
    }
  }
  // softmax + g write (hi @w2[0] stride 40, lo @w2[1280])
  {
    float d0 = ws[OFF_C1+128];
    float cu0 = fw1[2304 + l15];
    float cu1 = fw1[2304 + 16 + l15];
    bool m1 = (16 + l15) < 25;
    #pragma unroll
    for (int mt = 0; mt < 2; mt++){
      #pragma unroll
      for (int r = 0; r < 4; r++){
        int v = mt*16 + l4*4 + r;
        float cvv = (v < 25) ? fw1[2336+v] : 0.f;
        float s0 = aS[mt][0][r] + cu0 + cvv + d0;
        float s1 = m1 ? (aS[mt][1][r] + cu1 + cvv + d0) : -1e30f;
        float mx = fmaxf(s0, s1);
        mx = fmaxf(mx, __shfl_xor(mx, 1));
        mx = fmaxf(mx, __shfl_xor(mx, 2));
        mx = fmaxf(mx, __shfl_xor(mx, 4));
        mx = fmaxf(mx, __shfl_xor(mx, 8));
        float e0 = __expf(s0 - mx);
        float e1v = m1 ? __expf(s1 - mx) : 0.f;
        float sm = e0 + e1v;
        sm += __shfl_xor(sm, 1);
        sm += __shfl_xor(sm, 2);
        sm += __shfl_xor(sm, 4);
        sm += __shfl_xor(sm, 8);
        float inv = 1.f/sm;
        float g0 = e0*inv, g1 = e1v*inv;
        ushortT g0h = f2b(g0), g1h = f2b(g1);
        w2[v*40+l15]         = g0h;
        w2[1280+v*40+l15]    = f2b(g0 - b2f(g0h));
        w2[v*40+16+l15]      = g1h;
        w2[1280+v*40+16+l15] = f2b(g1 - b2f(g1h));
      }
    }
  }
  // g fragments
  s16x8 gfh[2], gfl[2];
  #pragma unroll
  for (int nt = 0; nt < 2; nt++){
    gfh[nt] = *(const s16x8*)&w2[(nt*16+l15)*40 + l4*8];
    gfl[nt] = *(const s16x8*)&w2[1280 + (nt*16+l15)*40 + l4*8];
  }
  // zero sHB pad rows (25..31)
  for (int i = lane; i < 119; i += 64) *(uint4*)&w2[3400 + i*8] = (uint4){0u,0u,0u,0u};

  // gcn chain (w1 = YT scratch, w2 = h buffer)
  const float* tmtt = ws + OFF_TMT + t*128;
  gcn_layer<2,1,0>(hfh, wf+WF_W1, wf+WF_W1B, sBN, sBN+64, gfh, gfl, w1, w2, tmtt, lane);
  #pragma unroll
  for (int nt = 0; nt < 2; nt++)
    #pragma unroll
    for (int kk = 0; kk < 2; kk++)
      hfh[nt][kk] = *(const s16x8*)&w2[(nt*16+l15)*136 + kk*32 + l4*8];
  gcn_layer<2,2,0>(hfh, wf+WF_W2, wf+WF_W2B, sBN+128, sBN+256, gfh, gfl, w1, w2, tmtt, lane);
  #pragma unroll
  for (int nt = 0; nt < 2; nt++)
    #pragma unroll
    for (int kk = 0; kk < 4; kk++)
      hfh[nt][kk] = *(const s16x8*)&w2[(nt*16+l15)*136 + kk*32 + l4*8];
  gcn_layer<4,2,1>(hfh, wf+WF_W3, wf+WF_W3B, sBN+384, sBN+512, gfh, gfl, w1, w2, tmtt, lane);

  __syncthreads();
  // 4-t maxpool across the block's 4 waves
  int bb = ic0 >> 6, sg = (ic0 & 63) >> 2;
  for (int i = tid; i < 3200; i += 256){
    int v = i >> 7, co = i & 127;
    float mx =     b2f(W2[0][v*136+co]);
    mx = fmaxf(mx, b2f(W2[1][v*136+co]));
    mx = fmaxf(mx, b2f(W2[2][v*136+co]));
    mx = fmaxf(mx, b2f(W2[3][v*136+co]));
    p.poolb[(((size_t)bb*16+sg)*25+v)*128 + co] = f2b(mx);
  }
}

// ---------------- k_lc: fused loc (conv3 + 1x1 + sum_s), wave = (b,v) --------
__global__ __launch_bounds__(256) void k_lc(P p){
  __shared__ ushortT sA[4][2448];
  __shared__ ushortT sO[4][2176];
  __shared__ float sB1[256], sB2[512];
  int tid = threadIdx.x, wave = tid >> 6, lane = tid & 63;
  int l15 = lane & 15, l4 = lane >> 4;
  int tk = blockIdx.x*4 + wave;
  int b = tk / 25, v = tk % 25;
  float* ws = p.ws;
  if (tid < 256) sB1[tid] = ws[OFF_BNL1 + tid];
  for (int i = tid; i < 512; i += 256) sB2[i] = ws[OFF_BNL2 + i];
  __syncthreads();

  ushortT* A = sA[wave];
  ushortT* O = sO[wave];
  for (int i = lane; i < 68; i += 64){
    *(unsigned*)&A[i*2] = 0u;
    *(unsigned*)&A[2312 + i*2] = 0u;
  }
  for (int i = lane; i < 256; i += 64){
    int r = i >> 4, c8 = i & 15;
    *(uint4*)&A[(r+1)*136 + c8*8] =
      *(const uint4*)&p.poolb[((size_t)(b*16+r)*25 + v)*128 + c8*8];
  }
  const ushortT* lw1f = p.wf + WF_LW1;
  const ushortT* lw2f = p.wf + WF_LW2;

  f32x4 a1[8];
  #pragma unroll
  for (int ct = 0; ct < 8; ct++) a1[ct] = (f32x4){0.f,0.f,0.f,0.f};
  #pragma unroll
  for (int d = 0; d < 3; d++){
    #pragma unroll
    for (int kk = 0; kk < 4; kk++){
      s16x8 af = *(const s16x8*)&A[(l15+d)*136 + kk*32 + l4*8];
      #pragma unroll
      for (int ct = 0; ct < 8; ct++){
        s16x8 bf = *(const s16x8*)(lw1f + (size_t)(((d*4+kk)*8+ct)*512 + lane*8));
        a1[ct] = mfma16(af, bf, a1[ct]);
      }
    }
  }
  #pragma unroll
  for (int ct = 0; ct < 8; ct++){
    int co = ct*16 + l15;
    float s1 = sB1[co], o1 = sB1[128+co];
    #pragma unroll
    for (int r = 0; r < 4; r++)
      O[(l4*4+r)*136 + co] = f2b(fmaxf(s1*a1[ct][r] + o1, 0.f));
  }
  s16x8 af2[4];
  #pragma unroll
  for (int kk = 0; kk < 4; kk++)
    af2[kk] = *(const s16x8*)&O[l15*136 + kk*32 + l4*8];
  f32x4 a2[16];
  #pragma unroll
  for (int ct = 0; ct < 16; ct++) a2[ct] = (f32x4){0.f,0.f,0.f,0.f};
  #pragma unroll
  for (int kk = 0; kk < 4; kk++){
    #pragma unroll
    for (int ct = 0; ct < 16; ct++){
      s16x8 bf = *(const s16x8*)(lw2f + (size_t)((kk*16+ct)*512 + lane*8));
      a2[ct] = mfma16(af2[kk], bf, a2[ct]);
    }
  }
  #pragma unroll
  for (int ct = 0; ct < 16; ct++){
    int co = ct*16 + l15;
    float s2 = sB2[co], o2 = sB2[256+co];
    float sum = 0.f;
    #pragma unroll
    for (int r = 0; r < 4; r++) sum += fmaxf(s2*a2[ct][r] + o2, 0.f);
    sum += __shfl_xor(sum, 16);
    sum += __shfl_xor(sum, 32);
    if (lane < 16) ws[OFF_PART2 + (size_t)(b*25+v)*256 + co] = sum;
  }
}

// ---------------- k_final ---------------------------------------------------
__global__ __launch_bounds__(256) void k_final(P p){
  __shared__ float pool[5*256];
  int tid = threadIdx.x, n = blockIdx.x;
  const float* part = p.ws + OFF_PART2;
  float tot = 0.f, hd = 0.f, hn = 0.f, ft = 0.f, hq = 0.f;
  for (int m2 = 0; m2 < 2; m2++){
    for (int v = 0; v < 25; v++){
      float pv = part[(size_t)((n*2+m2)*25+v)*256 + tid];
      tot += pv;
      unsigned bit = 1u << v;
      if (bit & 0x10000Cu)  hd += pv;
      if (bit & 0x1E00FF0u) hn += pv;
      if (bit & 0xFF000u)   ft += pv;
      if (bit & 0x11007u)   hq += pv;
    }
  }
  pool[tid]      = tot * (1.f/800.f);
  pool[256+tid]  = hd  * (1.f/96.f);
  pool[512+tid]  = hn  * (1.f/384.f);
  pool[768+tid]  = ft  * (1.f/256.f);
  pool[1024+tid] = hq  * (1.f/160.f);
  __syncthreads();
  float* out = p.out;
  for (int o = tid; o < 2620; o += 256){
    const float* wrow; float bias; const float* pl; int off;
    if (o < 60)        { wrow = p.fcw + o*256;            bias = p.fcb[o];        pl = pool;       off = n*60+o; }
    else if (o < 572)  { int j=o-60;   wrow = p.hww + j*256;         bias = p.hwb[j];       pl = pool;       off = 7680   + n*512+j; }
    else if (o < 1084) { int j=o-572;  wrow = p.pw  + j*256;         bias = p.pb[j];        pl = pool+256;   off = 73221  + n*512+j; }
    else if (o < 1596) { int j=o-1084; wrow = p.pw  + (512+j)*256;   bias = p.pb[512+j];    pl = pool+512;   off = 138757 + n*512+j; }
    else if (o < 2108) { int j=o-1596; wrow = p.pw  + (1536+j)*256;  bias = p.pb[1536+j];   pl = pool+1024;  off = 204293 + n*512+j; }
    else               { int j=o-2108; wrow = p.pw  + (1024+j)*256;  bias = p.pb[1024+j];   pl = pool+768;   off = 269829 + n*512+j; }
    float acc = bias;
    for (int c = 0; c < 256; c++) acc += wrow[c]*pl[c];
    out[off] = acc;
  }
  if (n == 0 && tid < 5) out[73216+tid] = p.ls[tid];
}

extern "C" void kernel_launch(void* const* d_in, const int* in_sizes, int n_in,
                              void* d_out, int out_size, void* d_ws, size_t ws_size,
                              hipStream_t stream){
  P p;
  p.x        = (const float*)d_in[0];
  p.bn_joint = (const float*)d_in[1];
  p.jw1      = (const float*)d_in[2];
  p.jb1      = (const float*)d_in[3];
  p.jw2      = (const float*)d_in[4];
  p.jb2      = (const float*)d_in[5];
  p.bn_dif   = (const float*)d_in[6];
  p.dw1      = (const float*)d_in[7];
  p.db1      = (const float*)d_in[8];
  p.dw2      = (const float*)d_in[9];
  p.db2      = (const float*)d_in[10];
  p.tw1      = (const float*)d_in[11];
  p.tb1      = (const float*)d_in[12];
  p.tw2      = (const float*)d_in[13];
  p.tb2      = (const float*)d_in[14];
  p.sw1      = (const float*)d_in[15];
  p.sb1      = (const float*)d_in[16];
  p.sw2      = (const float*)d_in[17];
  p.sb2      = (const float*)d_in[18];
  p.g1w      = (const float*)d_in[19];
  p.g1b      = (const float*)d_in[20];
  p.g2w      = (const float*)d_in[21];
  p.g2b      = (const float*)d_in[22];
  p.c1w      = (const float*)d_in[23];
  p.c1w1     = (const float*)d_in[24];
  p.c1b1     = (const float*)d_in[25];
  p.bnc1     = (const float*)d_in[26];
  p.c2w      = (const float*)d_in[27];
  p.c2w1     = (const float*)d_in[28];
  p.c2b1     = (const float*)d_in[29];
  p.bnc2     = (const float*)d_in[30];
  p.c3w      = (const float*)d_in[31];
  p.c3w1     = (const float*)d_in[32];
  p.c3b1     = (const float*)d_in[33];
  p.bnc3     = (const float*)d_in[34];
  p.lw1      = (const float*)d_in[35];
  p.lb1      = (const float*)d_in[36];
  p.bnl1     = (const float*)d_in[37];
  p.lw2      = (const float*)d_in[38];
  p.lb2      = (const float*)d_in[39];
  p.bnl2     = (const float*)d_in[40];
  p.fcw      = (const float*)d_in[41];
  p.fcb      = (const float*)d_in[42];
  p.hww      = (const float*)d_in[43];
  p.hwb      = (const float*)d_in[44];
  p.pw       = (const float*)d_in[45];
  p.pb       = (const float*)d_in[46];
  p.ls       = (const float*)d_in[47];
  p.ws  = (float*)d_ws;
  p.out = (float*)d_out;

  char* wsb = (char*)d_ws;
  p.wf    = (const ushortT*)(wsb + WF_B);
  p.poolb = (ushortT*)(wsb + POOL_B);

  k_pre  <<<dim3(1),    dim3(256), 0, stream>>>(p);
  k_fwd  <<<dim3(4096), dim3(256), 0, stream>>>(p);
  k_lc   <<<dim3(1600), dim3(256), 0, stream>>>(p);
  k_final<<<dim3(128),  dim3(256), 0, stream>>>(p);
}

// Round 11
// 449.458 us; speedup vs baseline: 9.3903x; 1.4461x over previous
//
#include <hip/hip_runtime.h>

#define EPS 1e-5f

// table float offsets
#define OFF_S1   0
#define OFF_T1   800
#define OFF_A    8992
#define OFF_C1   13088
#define OFF_BNJ  13217
#define OFF_BND  13367
#define OFF_BN1  13517
#define OFF_BNL1 14157
#define OFF_BNL2 14413
#define OFF_CUS  14928
#define OFF_TMT  16384      // [64t][128co] f32

// byte layout
#define WF_B     98304
#define POOL_B   458752
#define PART_B   (POOL_B + 26214400)
#define OFF_PART2 (PART_B/4)

// WF ush offsets
#define WF_W1    0
#define WF_W1B   4096
#define WF_W2    8192
#define WF_W2B   16384
#define WF_W3    24576
#define WF_W3B   40960
#define WF_LW1   57344
#define WF_LW2   106496
#define WF_JW2H  139264
#define WF_JW2L  141312
#define WF_DW2H  143360
#define WF_DW2L  145408
#define WF_AH    147456
#define WF_AL    151552
#define WF_SPAH  155648
#define WF_SPAL  156448

typedef unsigned short ushortT;
typedef float  f32x4 __attribute__((ext_vector_type(4)));
typedef short  s16x8 __attribute__((ext_vector_type(8)));

struct P {
  const float *x,*bn_joint,*jw1,*jb1,*jw2,*jb2,*bn_dif,*dw1,*db1,*dw2,*db2,
    *tw1,*tb1,*tw2,*tb2,*sw1,*sb1,*sw2,*sb2,*g1w,*g1b,*g2w,*g2b,
    *c1w,*c1w1,*c1b1,*bnc1,*c2w,*c2w1,*c2b1,*bnc2,*c3w,*c3w1,*c3b1,*bnc3,
    *lw1,*lb1,*bnl1,*lw2,*lb2,*bnl2,*fcw,*fcb,*hww,*hwb,*pw,*pb,*ls;
  float *ws, *out;
  const ushortT* wf;
  ushortT *poolb;
};

// LDS ordering fence (defeats TBAA reordering across reused LDS addresses)
__device__ inline void lfence(){ __threadfence_block(); }

__device__ inline unsigned bbits(float x){
  union{float f;unsigned u;} a; a.f = x;
  return ((a.u + 0x7fffu + ((a.u>>16)&1u))>>16) & 0xffffu;
}
__device__ inline ushortT f2b(float x){ return (ushortT)bbits(x); }
__device__ inline float b2f(ushortT b){
  union{unsigned u;float f;} a; a.u = ((unsigned)b)<<16; return a.f;
}
__device__ inline f32x4 mfma16(s16x8 a, s16x8 b, f32x4 c){
  return __builtin_amdgcn_mfma_f32_16x16x32_bf16(a, b, c, 0, 0, 0);
}

__device__ inline void bn_pre(const float* bn, int C, float* dst, int gt, int NT){
  for (int c = gt; c < C; c += NT){
    float g = bn[c], b = bn[C+c], m = bn[2*C+c], v = bn[3*C+c];
    float s = g * rsqrtf(v + EPS);
    dst[c] = s; dst[C+c] = b - m*s;
  }
}

__device__ inline void wb_fill(const float* src, ushortT* dst, int COUT, int CIN, int gt, int NT){
  int KS = CIN/32;
  int total = COUT*CIN;
  for (int d = gt; d < total; d += NT){
    int j = d & 7, l = (d>>3) & 63, rest = d >> 9;
    int kk = rest % KS, tile = rest / KS;
    int co = tile*16 + (l & 15);
    int k  = kk*32 + (l >> 4)*8 + j;
    dst[d] = f2b(src[(size_t)co*CIN + k]);
  }
}

__device__ inline void wb_fill_hl(const float* src, ushortT* dh, ushortT* dl, int COUT, int CIN, int gt, int NT){
  int KS = CIN/32;
  int total = COUT*CIN;
  for (int d = gt; d < total; d += NT){
    int j = d & 7, l = (d>>3) & 63, rest = d >> 9;
    int kk = rest % KS, tile = rest / KS;
    int co = tile*16 + (l & 15);
    int k  = kk*32 + (l >> 4)*8 + j;
    float v = src[(size_t)co*CIN + k];
    ushortT h = f2b(v);
    dh[d] = h; dl[d] = f2b(v - b2f(h));
  }
}

__global__ __launch_bounds__(256) void k_pre1(P p){
  int gt = blockIdx.x*256 + threadIdx.x, NT = gridDim.x*256;
  float* ws = p.ws;
  bn_pre(p.bn_joint, 75, ws+OFF_BNJ, gt, NT);
  bn_pre(p.bn_dif,   75, ws+OFF_BND, gt, NT);
  bn_pre(p.bnc1,     64, ws+OFF_BN1, gt, NT);
  bn_pre(p.bnc2,    128, ws+OFF_BN1+128, gt, NT);
  bn_pre(p.bnc3,    128, ws+OFF_BN1+384, gt, NT);
  bn_pre(p.bnl1,    128, ws+OFF_BNL1, gt, NT);
  bn_pre(p.bnl2,    256, ws+OFF_BNL2, gt, NT);
  for (int idx = gt; idx < 800; idx += NT){
    int v = idx >> 5, o2 = idx & 31;
    float acc = p.sb2[o2];
    for (int o = 0; o < 64; o++){
      float e = fmaxf(p.sw1[o*25+v] + p.sb1[o], 0.f);
      acc += p.sw2[o2*64+o] * e;
    }
    ws[OFF_S1+idx] = fmaxf(acc, 0.f);
  }
  for (int idx = gt; idx < 8192; idx += NT){
    int o = idx / 64, t = idx % 64;
    float acc = p.tb2[o];
    for (int o1 = 0; o1 < 64; o1++){
      float e = fmaxf(p.tw1[o1*64+t] + p.tb1[o1], 0.f);
      acc += p.tw2[o*64+o1] * e;
    }
    ws[OFF_T1+idx] = fmaxf(acc, 0.f);
  }
  for (int idx = gt; idx < 4096; idx += NT){
    int i = idx / 64, j = idx % 64;
    float acc = 0.f;
    for (int c = 0; c < 128; c++) acc += p.g1w[c*64+i] * p.g2w[c*64+j];
    ws[OFF_A+idx] = acc;
  }
  if (gt < 64){
    float a = 0.f; for (int c = 0; c < 128; c++) a += p.g1b[c]*p.g2w[c*64+gt];
    ws[OFF_C1+gt] = a;
  } else if (gt < 128){
    int j = gt - 64;
    float a = 0.f; for (int c = 0; c < 128; c++) a += p.g2b[c]*p.g1w[c*64+j];
    ws[OFF_C1+64+j] = a;
  } else if (gt == 128){
    float a = 0.f; for (int c = 0; c < 128; c++) a += p.g1b[c]*p.g2b[c];
    ws[OFF_C1+128] = a;
  }
}

__global__ __launch_bounds__(256) void k_pre2(P p){
  int gt = blockIdx.x*256 + threadIdx.x, NT = gridDim.x*256;
  float* ws = p.ws;
  ushortT* wf = (ushortT*)((char*)ws + WF_B);
  // bias folds (k_pre1 rewrote the slots this call, so += stays per-call correct)
  if (gt < 64)  ws[OFF_BN1+64+gt]  += ws[OFF_BN1+gt]     * p.c1b1[gt];
  if (gt < 128){
    ws[OFF_BN1+256+gt] += ws[OFF_BN1+128+gt] * p.c2b1[gt];
    ws[OFF_BN1+512+gt] += ws[OFF_BN1+384+gt] * p.c3b1[gt];
    ws[OFF_BNL1+128+gt] += ws[OFF_BNL1+gt] * p.lb1[gt];
  }
  if (gt < 256) ws[OFF_BNL2+256+gt] += ws[OFF_BNL2+gt] * p.lb2[gt];

  wb_fill(p.c1w,  wf + WF_W1,  64, 64, gt, NT);
  wb_fill(p.c1w1, wf + WF_W1B, 64, 64, gt, NT);
  wb_fill(p.c2w,  wf + WF_W2, 128, 64, gt, NT);
  wb_fill(p.c2w1, wf + WF_W2B,128, 64, gt, NT);
  wb_fill(p.c3w,  wf + WF_W3, 128,128, gt, NT);
  wb_fill(p.c3w1, wf + WF_W3B,128,128, gt, NT);
  wb_fill_hl(p.jw2, wf + WF_JW2H, wf + WF_JW2L, 32, 64, gt, NT);
  wb_fill_hl(p.dw2, wf + WF_DW2H, wf + WF_DW2L, 32, 64, gt, NT);
  wb_fill_hl(ws + OFF_A, wf + WF_AH, wf + WF_AL, 64, 64, gt, NT);
  for (int d_ = gt; d_ < 49152; d_ += NT){
    int j = d_ & 7, l = (d_>>3) & 63, rest = d_ >> 9;
    int ct = rest & 7, kk = (rest>>3) & 3, d = rest>>5;
    int co = ct*16 + (l & 15);
    int ci = kk*32 + (l>>4)*8 + j;
    wf[WF_LW1 + d_] = f2b(p.lw1[(size_t)co*384 + ci*3 + d]);
  }
  for (int d_ = gt; d_ < 32768; d_ += NT){
    int j = d_ & 7, l = (d_>>3) & 63, rest = d_ >> 9;
    int ct = rest & 15, kk = rest >> 4;
    int co = ct*16 + (l & 15);
    int ci = kk*32 + (l>>4)*8 + j;
    wf[WF_LW2 + d_] = f2b(p.lw2[(size_t)co*128 + ci]);
  }
  for (int idx = gt; idx < 8192; idx += NT){
    int t = idx >> 7, co = idx & 127;
    ws[OFF_TMT + idx] = ws[OFF_T1 + co*64 + t];
  }
  for (int i = gt; i < 800; i += NT){
    float v = ws[OFF_S1+i];
    ushortT h = f2b(v);
    wf[WF_SPAH+i] = h; wf[WF_SPAL+i] = f2b(v - b2f(h));
  }
}

// ---------------- gcn layer (r8 two-plane YT, linear sHB) + fences -----------
template<int KS, int SECS, int L3>
__device__ inline void gcn_layer(const s16x8 hf[2][4], const ushortT* WB, const ushortT* W1B,
    const float* bnS, const float* bnO, const s16x8* gfh, const s16x8* gfl,
    ushortT* sYT, ushortT* sHB, const float* tmtt, int lane){
  int l15 = lane & 15, l4 = lane >> 4;
  for (int sec = 0; sec < SECS; sec++){
    f32x4 accY[2][4];
    #pragma unroll
    for (int ut = 0; ut < 2; ut++)
      #pragma unroll
      for (int mt = 0; mt < 4; mt++) accY[ut][mt] = (f32x4){0.f,0.f,0.f,0.f};
    #pragma unroll
    for (int kk = 0; kk < KS; kk++){
      #pragma unroll
      for (int mt = 0; mt < 4; mt++){
        s16x8 bw = *(const s16x8*)(WB + ((size_t)((sec*4+mt)*KS + kk)*64 + lane)*8);
        accY[0][mt] = mfma16(hf[0][kk], bw, accY[0][mt]);
        accY[1][mt] = mfma16(hf[1][kk], bw, accY[1][mt]);
      }
    }
    lfence();  // previous sec's ah/al reads complete before overwrite (WAR)
    #pragma unroll
    for (int ut = 0; ut < 2; ut++){
      #pragma unroll
      for (int mt = 0; mt < 4; mt++){
        unsigned h0 = bbits(accY[ut][mt][0]), h1 = bbits(accY[ut][mt][1]);
        unsigned h2 = bbits(accY[ut][mt][2]), h3 = bbits(accY[ut][mt][3]);
        float l0 = accY[ut][mt][0] - b2f((ushortT)h0);
        float l1 = accY[ut][mt][1] - b2f((ushortT)h1);
        float l2 = accY[ut][mt][2] - b2f((ushortT)h2);
        float l3 = accY[ut][mt][3] - b2f((ushortT)h3);
        int base = (mt*16 + l15)*40 + ut*16 + l4*4;
        uint2 hi, lo;
        hi.x = h0 | (h1<<16);  hi.y = h2 | (h3<<16);
        lo.x = bbits(l0) | (bbits(l1)<<16);  lo.y = bbits(l2) | (bbits(l3)<<16);
        *(uint2*)&sYT[base] = hi;
        *(uint2*)&sYT[2560 + base] = lo;
      }
    }
    f32x4 accZ[4][2];
    #pragma unroll
    for (int mt = 0; mt < 4; mt++)
      #pragma unroll
      for (int nt = 0; nt < 2; nt++) accZ[mt][nt] = (f32x4){0.f,0.f,0.f,0.f};
    #pragma unroll
    for (int kk = 0; kk < KS; kk++){
      #pragma unroll
      for (int mt = 0; mt < 4; mt++){
        s16x8 aw = *(const s16x8*)(W1B + ((size_t)((sec*4+mt)*KS + kk)*64 + lane)*8);
        accZ[mt][0] = mfma16(aw, hf[0][kk], accZ[mt][0]);
        accZ[mt][1] = mfma16(aw, hf[1][kk], accZ[mt][1]);
      }
    }
    lfence();  // YT writes visible before ah/al reads (RAW)
    #pragma unroll
    for (int mt = 0; mt < 4; mt++){
      s16x8 ah = *(const s16x8*)&sYT[(mt*16 + l15)*40 + l4*8];
      s16x8 al = *(const s16x8*)&sYT[2560 + (mt*16 + l15)*40 + l4*8];
      #pragma unroll
      for (int nt = 0; nt < 2; nt++){
        accZ[mt][nt] = mfma16(ah, gfh[nt], accZ[mt][nt]);
        accZ[mt][nt] = mfma16(ah, gfl[nt], accZ[mt][nt]);
        accZ[mt][nt] = mfma16(al, gfh[nt], accZ[mt][nt]);
      }
    }
    #pragma unroll
    for (int mt = 0; mt < 4; mt++){
      #pragma unroll
      for (int nt = 0; nt < 2; nt++){
        int co0 = sec*64 + mt*16 + l4*4;
        int v = nt*16 + l15;
        float z[4];
        #pragma unroll
        for (int r = 0; r < 4; r++)
          z[r] = fmaxf(bnS[co0+r]*accZ[mt][nt][r] + bnO[co0+r], 0.f);
        if (L3){
          float4 tv = *(const float4*)&tmtt[co0];
          z[0] += tv.x; z[1] += tv.y; z[2] += tv.z; z[3] += tv.w;
        }
        if (v < 25){
          uint2 pk;
          pk.x = bbits(z[0]) | (bbits(z[1])<<16);
          pk.y = bbits(z[2]) | (bbits(z[3])<<16);
          *(uint2*)&sHB[v*136 + co0] = pk;
        }
      }
    }
  }
}

// ---------------- k_fwd: r8 structure + fences, wave = (b,t) instance --------
__global__ __launch_bounds__(256, 2) void k_fwd(P p){
  __shared__ __attribute__((aligned(16))) ushortT W1[4][5120];
  __shared__ __attribute__((aligned(16))) ushortT W2[4][4352];
  __shared__ float sBN[640], sBnJ[152], sBnD[152];
  int tid = threadIdx.x, wave = tid >> 6, lane = tid & 63;
  int l15 = lane & 15, l4 = lane >> 4;
  float* ws = p.ws;
  const ushortT* wf = p.wf;
  for (int i = tid; i < 640; i += 256) sBN[i] = ws[OFF_BN1+i];
  for (int i = tid; i < 150; i += 256){ sBnJ[i] = ws[OFF_BNJ+i]; sBnD[i] = ws[OFF_BND+i]; }
  __syncthreads();

  int ic0 = blockIdx.x*4;
  int ic = ic0 + wave;
  int b = ic >> 6, t = ic & 63;
  int n = b >> 1, m = b & 1;
  ushortT* w1 = W1[wave];
  ushortT* w2 = W2[wave];
  float* fw1 = (float*)w1;
  float* fw2 = (float*)w2;

  // zero w1 fully (pad rows of e1/h0 planes must read 0)
  for (int i = lane; i < 640; i += 64) ((uint4*)w1)[i] = (uint4){0u,0u,0u,0u};
  // x gather -> fw2[0..149]
  for (int i = lane; i < 150; i += 64){
    int which = (i < 75) ? 0 : 1;
    int j = i - which*75;
    int c = j/25, vj = j%25;
    int ts = t - which;
    fw2[i] = (ts >= 0) ? p.x[(((n*3+c)*64+ts)*25+vj)*2+m] : 0.f;
  }
  lfence();   // zero + x-gather visible
  // e1 (lane = o): e1p @w1[0] stride 72, e1d @w1[2304]
  {
    float jwv[3], dwv[3];
    #pragma unroll
    for (int c = 0; c < 3; c++){ jwv[c] = p.jw1[lane*3+c]; dwv[c] = p.dw1[lane*3+c]; }
    float jb = p.jb1[lane], db = p.db1[lane];
    for (int v = 0; v < 25; v++){
      float pa = jb, da = db;
      #pragma unroll
      for (int c = 0; c < 3; c++){
        int ch = c*25+v;
        float xc = fw2[ch];
        float y  = sBnJ[ch]*xc + sBnJ[75+ch];
        float d  = (t > 0) ? (xc - fw2[75+ch]) : 0.f;
        float yd = sBnD[ch]*d + sBnD[75+ch];
        pa += jwv[c]*y;  da += dwv[c]*yd;
      }
      w1[v*72+lane]      = f2b(fmaxf(pa, 0.f));
      w1[2304+v*72+lane] = f2b(fmaxf(da, 0.f));
    }
  }
  lfence();   // e1 writes visible
  // e1 fragments
  s16x8 ep[2][2], ed[2][2];
  #pragma unroll
  for (int mt = 0; mt < 2; mt++)
    #pragma unroll
    for (int kk = 0; kk < 2; kk++){
      ep[mt][kk] = *(const s16x8*)&w1[(mt*16+l15)*72 + kk*32 + l4*8];
      ed[mt][kk] = *(const s16x8*)&w1[2304 + (mt*16+l15)*72 + kk*32 + l4*8];
    }
  // h0 GEMM: pos/dif, hi/lo weights
  f32x4 aP[2][2], aD[2][2];
  #pragma unroll
  for (int mt = 0; mt < 2; mt++)
    #pragma unroll
    for (int nt = 0; nt < 2; nt++){ aP[mt][nt] = (f32x4){0.f,0.f,0.f,0.f}; aD[mt][nt] = (f32x4){0.f,0.f,0.f,0.f}; }
  #pragma unroll
  for (int kk = 0; kk < 2; kk++){
    #pragma unroll
    for (int nt = 0; nt < 2; nt++){
      size_t fo = ((size_t)(nt*2+kk)*64 + lane)*8;
      s16x8 bjh = *(const s16x8*)(wf + WF_JW2H + fo);
      s16x8 bjl = *(const s16x8*)(wf + WF_JW2L + fo);
      s16x8 bdh = *(const s16x8*)(wf + WF_DW2H + fo);
      s16x8 bdl = *(const s16x8*)(wf + WF_DW2L + fo);
      #pragma unroll
      for (int mt = 0; mt < 2; mt++){
        aP[mt][nt] = mfma16(ep[mt][kk], bjh, aP[mt][nt]);
        aP[mt][nt] = mfma16(ep[mt][kk], bjl, aP[mt][nt]);
        aD[mt][nt] = mfma16(ed[mt][kk], bdh, aD[mt][nt]);
        aD[mt][nt] = mfma16(ed[mt][kk], bdl, aD[mt][nt]);
      }
    }
  }
  lfence();   // ep/ed LDS reads complete before h0-plane overwrite (WAR)
  // h0 = relu(P+jb2)+relu(D+db2) -> hi @w1[0], lo @w1[2304] (cols 0-31)
  #pragma unroll
  for (int nt = 0; nt < 2; nt++){
    int c2 = nt*16 + l15;
    float jb2v = p.jb2[c2], db2v = p.db2[c2];
    #pragma unroll
    for (int mt = 0; mt < 2; mt++){
      #pragma unroll
      for (int r = 0; r < 4; r++){
        int v = mt*16 + l4*4 + r;
        if (v < 25){
          float h0 = fmaxf(aP[mt][nt][r]+jb2v, 0.f) + fmaxf(aD[mt][nt][r]+db2v, 0.f);
          ushortT hh = f2b(h0);
          w1[v*72+c2] = hh;
          w1[2304+v*72+c2] = f2b(h0 - b2f(hh));
        }
      }
    }
  }
  // spa cols 32..63 from packed table (both planes)
  for (int i = lane; i < 100; i += 64){
    int v = i >> 2, ch = i & 3;
    *(uint4*)&w1[v*72+32+ch*8]      = *(const uint4*)(wf + WF_SPAH + i*8);
    *(uint4*)&w1[2304+v*72+32+ch*8] = *(const uint4*)(wf + WF_SPAL + i*8);
  }
  lfence();   // h0 hi/lo planes visible
  // h fragments
  s16x8 hfh[2][4], hfl[2][2];
  #pragma unroll
  for (int nt = 0; nt < 2; nt++)
    #pragma unroll
    for (int kk = 0; kk < 2; kk++){
      hfh[nt][kk] = *(const s16x8*)&w1[(nt*16+l15)*72 + kk*32 + l4*8];
      hfl[nt][kk] = *(const s16x8*)&w1[2304 + (nt*16+l15)*72 + kk*32 + l4*8];
    }
  // Cu/Cv (VALU from LDS planes): fw1[2304+u], fw1[2336+v]
  {
    int up = lane >> 5, r = lane & 31;
    float acc = 0.f;
    if (r < 25){
      const float* cv = ws + OFF_C1 + up*64;
      for (int j8 = 0; j8 < 8; j8++){
        s16x8 hh = *(const s16x8*)&w1[r*72 + j8*8];
        s16x8 ll = *(const s16x8*)&w1[2304 + r*72 + j8*8];
        #pragma unroll
        for (int e = 0; e < 8; e++)
          acc += cv[j8*8+e] * (b2f((ushortT)hh[e]) + b2f((ushortT)ll[e]));
      }
    }
    fw1[2304 + up*32 + r] = acc;
  }
  // Y-GEMM: Y[u][i] = (A h_u)[i], 3-term hi/lo
  f32x4 aY[2][4];
  #pragma unroll
  for (int mt = 0; mt < 2; mt++)
    #pragma unroll
    for (int nt = 0; nt < 4; nt++) aY[mt][nt] = (f32x4){0.f,0.f,0.f,0.f};
  #pragma unroll
  for (int kk = 0; kk < 2; kk++){
    #pragma unroll
    for (int nt = 0; nt < 4; nt++){
      size_t fo = ((size_t)(nt*2+kk)*64 + lane)*8;
      s16x8 bah = *(const s16x8*)(wf + WF_AH + fo);
      s16x8 bal = *(const s16x8*)(wf + WF_AL + fo);
      #pragma unroll
      for (int mt = 0; mt < 2; mt++){
        aY[mt][nt] = mfma16(hfh[mt][kk], bah, aY[mt][nt]);
        aY[mt][nt] = mfma16(hfl[mt][kk], bah, aY[mt][nt]);
        aY[mt][nt] = mfma16(hfh[mt][kk], bal, aY[mt][nt]);
      }
    }
  }
  lfence();   // x/e1d-region reads done before Y pack overwrites w2 (WAR)
  // pack Y: hi @w2[0] stride 72, lo @w2[2304] stride 64 chunk-XOR swizzled
  #pragma unroll
  for (int mt = 0; mt < 2; mt++){
    #pragma unroll
    for (int nt = 0; nt < 4; nt++){
      int i_ = nt*16 + l15;
      #pragma unroll
      for (int r = 0; r < 4; r++){
        int u = mt*16 + l4*4 + r;
        float y = aY[mt][nt][r];
        ushortT hh = f2b(y);
        w2[u*72 + i_] = hh;
        w2[2304 + u*64 + (((i_>>3) ^ (u&7))<<3) + (i_&7)] = f2b(y - b2f(hh));
      }
    }
  }
  lfence();   // Y planes visible
  // S-GEMM: S[v][u] = h_v . Y_u, 3-term
  f32x4 aS[2][2];
  #pragma unroll
  for (int mt = 0; mt < 2; mt++)
    #pragma unroll
    for (int nt = 0; nt < 2; nt++) aS[mt][nt] = (f32x4){0.f,0.f,0.f,0.f};
  #pragma unroll
  for (int kk = 0; kk < 2; kk++){
    #pragma unroll
    for (int nt = 0; nt < 2; nt++){
      int ur = nt*16 + l15;
      s16x8 byh = *(const s16x8*)&w2[ur*72 + kk*32 + l4*8];
      s16x8 byl = *(const s16x8*)&w2[2304 + ur*64 + ((((kk*4+l4)) ^ (ur&7))<<3)];
      #pragma unroll
      for (int mt = 0; mt < 2; mt++){
        aS[mt][nt] = mfma16(hfh[mt][kk], byh, aS[mt][nt]);
        aS[mt][nt] = mfma16(hfl[mt][kk], byh, aS[mt][nt]);
        aS[mt][nt] = mfma16(hfh[mt][kk], byl, aS[mt][nt]);
      }
    }
  }
  lfence();   // byh/byl reads done before g overwrite of w2 (WAR)
  // softmax + g write (hi @w2[0] stride 40, lo @w2[1280])
  {
    float d0 = ws[OFF_C1+128];
    float cu0 = fw1[2304 + l15];
    float cu1 = fw1[2304 + 16 + l15];
    bool m1 = (16 + l15) < 25;
    #pragma unroll
    for (int mt = 0; mt < 2; mt++){
      #pragma unroll
      for (int r = 0; r < 4; r++){
        int v = mt*16 + l4*4 + r;
        float cvv = (v < 25) ? fw1[2336+v] : 0.f;
        float s0 = aS[mt][0][r] + cu0 + cvv + d0;
        float s1 = m1 ? (aS[mt][1][r] + cu1 + cvv + d0) : -1e30f;
        float mx = fmaxf(s0, s1);
        mx = fmaxf(mx, __shfl_xor(mx, 1));
        mx = fmaxf(mx, __shfl_xor(mx, 2));
        mx = fmaxf(mx, __shfl_xor(mx, 4));
        mx = fmaxf(mx, __shfl_xor(mx, 8));
        float e0 = __expf(s0 - mx);
        float e1v = m1 ? __expf(s1 - mx) : 0.f;
        float sm = e0 + e1v;
        sm += __shfl_xor(sm, 1);
        sm += __shfl_xor(sm, 2);
        sm += __shfl_xor(sm, 4);
        sm += __shfl_xor(sm, 8);
        float inv = 1.f/sm;
        float g0 = e0*inv, g1 = e1v*inv;
        ushortT g0h = f2b(g0), g1h = f2b(g1);
        w2[v*40+l15]         = g0h;
        w2[1280+v*40+l15]    = f2b(g0 - b2f(g0h));
        w2[v*40+16+l15]      = g1h;
        w2[1280+v*40+16+l15] = f2b(g1 - b2f(g1h));
      }
    }
  }
  lfence();   // g writes visible
  s16x8 gfh[2], gfl[2];
  #pragma unroll
  for (int nt = 0; nt < 2; nt++){
    gfh[nt] = *(const s16x8*)&w2[(nt*16+l15)*40 + l4*8];
    gfl[nt] = *(const s16x8*)&w2[1280 + (nt*16+l15)*40 + l4*8];
  }
  lfence();   // gf reads done before sHB pad-zero / overwrite (WAR)
  // zero sHB pad rows (25..31)
  for (int i = lane; i < 119; i += 64) *(uint4*)&w2[3400 + i*8] = (uint4){0u,0u,0u,0u};
  lfence();   // pad zeros visible

  // gcn chain (w1 = YT scratch, w2 = h buffer stride 136)
  const float* tmtt = ws + OFF_TMT + t*128;
  gcn_layer<2,1,0>(hfh, wf+WF_W1, wf+WF_W1B, sBN, sBN+64, gfh, gfl, w1, w2, tmtt, lane);
  lfence();   // sHB writes visible
  #pragma unroll
  for (int nt = 0; nt < 2; nt++)
    #pragma unroll
    for (int kk = 0; kk < 2; kk++)
      hfh[nt][kk] = *(const s16x8*)&w2[(nt*16+l15)*136 + kk*32 + l4*8];
  lfence();   // reload done before next layer overwrites sHB (WAR)
  gcn_layer<2,2,0>(hfh, wf+WF_W2, wf+WF_W2B, sBN+128, sBN+256, gfh, gfl, w1, w2, tmtt, lane);
  lfence();
  #pragma unroll
  for (int nt = 0; nt < 2; nt++)
    #pragma unroll
    for (int kk = 0; kk < 4; kk++)
      hfh[nt][kk] = *(const s16x8*)&w2[(nt*16+l15)*136 + kk*32 + l4*8];
  lfence();
  gcn_layer<4,2,1>(hfh, wf+WF_W3, wf+WF_W3B, sBN+384, sBN+512, gfh, gfl, w1, w2, tmtt, lane);

  __syncthreads();
  // 4-t maxpool across the block's 4 waves
  int bb = ic0 >> 6, sg = (ic0 & 63) >> 2;
  for (int i = tid; i < 3200; i += 256){
    int v = i >> 7, co = i & 127;
    float mx =     b2f(W2[0][v*136+co]);
    mx = fmaxf(mx, b2f(W2[1][v*136+co]));
    mx = fmaxf(mx, b2f(W2[2][v*136+co]));
    mx = fmaxf(mx, b2f(W2[3][v*136+co]));
    p.poolb[(((size_t)bb*16+sg)*25+v)*128 + co] = f2b(mx);
  }
}

// ---------------- k_lc: fused loc (conv3 + 1x1 + sum_s), wave = (b,v) --------
__global__ __launch_bounds__(256) void k_lc(P p){
  __shared__ ushortT sA[4][2448];
  __shared__ ushortT sO[4][2176];
  __shared__ float sB1[256], sB2[512];
  int tid = threadIdx.x, wave = tid >> 6, lane = tid & 63;
  int l15 = lane & 15, l4 = lane >> 4;
  int tk = blockIdx.x*4 + wave;
  int b = tk / 25, v = tk % 25;
  float* ws = p.ws;
  if (tid < 256) sB1[tid] = ws[OFF_BNL1 + tid];
  for (int i = tid; i < 512; i += 256) sB2[i] = ws[OFF_BNL2 + i];
  __syncthreads();

  ushortT* A = sA[wave];
  ushortT* O = sO[wave];
  for (int i = lane; i < 68; i += 64){
    *(unsigned*)&A[i*2] = 0u;
    *(unsigned*)&A[2312 + i*2] = 0u;
  }
  for (int i = lane; i < 256; i += 64){
    int r = i >> 4, c8 = i & 15;
    *(uint4*)&A[(r+1)*136 + c8*8] =
      *(const uint4*)&p.poolb[((size_t)(b*16+r)*25 + v)*128 + c8*8];
  }
  lfence();
  const ushortT* lw1f = p.wf + WF_LW1;
  const ushortT* lw2f = p.wf + WF_LW2;

  f32x4 a1[8];
  #pragma unroll
  for (int ct = 0; ct < 8; ct++) a1[ct] = (f32x4){0.f,0.f,0.f,0.f};
  #pragma unroll
  for (int d = 0; d < 3; d++){
    #pragma unroll
    for (int kk = 0; kk < 4; kk++){
      s16x8 af = *(const s16x8*)&A[(l15+d)*136 + kk*32 + l4*8];
      #pragma unroll
      for (int ct = 0; ct < 8; ct++){
        s16x8 bf = *(const s16x8*)(lw1f + (size_t)(((d*4+kk)*8+ct)*512 + lane*8));
        a1[ct] = mfma16(af, bf, a1[ct]);
      }
    }
  }
  #pragma unroll
  for (int ct = 0; ct < 8; ct++){
    int co = ct*16 + l15;
    float s1 = sB1[co], o1 = sB1[128+co];
    #pragma unroll
    for (int r = 0; r < 4; r++)
      O[(l4*4+r)*136 + co] = f2b(fmaxf(s1*a1[ct][r] + o1, 0.f));
  }
  lfence();
  s16x8 af2[4];
  #pragma unroll
  for (int kk = 0; kk < 4; kk++)
    af2[kk] = *(const s16x8*)&O[l15*136 + kk*32 + l4*8];
  f32x4 a2[16];
  #pragma unroll
  for (int ct = 0; ct < 16; ct++) a2[ct] = (f32x4){0.f,0.f,0.f,0.f};
  #pragma unroll
  for (int kk = 0; kk < 4; kk++){
    #pragma unroll
    for (int ct = 0; ct < 16; ct++){
      s16x8 bf = *(const s16x8*)(lw2f + (size_t)((kk*16+ct)*512 + lane*8));
      a2[ct] = mfma16(af2[kk], bf, a2[ct]);
    }
  }
  #pragma unroll
  for (int ct = 0; ct < 16; ct++){
    int co = ct*16 + l15;
    float s2 = sB2[co], o2 = sB2[256+co];
    float sum = 0.f;
    #pragma unroll
    for (int r = 0; r < 4; r++) sum += fmaxf(s2*a2[ct][r] + o2, 0.f);
    sum += __shfl_xor(sum, 16);
    sum += __shfl_xor(sum, 32);
    if (lane < 16) ws[OFF_PART2 + (size_t)(b*25+v)*256 + co] = sum;
  }
}

// ---------------- k_final ---------------------------------------------------
__global__ __launch_bounds__(256) void k_final(P p){
  __shared__ float pool[5*256];
  int tid = threadIdx.x, n = blockIdx.x;
  const float* part = p.ws + OFF_PART2;
  float tot = 0.f, hd = 0.f, hn = 0.f, ft = 0.f, hq = 0.f;
  for (int m2 = 0; m2 < 2; m2++){
    for (int v = 0; v < 25; v++){
      float pv = part[(size_t)((n*2+m2)*25+v)*256 + tid];
      tot += pv;
      unsigned bit = 1u << v;
      if (bit & 0x10000Cu)  hd += pv;
      if (bit & 0x1E00FF0u) hn += pv;
      if (bit & 0xFF000u)   ft += pv;
      if (bit & 0x11007u)   hq += pv;
    }
  }
  pool[tid]      = tot * (1.f/800.f);
  pool[256+tid]  = hd  * (1.f/96.f);
  pool[512+tid]  = hn  * (1.f/384.f);
  pool[768+tid]  = ft  * (1.f/256.f);
  pool[1024+tid] = hq  * (1.f/160.f);
  __syncthreads();
  float* out = p.out;
  for (int o = tid; o < 2620; o += 256){
    const float* wrow; float bias; const float* pl; int off;
    if (o < 60)        { wrow = p.fcw + o*256;            bias = p.fcb[o];        pl = pool;       off = n*60+o; }
    else if (o < 572)  { int j=o-60;   wrow = p.hww + j*256;         bias = p.hwb[j];       pl = pool;       off = 7680   + n*512+j; }
    else if (o < 1084) { int j=o-572;  wrow = p.pw  + j*256;         bias = p.pb[j];        pl = pool+256;   off = 73221  + n*512+j; }
    else if (o < 1596) { int j=o-1084; wrow = p.pw  + (512+j)*256;   bias = p.pb[512+j];    pl = pool+512;   off = 138757 + n*512+j; }
    else if (o < 2108) { int j=o-1596; wrow = p.pw  + (1536+j)*256;  bias = p.pb[1536+j];   pl = pool+1024;  off = 204293 + n*512+j; }
    else               { int j=o-2108; wrow = p.pw  + (1024+j)*256;  bias = p.pb[1024+j];   pl = pool+768;   off = 269829 + n*512+j; }
    float acc = bias;
    for (int c = 0; c < 256; c++) acc += wrow[c]*pl[c];
    out[off] = acc;
  }
  if (n == 0 && tid < 5) out[73216+tid] = p.ls[tid];
}

extern "C" void kernel_launch(void* const* d_in, const int* in_sizes, int n_in,
                              void* d_out, int out_size, void* d_ws, size_t ws_size,
                              hipStream_t stream){
  P p;
  p.x        = (const float*)d_in[0];
  p.bn_joint = (const float*)d_in[1];
  p.jw1      = (const float*)d_in[2];
  p.jb1      = (const float*)d_in[3];
  p.jw2      = (const float*)d_in[4];
  p.jb2      = (const float*)d_in[5];
  p.bn_dif   = (const float*)d_in[6];
  p.dw1      = (const float*)d_in[7];
  p.db1      = (const float*)d_in[8];
  p.dw2      = (const float*)d_in[9];
  p.db2      = (const float*)d_in[10];
  p.tw1      = (const float*)d_in[11];
  p.tb1      = (const float*)d_in[12];
  p.tw2      = (const float*)d_in[13];
  p.tb2      = (const float*)d_in[14];
  p.sw1      = (const float*)d_in[15];
  p.sb1      = (const float*)d_in[16];
  p.sw2      = (const float*)d_in[17];
  p.sb2      = (const float*)d_in[18];
  p.g1w      = (const float*)d_in[19];
  p.g1b      = (const float*)d_in[20];
  p.g2w      = (const float*)d_in[21];
  p.g2b      = (const float*)d_in[22];
  p.c1w      = (const float*)d_in[23];
  p.c1w1     = (const float*)d_in[24];
  p.c1b1     = (const float*)d_in[25];
  p.bnc1     = (const float*)d_in[26];
  p.c2w      = (const float*)d_in[27];
  p.c2w1     = (const float*)d_in[28];
  p.c2b1     = (const float*)d_in[29];
  p.bnc2     = (const float*)d_in[30];
  p.c3w      = (const float*)d_in[31];
  p.c3w1     = (const float*)d_in[32];
  p.c3b1     = (const float*)d_in[33];
  p.bnc3     = (const float*)d_in[34];
  p.lw1      = (const float*)d_in[35];
  p.lb1      = (const float*)d_in[36];
  p.bnl1     = (const float*)d_in[37];
  p.lw2      = (const float*)d_in[38];
  p.lb2      = (const float*)d_in[39];
  p.bnl2     = (const float*)d_in[40];
  p.fcw      = (const float*)d_in[41];
  p.fcb      = (const float*)d_in[42];
  p.hww      = (const float*)d_in[43];
  p.hwb      = (const float*)d_in[44];
  p.pw       = (const float*)d_in[45];
  p.pb       = (const float*)d_in[46];
  p.ls       = (const float*)d_in[47];
  p.ws  = (float*)d_ws;
  p.out = (float*)d_out;

  char* wsb = (char*)d_ws;
  p.wf    = (const ushortT*)(wsb + WF_B);
  p.poolb = (ushortT*)(wsb + POOL_B);

  k_pre1 <<<dim3(32),   dim3(256), 0, stream>>>(p);
  k_pre2 <<<dim3(32),   dim3(256), 0, stream>>>(p);
  k_fwd  <<<dim3(4096), dim3(256), 0, stream>>>(p);
  k_lc   <<<dim3(1600), dim3(256), 0, stream>>>(p);
  k_final<<<dim3(128),  dim3(256), 0, stream>>>(p);
}